// Round 4
// baseline (4676.101 us; speedup 1.0000x reference)
//
#include <hip/hip_runtime.h>
#include <stdint.h>
#include <stddef.h>

// SpatialNSA on MI355X — round 4:
//  * attention rewritten: lane = (query, d-chunk) 4-way split; ~60 VGPRs live,
//    no scratch spill, no LDS. 2-pass (importance needs final softmax).
//  * everything else identical to the passing round-3 pipeline.

#define DEV __device__ __forceinline__

typedef __attribute__((ext_vector_type(8))) short short8;
typedef __attribute__((ext_vector_type(4))) float f32x4;

DEV unsigned short f2bf(float f){
    unsigned u = __float_as_uint(f);
    u += 0x7FFFu + ((u>>16)&1u);   // RNE
    return (unsigned short)(u>>16);
}

// ---------------- transpose: x (B,C,N) f32 -> xs (B,N,C) f32 -------------
__global__ void k_xs(const float* __restrict__ x, float* __restrict__ xs){
    __shared__ float t[32][33];
    int b = blockIdx.z; int c0 = blockIdx.y*32; int n0 = blockIdx.x*32;
    int tx = threadIdx.x, ty = threadIdx.y;            // (32,8)
    for(int i=ty;i<32;i+=8)
        t[i][tx] = x[((size_t)(b*256 + c0+i))*4096 + n0 + tx];
    __syncthreads();
    for(int i=ty;i<32;i+=8)
        xs[((size_t)(b*4096 + n0+i))*256 + c0 + tx] = t[tx][i];
}

// -------- weight transpose+cast: W (K,N) f32 -> WT (N,K) bf16 ---------------
__global__ void k_wt(const float* __restrict__ W, unsigned short* __restrict__ WT,
                     int K, int N){
    __shared__ float t[32][33];
    int k0 = blockIdx.x*32, n0 = blockIdx.y*32;
    int tx = threadIdx.x, ty = threadIdx.y;            // (32,8)
    for(int i=ty;i<32;i+=8)
        if(k0+i<K && n0+tx<N) t[i][tx] = W[(size_t)(k0+i)*N + n0+tx];
    __syncthreads();
    for(int i=ty;i<32;i+=8)
        if(n0+i<N && k0+tx<K) WT[(size_t)(n0+i)*K + k0+tx] = f2bf(t[tx][i]);
}

// ---------------- f32 GEMM (selection-critical path) -------------------------
__global__ __launch_bounds__(256) void k_gemm(
        const float* __restrict__ A, const float* __restrict__ W,
        const float* __restrict__ bias, float* __restrict__ C,
        int M, int K, int Nn, int act)
{
    __shared__ float As[16][68];
    __shared__ float Bs[16][64];
    const int m0 = blockIdx.y*64, n0 = blockIdx.x*64;
    const int t = threadIdx.x, tx = t&15, ty = t>>4;
    float acc[4][4] = {};
    const int am = t>>2;
    const int ak = (t&3)*4;
    const bool arow_ok = (m0+am) < M;

    for(int k0=0;k0<K;k0+=16){
        float4 av = make_float4(0.f,0.f,0.f,0.f);
        if(arow_ok) av = *reinterpret_cast<const float4*>(&A[(size_t)(m0+am)*K + k0 + ak]);
        As[ak+0][am]=av.x; As[ak+1][am]=av.y; As[ak+2][am]=av.z; As[ak+3][am]=av.w;
        if((Nn & 3) == 0){
            int bn = (t&15)*4, bk = t>>4;
            float4 bv = make_float4(0.f,0.f,0.f,0.f);
            if(n0+bn < Nn)
                bv = *reinterpret_cast<const float4*>(&W[(size_t)(k0+bk)*Nn + n0+bn]);
            Bs[bk][bn]=bv.x; Bs[bk][bn+1]=bv.y; Bs[bk][bn+2]=bv.z; Bs[bk][bn+3]=bv.w;
        } else {
            int n = t&63, kb = t>>6;
            #pragma unroll
            for(int r=0;r<4;r++){
                int kk = r*4 + kb; float v = 0.f;
                if(n0+n < Nn) v = W[(size_t)(k0+kk)*Nn + n0+n];
                Bs[kk][n] = v;
            }
        }
        __syncthreads();
        #pragma unroll
        for(int kk=0;kk<16;kk++){
            float a0=As[kk][ty*4+0], a1=As[kk][ty*4+1], a2=As[kk][ty*4+2], a3=As[kk][ty*4+3];
            float b0=Bs[kk][tx*4+0], b1=Bs[kk][tx*4+1], b2=Bs[kk][tx*4+2], b3=Bs[kk][tx*4+3];
            acc[0][0]=fmaf(a0,b0,acc[0][0]); acc[0][1]=fmaf(a0,b1,acc[0][1]);
            acc[0][2]=fmaf(a0,b2,acc[0][2]); acc[0][3]=fmaf(a0,b3,acc[0][3]);
            acc[1][0]=fmaf(a1,b0,acc[1][0]); acc[1][1]=fmaf(a1,b1,acc[1][1]);
            acc[1][2]=fmaf(a1,b2,acc[1][2]); acc[1][3]=fmaf(a1,b3,acc[1][3]);
            acc[2][0]=fmaf(a2,b0,acc[2][0]); acc[2][1]=fmaf(a2,b1,acc[2][1]);
            acc[2][2]=fmaf(a2,b2,acc[2][2]); acc[2][3]=fmaf(a2,b3,acc[2][3]);
            acc[3][0]=fmaf(a3,b0,acc[3][0]); acc[3][1]=fmaf(a3,b1,acc[3][1]);
            acc[3][2]=fmaf(a3,b2,acc[3][2]); acc[3][3]=fmaf(a3,b3,acc[3][3]);
        }
        __syncthreads();
    }
    #pragma unroll
    for(int i=0;i<4;i++){
        int m = m0 + ty*4 + i;
        if(m >= M) continue;
        #pragma unroll
        for(int j=0;j<4;j++){
            int n = n0 + tx*4 + j;
            if(n >= Nn) continue;
            float v = acc[i][j] + bias[n];
            if(act==1)      v = 0.5f*v*(1.0f + erff(v*0.70710678118654752f));
            else if(act==2) v = 1.0f/(1.0f + expf(-v));
            C[(size_t)m*Nn + n] = v;
        }
    }
}

// ---------------- bf16 MFMA GEMM: C = act(A(M,K f32) @ W + bias) -------------
__global__ __launch_bounds__(256) void k_gemm_mfma(
        const float* __restrict__ A, const unsigned short* __restrict__ WT,
        const float* __restrict__ bias, float* __restrict__ C,
        int M, int K, int Nn, int act)
{
    __shared__ unsigned short Al[128*64];
    __shared__ unsigned short Bl[128*64];
    const int m0 = blockIdx.y*128, n0 = blockIdx.x*128;
    const int tid = threadIdx.x, lane = tid&63, wv = tid>>6;
    const int wm = (wv>>1)*64, wn = (wv&1)*64;
    f32x4 acc[4][4] = {};

    const int srow = tid>>1;
    const int sks  = (tid&1)*32;

    for(int kt=0; kt<K; kt+=64){
        {
            const bool ok = (m0+srow) < M;
            const float* src = &A[(size_t)(m0+srow)*K + kt + sks];
            #pragma unroll
            for(int c=0;c<4;c++){
                float4 v0 = make_float4(0,0,0,0), v1 = v0;
                if(ok){
                    v0 = *reinterpret_cast<const float4*>(src + c*8);
                    v1 = *reinterpret_cast<const float4*>(src + c*8 + 4);
                }
                short8 s;
                s[0]=(short)f2bf(v0.x); s[1]=(short)f2bf(v0.y);
                s[2]=(short)f2bf(v0.z); s[3]=(short)f2bf(v0.w);
                s[4]=(short)f2bf(v1.x); s[5]=(short)f2bf(v1.y);
                s[6]=(short)f2bf(v1.z); s[7]=(short)f2bf(v1.w);
                int byteoff = srow*128 + ((sks*2 + c*16) ^ ((srow&7)<<4));
                *reinterpret_cast<short8*>(reinterpret_cast<char*>(Al) + byteoff) = s;
            }
        }
        {
            const bool ok = (n0+srow) < Nn;
            const unsigned short* src = &WT[(size_t)(n0+srow)*K + kt + sks];
            #pragma unroll
            for(int c=0;c<4;c++){
                short8 s = {};
                if(ok) s = *reinterpret_cast<const short8*>(src + c*8);
                int byteoff = srow*128 + ((sks*2 + c*16) ^ ((srow&7)<<4));
                *reinterpret_cast<short8*>(reinterpret_cast<char*>(Bl) + byteoff) = s;
            }
        }
        __syncthreads();
        #pragma unroll
        for(int kb=0;kb<2;kb++){
            short8 af[4], bfr[4];
            #pragma unroll
            for(int i=0;i<4;i++){
                int ar = wm + i*16 + (lane&15);
                int abyte = ar*128 + (((kb*64) + ((lane>>4)*16)) ^ ((ar&7)<<4));
                af[i] = *reinterpret_cast<const short8*>(reinterpret_cast<const char*>(Al) + abyte);
                int br = wn + i*16 + (lane&15);
                int bbyte = br*128 + (((kb*64) + ((lane>>4)*16)) ^ ((br&7)<<4));
                bfr[i] = *reinterpret_cast<const short8*>(reinterpret_cast<const char*>(Bl) + bbyte);
            }
            #pragma unroll
            for(int mi=0;mi<4;mi++)
                #pragma unroll
                for(int ni=0;ni<4;ni++)
                    acc[mi][ni] = __builtin_amdgcn_mfma_f32_16x16x32_bf16(
                                      af[mi], bfr[ni], acc[mi][ni], 0, 0, 0);
        }
        __syncthreads();
    }
    #pragma unroll
    for(int mi=0;mi<4;mi++){
        #pragma unroll
        for(int ni=0;ni<4;ni++){
            int col = n0 + wn + ni*16 + (lane&15);
            if(col >= Nn) continue;
            int rowb = m0 + wm + mi*16 + ((lane>>4)*4);
            float bv = bias[col];
            #pragma unroll
            for(int r=0;r<4;r++){
                int m = rowb + r;
                if(m >= M) continue;
                float v = acc[mi][ni][r] + bv;
                if(act==1)      v = 0.5f*v*(1.0f + erff(v*0.70710678118654752f));
                else if(act==2) v = 1.0f/(1.0f + expf(-v));
                C[(size_t)m*Nn + col] = v;
            }
        }
    }
}

// ------------- unfold (CBS=4, stride 2) with torch-quirk flat order -----------
__global__ void k_unfold(const float* __restrict__ qkv, const float* __restrict__ pos,
                         float* __restrict__ outA, int chanBase){
    int row = blockIdx.x;                 // 0..3843
    int b = row / 961, blk = row % 961;
    int bi = blk / 31, bj = blk % 31;
    for(int j = threadIdx.x; j < 4096; j += 256){
        int ch = j >> 4;
        int kh = (j >> 2) & 3, kw = j & 3;
        int n = (bi*2 + kh)*64 + (bj*2 + kw);
        float v = qkv[((size_t)(b*4096) + n)*768 + chanBase + ch];
        if(pos) v += pos[j];
        outA[(size_t)row*4096 + j] = v;
    }
}

// ------------- attention v3: lane=(query, d-chunk), no LDS, no spill ----------
// Block: 256 thr = 4 waves; wave owns 16 queries; lane&3 = d-chunk (16 floats).
// qsrc rows: (b*4096+q)*768 + h*64 ; Km/Vm rows: (b*NK+key)*256 + h*64
// impp (if non-null): row = ((b*4+h)*64 + qt)*4 + wv, 961 cols.
__global__ __launch_bounds__(256) void k_attn3(
    const float* __restrict__ qsrc, const float* __restrict__ Km,
    const float* __restrict__ Vm, int NK,
    float* __restrict__ outp, float* __restrict__ impp)
{
    const int qt = blockIdx.x, h = blockIdx.y, b = blockIdx.z;
    const int tid = threadIdx.x, wv = tid>>6, lane = tid&63;
    const int qi = wv*16 + (lane>>2);          // query within block
    const int chunk = lane&3;                  // 16-float d-chunk
    const int q = qt*64 + qi;

    const float4* qp = reinterpret_cast<const float4*>(
        &qsrc[((size_t)(b*4096 + q))*768 + h*64 + chunk*16]);
    float4 q0 = qp[0], q1 = qp[1], q2 = qp[2], q3 = qp[3];

    const float4* kbase = reinterpret_cast<const float4*>(
        Km + ((size_t)b*NK)*256 + h*64 + chunk*16);
    const float4* vbase = reinterpret_cast<const float4*>(
        Vm + ((size_t)b*NK)*256 + h*64 + chunk*16);

    // ---- pass 1: running max + denom ----
    float m = -1e30f, l = 0.f;
    for(int key=0; key<NK; ++key){
        const float4* kp = kbase + (size_t)key*64;
        float4 k0 = kp[0], k1 = kp[1], k2 = kp[2], k3 = kp[3];
        float s0 = q0.x*k0.x + q0.y*k0.y + q0.z*k0.z + q0.w*k0.w;
        s0 = fmaf(q1.x,k1.x, fmaf(q1.y,k1.y, fmaf(q1.z,k1.z, fmaf(q1.w,k1.w, s0))));
        s0 = fmaf(q2.x,k2.x, fmaf(q2.y,k2.y, fmaf(q2.z,k2.z, fmaf(q2.w,k2.w, s0))));
        s0 = fmaf(q3.x,k3.x, fmaf(q3.y,k3.y, fmaf(q3.z,k3.z, fmaf(q3.w,k3.w, s0))));
        s0 += __shfl_xor(s0, 1);
        s0 += __shfl_xor(s0, 2);
        float s = s0 * 0.125f;
        float mn = fmaxf(m, s);
        l = l*__expf(m - mn) + __expf(s - mn);
        m = mn;
    }
    const float inv_l = 1.f / l;

    // ---- pass 2: probs, PV, importance ----
    float4 a0 = {0,0,0,0}, a1 = {0,0,0,0}, a2 = {0,0,0,0}, a3 = {0,0,0,0};
    const size_t improw = impp ? ((size_t)((b*4 + h)*64 + qt)*4 + wv)*961 : 0;
    for(int key=0; key<NK; ++key){
        const float4* kp = kbase + (size_t)key*64;
        float4 k0 = kp[0], k1 = kp[1], k2 = kp[2], k3 = kp[3];
        float s0 = q0.x*k0.x + q0.y*k0.y + q0.z*k0.z + q0.w*k0.w;
        s0 = fmaf(q1.x,k1.x, fmaf(q1.y,k1.y, fmaf(q1.z,k1.z, fmaf(q1.w,k1.w, s0))));
        s0 = fmaf(q2.x,k2.x, fmaf(q2.y,k2.y, fmaf(q2.z,k2.z, fmaf(q2.w,k2.w, s0))));
        s0 = fmaf(q3.x,k3.x, fmaf(q3.y,k3.y, fmaf(q3.z,k3.z, fmaf(q3.w,k3.w, s0))));
        s0 += __shfl_xor(s0, 1);
        s0 += __shfl_xor(s0, 2);
        float p = __expf(s0*0.125f - m);
        const float4* vp = vbase + (size_t)key*64;
        float4 v0 = vp[0], v1 = vp[1], v2 = vp[2], v3 = vp[3];
        a0.x = fmaf(p, v0.x, a0.x); a0.y = fmaf(p, v0.y, a0.y);
        a0.z = fmaf(p, v0.z, a0.z); a0.w = fmaf(p, v0.w, a0.w);
        a1.x = fmaf(p, v1.x, a1.x); a1.y = fmaf(p, v1.y, a1.y);
        a1.z = fmaf(p, v1.z, a1.z); a1.w = fmaf(p, v1.w, a1.w);
        a2.x = fmaf(p, v2.x, a2.x); a2.y = fmaf(p, v2.y, a2.y);
        a2.z = fmaf(p, v2.z, a2.z); a2.w = fmaf(p, v2.w, a2.w);
        a3.x = fmaf(p, v3.x, a3.x); a3.y = fmaf(p, v3.y, a3.y);
        a3.z = fmaf(p, v3.z, a3.z); a3.w = fmaf(p, v3.w, a3.w);
        if(impp){
            float pn = p * inv_l;           // same within chunk-group of 4 lanes
            pn += __shfl_xor(pn, 4);
            pn += __shfl_xor(pn, 8);
            pn += __shfl_xor(pn, 16);
            pn += __shfl_xor(pn, 32);
            if(lane==0) impp[improw + key] = pn * 0.25f;  // 4 chunk-copies per query
        }
    }
    float4* op = reinterpret_cast<float4*>(
        &outp[((size_t)(b*4096 + q))*256 + h*64 + chunk*16]);
    a0.x*=inv_l; a0.y*=inv_l; a0.z*=inv_l; a0.w*=inv_l;
    a1.x*=inv_l; a1.y*=inv_l; a1.z*=inv_l; a1.w*=inv_l;
    a2.x*=inv_l; a2.y*=inv_l; a2.z*=inv_l; a2.w*=inv_l;
    a3.x*=inv_l; a3.y*=inv_l; a3.z*=inv_l; a3.w*=inv_l;
    op[0]=a0; op[1]=a1; op[2]=a2; op[3]=a3;
}

// ------------- deterministic importance reduce (1024 rows/batch) ------------
__global__ void k_imp_reduce(const float* __restrict__ impp, float* __restrict__ imp){
    int blk = blockIdx.x*256 + threadIdx.x;
    int b = blockIdx.y;
    if(blk >= 961) return;
    float s = 0.f;
    for(int r=0;r<1024;r++) s += impp[(size_t)(b*1024 + r)*961 + blk];
    imp[b*961 + blk] = s;
}

// ------------- top-16 with lowest-index tie-break ----------------------------
__global__ void k_topk(const float* __restrict__ imp, int* __restrict__ idx){
    int b = blockIdx.x;
    __shared__ float v[961];
    __shared__ float bestv[256];
    __shared__ int   besti[256];
    int t = threadIdx.x;
    for(int i=t;i<961;i+=256) v[i] = imp[b*961+i];
    __syncthreads();
    for(int it=0; it<16; it++){
        float bv = -1e30f; int bi = 0;
        for(int i=t;i<961;i+=256){
            if(v[i] > bv){ bv=v[i]; bi=i; }
        }
        bestv[t]=bv; besti[t]=bi;
        __syncthreads();
        if(t==0){
            float gb=-1e30f; int gi=0;
            for(int i=0;i<256;i++){
                if(bestv[i]>gb || (bestv[i]==gb && besti[i]<gi)){ gb=bestv[i]; gi=besti[i]; }
            }
            idx[b*16+it] = gi;
            v[gi] = -1e30f;
        }
        __syncthreads();
    }
}

// ------------- gather selected K/V (quirk layout, clip to 255) ----------------
__global__ void k_gather_sel(const float* __restrict__ qkv2, const int* __restrict__ idx,
                             float* __restrict__ Ks, float* __restrict__ Vs){
    int row = blockIdx.x;            // b*256 + t ; t = sel*16 + p
    int b = row >> 8, tt = row & 255;
    int sel = tt >> 4, p = tt & 15;
    int blk = idx[b*16+sel]; if(blk > 255) blk = 255;
    int bi = blk >> 4, bj = blk & 15;
    int cc = threadIdx.x;
    int y = bi*4 + ((cc>>2)&3), xx = bj*4 + (cc&3);
    int ch = p*16 + (cc>>4);
    size_t src = ((size_t)(b*4096) + y*64 + xx)*768;
    Ks[(size_t)row*256 + cc] = qkv2[src + 256 + ch];
    Vs[(size_t)row*256 + cc] = qkv2[src + 512 + ch];
}

// ------------- build padded window tokens xw (400*49, 256) -------------------
__global__ void k_xw(const float* __restrict__ xs, float* __restrict__ xw){
    int row = blockIdx.x;             // wb*49 + t
    int wb = row / 49, t = row % 49;
    int b = wb / 100, wrem = wb % 100;
    int wy = wrem / 10, wx = wrem % 10;
    int ty = t / 7, tx = t % 7;
    int y = wy*7 + ty, xx = wx*7 + tx;
    int c = threadIdx.x;
    float v = 0.f;
    if(y < 64 && xx < 64) v = xs[((size_t)(b*4096) + y*64 + xx)*256 + c];
    xw[(size_t)row*256 + c] = v;
}

// ------------- window attention: 49 tokens, rel-pos bias ---------------------
__global__ __launch_bounds__(64) void k_attn_win(
    const float* __restrict__ qkvw, const float* __restrict__ btab,
    float* __restrict__ outp)
{
    const int wb = blockIdx.x, h = blockIdx.y;
    const int lane = threadIdx.x;
    __shared__ float lk[49][64];
    __shared__ float lv[49][64];
    __shared__ float ls[49][51];
    __shared__ float lbias[169];
    for(int i=lane;i<169;i+=64) lbias[i] = btab[i*4 + h];
    for(int r=0;r<49;r++){
        lk[r][lane] = qkvw[((size_t)(wb*49 + r))*768 + 256 + h*64 + lane];
        lv[r][lane] = qkvw[((size_t)(wb*49 + r))*768 + 512 + h*64 + lane];
    }
    __syncthreads();
    if(lane < 49){
        const float* qptr = &qkvw[((size_t)(wb*49 + lane))*768 + h*64];
        float qreg[64];
        #pragma unroll
        for(int d=0;d<64;++d) qreg[d] = qptr[d];
        int ih = lane/7, iw = lane%7;
        float m = -1e30f;
        for(int j=0;j<49;j++){
            float s0=0,s1=0,s2=0,s3=0;
            #pragma unroll
            for(int d=0; d<64; d+=4){
                s0 = fmaf(qreg[d+0], lk[j][d+0], s0);
                s1 = fmaf(qreg[d+1], lk[j][d+1], s1);
                s2 = fmaf(qreg[d+2], lk[j][d+2], s2);
                s3 = fmaf(qreg[d+3], lk[j][d+3], s3);
            }
            int jh=j/7, jw=j%7;
            float s = ((s0+s1)+(s2+s3))*0.125f + lbias[(ih-jh+6)*13 + (iw-jw+6)];
            ls[lane][j] = s;
            m = fmaxf(m, s);
        }
        float l = 0.f;
        for(int j=0;j<49;j++){ float p = __expf(ls[lane][j] - m); ls[lane][j] = p; l += p; }
        float inv = 1.f/l;
        float* op = &outp[((size_t)(wb*49 + lane))*256 + h*64];
        for(int d=0;d<64;d++){
            float a0=0,a1=0;
            for(int j=0;j<48;j+=2){
                a0 = fmaf(ls[lane][j],   lv[j][d],   a0);
                a1 = fmaf(ls[lane][j+1], lv[j+1][d], a1);
            }
            a0 = fmaf(ls[lane][48], lv[48][d], a0);
            op[d] = (a0+a1)*inv;
        }
    }
}

// ------------- final gated combine + transpose to (B,C,H,W) f32 -------------
__global__ void k_combine(const float* __restrict__ ocp, const float* __restrict__ osp,
                          const float* __restrict__ owp, const float* __restrict__ g,
                          float* __restrict__ out){
    __shared__ float tile[32][33];
    int b = blockIdx.z; int c0 = blockIdx.y*32, n0 = blockIdx.x*32;
    int tx = threadIdx.x, ty = threadIdx.y;    // (32,8)
    for(int i=ty;i<32;i+=8){
        int n = n0 + i;
        float g0 = g[(size_t)(b*4096+n)*3 + 0];
        float g1 = g[(size_t)(b*4096+n)*3 + 1];
        float g2 = g[(size_t)(b*4096+n)*3 + 2];
        int y = n >> 6, xx = n & 63;
        int wy = y/7, ty2 = y%7, wx = xx/7, tx2 = xx%7;
        size_t wrow = (size_t)(b*100 + wy*10 + wx)*49 + ty2*7 + tx2;
        size_t base = ((size_t)(b*4096) + n)*256 + c0;
        float vc = ocp[base + tx];
        float vs = osp[base + tx];
        float vw = owp[wrow*256 + c0 + tx];
        tile[i][tx] = g0*vc + g1*vs + g2*vw;
    }
    __syncthreads();
    for(int i=ty;i<32;i+=8)
        out[((size_t)(b*256 + c0+i))*4096 + n0 + tx] = tile[tx][i];
}

// =============================== host side ===================================
extern "C" void kernel_launch(void* const* d_in, const int* in_sizes, int n_in,
                              void* d_out, int out_size, void* d_ws, size_t ws_size,
                              hipStream_t stream)
{
    typedef const float* fp;
    fp x          = (fp)d_in[0];
    fp qkv_cmp_w  = (fp)d_in[1];  fp qkv_cmp_b = (fp)d_in[2];
    fp qkv_slc_w  = (fp)d_in[3];  fp qkv_slc_b = (fp)d_in[4];
    fp cmpk_w1    = (fp)d_in[5];  fp cmpk_b1   = (fp)d_in[6];
    fp cmpk_w2    = (fp)d_in[7];  fp cmpk_b2   = (fp)d_in[8];
    fp cmpv_w1    = (fp)d_in[9];  fp cmpv_b1   = (fp)d_in[10];
    fp cmpv_w2    = (fp)d_in[11]; fp cmpv_b2   = (fp)d_in[12];
    fp pos_embed  = (fp)d_in[13];
    fp win_qkv_w  = (fp)d_in[14]; fp win_qkv_b = (fp)d_in[15];
    fp win_proj_w = (fp)d_in[16]; fp win_proj_b= (fp)d_in[17];
    fp win_btab   = (fp)d_in[18];
    fp proj_cmp_w = (fp)d_in[19]; fp proj_cmp_b= (fp)d_in[20];
    fp proj_slc_w = (fp)d_in[21]; fp proj_slc_b= (fp)d_in[22];
    fp gate_w1    = (fp)d_in[23]; fp gate_b1   = (fp)d_in[24];
    fp gate_w2    = (fp)d_in[25]; fp gate_b2   = (fp)d_in[26];
    (void)in_sizes; (void)n_in; (void)out_size;

    char* ws = (char*)d_ws;
    size_t off = 0;
    auto alloc = [&](size_t bytes)->size_t{
        size_t r = off; off += (bytes + 255) & ~(size_t)255; return r;
    };
    const size_t XS   = alloc((size_t)16384*256*4);
    const size_t QKV  = alloc((size_t)16384*768*4);
    const size_t BIGA = alloc((size_t)3844*4096*4);
    const size_t HID  = alloc((size_t)3844*512*4);
    const size_t KC   = alloc((size_t)3844*256*4);
    const size_t VC   = alloc((size_t)3844*256*4);
    const size_t OC   = alloc((size_t)16384*256*4);
    const size_t IMPP = alloc((size_t)4096*961*4);
    const size_t IMP  = alloc((size_t)4*961*4);
    const size_t IDX  = alloc((size_t)4*16*4);
    const size_t OCP  = alloc((size_t)16384*256*4);
    const size_t XW   = alloc((size_t)19600*256*4);
    const size_t OWP  = alloc((size_t)19600*256*4);
    const size_t KS   = alloc((size_t)4*256*256*4);
    const size_t VS   = alloc((size_t)4*256*256*4);
    const size_t G2   = alloc((size_t)16384*3*4);
    const size_t TQS  = alloc((size_t)768*256*2);
    const size_t TWQ  = alloc((size_t)768*256*2);
    const size_t TV1  = alloc((size_t)512*4096*2);
    const size_t TV2  = alloc((size_t)256*512*2);
    const size_t TPC  = alloc((size_t)256*256*2);
    const size_t TPS  = alloc((size_t)256*256*2);
    const size_t TWP  = alloc((size_t)256*256*2);
    const size_t TG1  = alloc((size_t)64*256*2);
    if(off > ws_size) return;

    float* p_xs  = (float*)(ws + XS);
    float* p_qkv = (float*)(ws + QKV);
    float* p_big = (float*)(ws + BIGA);
    float* p_hid = (float*)(ws + HID);
    float* p_kc  = (float*)(ws + KC);
    float* p_vc  = (float*)(ws + VC);
    float* p_oc  = (float*)(ws + OC);
    float* p_impp= (float*)(ws + IMPP);
    float* p_imp = (float*)(ws + IMP);
    int*   p_idx = (int*)  (ws + IDX);
    float* p_ocp = (float*)(ws + OCP);
    float* p_xw  = (float*)(ws + XW);
    float* p_owp = (float*)(ws + OWP);
    float* p_ks  = (float*)(ws + KS);
    float* p_vs  = (float*)(ws + VS);
    float* p_g   = (float*)(ws + G2);
    unsigned short* t_qs = (unsigned short*)(ws + TQS);
    unsigned short* t_wq = (unsigned short*)(ws + TWQ);
    unsigned short* t_v1 = (unsigned short*)(ws + TV1);
    unsigned short* t_v2 = (unsigned short*)(ws + TV2);
    unsigned short* t_pc = (unsigned short*)(ws + TPC);
    unsigned short* t_ps = (unsigned short*)(ws + TPS);
    unsigned short* t_wp = (unsigned short*)(ws + TWP);
    unsigned short* t_g1 = (unsigned short*)(ws + TG1);

    auto gemm = [&](const float* A, fp W, fp bias, float* Cc, int M, int K, int Nn, int act){
        dim3 g((Nn+63)/64, (M+63)/64);
        k_gemm<<<g, 256, 0, stream>>>(A, W, bias, Cc, M, K, Nn, act);
    };
    auto wt = [&](fp W, unsigned short* WT, int K, int Nn){
        k_wt<<<dim3(K/32, Nn/32), dim3(32,8), 0, stream>>>(W, WT, K, Nn);
    };
    auto mgemm = [&](const float* A, const unsigned short* WT, fp bias, float* Cc,
                     int M, int K, int Nn, int act){
        dim3 g((Nn+127)/128, (M+127)/128);
        k_gemm_mfma<<<g, 256, 0, stream>>>(A, WT, bias, Cc, M, K, Nn, act);
    };

    // 0. transposed bf16 weights (selection-safe gemms)
    wt(qkv_slc_w, t_qs, 256, 768);
    wt(win_qkv_w, t_wq, 256, 768);
    wt(cmpv_w1,   t_v1, 4096, 512);
    wt(cmpv_w2,   t_v2, 512, 256);
    wt(proj_cmp_w,t_pc, 256, 256);
    wt(proj_slc_w,t_ps, 256, 256);
    wt(win_proj_w,t_wp, 256, 256);
    wt(gate_w1,   t_g1, 256, 64);

    // 1. xs = transpose(x)
    k_xs<<<dim3(128,8,4), dim3(32,8), 0, stream>>>(x, p_xs);
    // 2. qkv_cmp (f32 — selection-critical)
    gemm(p_xs, qkv_cmp_w, qkv_cmp_b, p_qkv, 16384, 256, 768, 0);
    // 3-5. compressed K path (f32 — selection-critical)
    k_unfold<<<3844, 256, 0, stream>>>(p_qkv, pos_embed, p_big, 256);
    gemm(p_big, cmpk_w1, cmpk_b1, p_hid, 3844, 4096, 512, 1);
    gemm(p_hid, cmpk_w2, cmpk_b2, p_kc, 3844, 512, 256, 0);
    // 6-8. compressed V path (MFMA)
    k_unfold<<<3844, 256, 0, stream>>>(p_qkv, nullptr, p_big, 512);
    mgemm(p_big, t_v1, cmpv_b1, p_hid, 3844, 4096, 512, 1);
    mgemm(p_hid, t_v2, cmpv_b2, p_vc, 3844, 512, 256, 0);
    // 9. compressed attention + importance
    k_attn3<<<dim3(64,4,4), 256, 0, stream>>>(p_qkv, p_kc, p_vc, 961, p_oc, p_impp);
    k_imp_reduce<<<dim3(4,4), 256, 0, stream>>>(p_impp, p_imp);
    k_topk<<<4, 256, 0, stream>>>(p_imp, p_idx);
    // 10. out_cmp projection (MFMA)
    mgemm(p_oc, t_pc, proj_cmp_b, p_ocp, 16384, 256, 256, 0);
    // 11. qkv_slc (MFMA)
    mgemm(p_xs, t_qs, qkv_slc_b, p_qkv, 16384, 256, 768, 0);
    // 12-14. window branch
    k_xw<<<19600, 256, 0, stream>>>(p_xs, p_xw);
    mgemm(p_xw, t_wq, win_qkv_b, p_big, 19600, 256, 768, 0);
    k_attn_win<<<dim3(400,4), 64, 0, stream>>>(p_big, win_btab, p_xw);   // xw := owin_tok
    mgemm(p_xw, t_wp, win_proj_b, p_owp, 19600, 256, 256, 0);
    // 15-17. selected branch
    k_gather_sel<<<1024, 256, 0, stream>>>(p_qkv, p_idx, p_ks, p_vs);
    k_attn3<<<dim3(64,4,4), 256, 0, stream>>>(p_qkv, p_ks, p_vs, 256, p_oc, nullptr);
    mgemm(p_oc, t_ps, proj_slc_b, p_xw, 16384, 256, 256, 0);             // xw := out_slc
    // 18-19. gate
    mgemm(p_xs, t_g1, gate_b1, p_hid, 16384, 256, 64, 1);
    gemm(p_hid, gate_w2, gate_b2, p_g, 16384, 64, 3, 2);
    // 20. combine
    k_combine<<<dim3(128,8,4), dim3(32,8), 0, stream>>>(p_ocp, p_xw, p_owp, p_g,
                                                        (float*)d_out);
}

// Round 5
// 2259.085 us; speedup vs baseline: 2.0699x; 2.0699x over previous
//
#include <hip/hip_runtime.h>
#include <stdint.h>
#include <stddef.h>

// SpatialNSA on MI355X — round 5:
//  * cmp/slc attention re-cast as GEMMs: S = Q·K^T (f32 64x64-tile GEMM),
//    softmax+importance kernel (register-resident rows), PV = P·V (f32 GEMM).
//    S lives in the freed BIGA buffer, per-batch sequential.
//  * selection path (qkv_cmp, cmpk MLP, S_cmp, softmax, imp) stays f32.
//  * selection-safe GEMMs stay bf16 MFMA (round-3 machinery).

#define DEV __device__ __forceinline__

typedef __attribute__((ext_vector_type(8))) short short8;
typedef __attribute__((ext_vector_type(4))) float f32x4;

DEV unsigned short f2bf(float f){
    unsigned u = __float_as_uint(f);
    u += 0x7FFFu + ((u>>16)&1u);   // RNE
    return (unsigned short)(u>>16);
}

// ---------------- transpose: x (B,C,N) f32 -> xs (B,N,C) f32 -------------
__global__ void k_xs(const float* __restrict__ x, float* __restrict__ xs){
    __shared__ float t[32][33];
    int b = blockIdx.z; int c0 = blockIdx.y*32; int n0 = blockIdx.x*32;
    int tx = threadIdx.x, ty = threadIdx.y;            // (32,8)
    for(int i=ty;i<32;i+=8)
        t[i][tx] = x[((size_t)(b*256 + c0+i))*4096 + n0 + tx];
    __syncthreads();
    for(int i=ty;i<32;i+=8)
        xs[((size_t)(b*4096 + n0+i))*256 + c0 + tx] = t[tx][i];
}

// -------- weight transpose+cast: W (K,N) f32 -> WT (N,K) bf16 ---------------
__global__ void k_wt(const float* __restrict__ W, unsigned short* __restrict__ WT,
                     int K, int N){
    __shared__ float t[32][33];
    int k0 = blockIdx.x*32, n0 = blockIdx.y*32;
    int tx = threadIdx.x, ty = threadIdx.y;            // (32,8)
    for(int i=ty;i<32;i+=8)
        if(k0+i<K && n0+tx<N) t[i][tx] = W[(size_t)(k0+i)*N + n0+tx];
    __syncthreads();
    for(int i=ty;i<32;i+=8)
        if(n0+i<N && k0+tx<K) WT[(size_t)(n0+i)*K + k0+tx] = f2bf(t[tx][i]);
}

// ---------------- f32 GEMM: C = act(A(M,K) @ W(K,N) + bias) ------------------
// lda/ldw/ldc leading dims; per-z offsets zsA/zsW/zsC (elements). bias nullable.
__global__ __launch_bounds__(256) void k_gemm(
        const float* __restrict__ A, const float* __restrict__ W,
        const float* __restrict__ bias, float* __restrict__ C,
        int M, int K, int Nn, int lda, int ldw, int ldc, int act,
        long zsA, long zsW, long zsC)
{
    A += (size_t)blockIdx.z * zsA;
    W += (size_t)blockIdx.z * zsW;
    C += (size_t)blockIdx.z * zsC;
    __shared__ float As[16][68];
    __shared__ float Bs[16][64];
    const int m0 = blockIdx.y*64, n0 = blockIdx.x*64;
    const int t = threadIdx.x, tx = t&15, ty = t>>4;
    float acc[4][4] = {};
    const int am = t>>2;
    const int ak = (t&3)*4;
    const bool arow_ok = (m0+am) < M;

    for(int k0=0;k0<K;k0+=16){
        float4 av = make_float4(0.f,0.f,0.f,0.f);
        if(arow_ok) av = *reinterpret_cast<const float4*>(&A[(size_t)(m0+am)*lda + k0 + ak]);
        As[ak+0][am]=av.x; As[ak+1][am]=av.y; As[ak+2][am]=av.z; As[ak+3][am]=av.w;
        if((Nn & 3) == 0){
            int bn = (t&15)*4, bk = t>>4;
            float4 bv = make_float4(0.f,0.f,0.f,0.f);
            if(n0+bn < Nn)
                bv = *reinterpret_cast<const float4*>(&W[(size_t)(k0+bk)*ldw + n0+bn]);
            Bs[bk][bn]=bv.x; Bs[bk][bn+1]=bv.y; Bs[bk][bn+2]=bv.z; Bs[bk][bn+3]=bv.w;
        } else {
            int n = t&63, kb = t>>6;
            #pragma unroll
            for(int r=0;r<4;r++){
                int kk = r*4 + kb; float v = 0.f;
                if(n0+n < Nn) v = W[(size_t)(k0+kk)*ldw + n0+n];
                Bs[kk][n] = v;
            }
        }
        __syncthreads();
        #pragma unroll
        for(int kk=0;kk<16;kk++){
            float a0=As[kk][ty*4+0], a1=As[kk][ty*4+1], a2=As[kk][ty*4+2], a3=As[kk][ty*4+3];
            float b0=Bs[kk][tx*4+0], b1=Bs[kk][tx*4+1], b2=Bs[kk][tx*4+2], b3=Bs[kk][tx*4+3];
            acc[0][0]=fmaf(a0,b0,acc[0][0]); acc[0][1]=fmaf(a0,b1,acc[0][1]);
            acc[0][2]=fmaf(a0,b2,acc[0][2]); acc[0][3]=fmaf(a0,b3,acc[0][3]);
            acc[1][0]=fmaf(a1,b0,acc[1][0]); acc[1][1]=fmaf(a1,b1,acc[1][1]);
            acc[1][2]=fmaf(a1,b2,acc[1][2]); acc[1][3]=fmaf(a1,b3,acc[1][3]);
            acc[2][0]=fmaf(a2,b0,acc[2][0]); acc[2][1]=fmaf(a2,b1,acc[2][1]);
            acc[2][2]=fmaf(a2,b2,acc[2][2]); acc[2][3]=fmaf(a2,b3,acc[2][3]);
            acc[3][0]=fmaf(a3,b0,acc[3][0]); acc[3][1]=fmaf(a3,b1,acc[3][1]);
            acc[3][2]=fmaf(a3,b2,acc[3][2]); acc[3][3]=fmaf(a3,b3,acc[3][3]);
        }
        __syncthreads();
    }
    #pragma unroll
    for(int i=0;i<4;i++){
        int m = m0 + ty*4 + i;
        if(m >= M) continue;
        #pragma unroll
        for(int j=0;j<4;j++){
            int n = n0 + tx*4 + j;
            if(n >= Nn) continue;
            float v = acc[i][j] + (bias ? bias[n] : 0.f);
            if(act==1)      v = 0.5f*v*(1.0f + erff(v*0.70710678118654752f));
            else if(act==2) v = 1.0f/(1.0f + expf(-v));
            C[(size_t)m*ldc + n] = v;
        }
    }
}

// ---------------- f32 GEMM-NT: C = scale * A(M,K) @ B(N,K)^T -----------------
__global__ __launch_bounds__(256) void k_gemm_nt(
        const float* __restrict__ A, const float* __restrict__ B,
        float* __restrict__ C, int M, int N, int K,
        int lda, int ldb, int ldc, long zsA, long zsB, long zsC, float scale)
{
    A += (size_t)blockIdx.z * zsA;
    B += (size_t)blockIdx.z * zsB;
    C += (size_t)blockIdx.z * zsC;
    __shared__ float As[16][68];
    __shared__ float Bs[16][68];
    const int m0 = blockIdx.y*64, n0 = blockIdx.x*64;
    const int t = threadIdx.x, tx = t&15, ty = t>>4;
    float acc[4][4] = {};
    const int am = t>>2;           // 0..63
    const int ak = (t&3)*4;        // 0,4,8,12

    for(int k0=0;k0<K;k0+=16){
        float4 av = make_float4(0.f,0.f,0.f,0.f);
        if(m0+am < M) av = *reinterpret_cast<const float4*>(&A[(size_t)(m0+am)*lda + k0 + ak]);
        As[ak+0][am]=av.x; As[ak+1][am]=av.y; As[ak+2][am]=av.z; As[ak+3][am]=av.w;
        float4 bv = make_float4(0.f,0.f,0.f,0.f);
        if(n0+am < N) bv = *reinterpret_cast<const float4*>(&B[(size_t)(n0+am)*ldb + k0 + ak]);
        Bs[ak+0][am]=bv.x; Bs[ak+1][am]=bv.y; Bs[ak+2][am]=bv.z; Bs[ak+3][am]=bv.w;
        __syncthreads();
        #pragma unroll
        for(int kk=0;kk<16;kk++){
            float a0=As[kk][ty*4+0], a1=As[kk][ty*4+1], a2=As[kk][ty*4+2], a3=As[kk][ty*4+3];
            float b0=Bs[kk][tx*4+0], b1=Bs[kk][tx*4+1], b2=Bs[kk][tx*4+2], b3=Bs[kk][tx*4+3];
            acc[0][0]=fmaf(a0,b0,acc[0][0]); acc[0][1]=fmaf(a0,b1,acc[0][1]);
            acc[0][2]=fmaf(a0,b2,acc[0][2]); acc[0][3]=fmaf(a0,b3,acc[0][3]);
            acc[1][0]=fmaf(a1,b0,acc[1][0]); acc[1][1]=fmaf(a1,b1,acc[1][1]);
            acc[1][2]=fmaf(a1,b2,acc[1][2]); acc[1][3]=fmaf(a1,b3,acc[1][3]);
            acc[2][0]=fmaf(a2,b0,acc[2][0]); acc[2][1]=fmaf(a2,b1,acc[2][1]);
            acc[2][2]=fmaf(a2,b2,acc[2][2]); acc[2][3]=fmaf(a2,b3,acc[2][3]);
            acc[3][0]=fmaf(a3,b0,acc[3][0]); acc[3][1]=fmaf(a3,b1,acc[3][1]);
            acc[3][2]=fmaf(a3,b2,acc[3][2]); acc[3][3]=fmaf(a3,b3,acc[3][3]);
        }
        __syncthreads();
    }
    #pragma unroll
    for(int i=0;i<4;i++){
        int m = m0 + ty*4 + i;
        if(m >= M) continue;
        #pragma unroll
        for(int j=0;j<4;j++){
            int n = n0 + tx*4 + j;
            if(n >= N) continue;
            C[(size_t)m*ldc + n] = acc[i][j]*scale;
        }
    }
}

// ------------- softmax (+optional importance partials) over S rows -----------
// Block: 256 thr = 16 rows x 16 lanes. Grid: (4096/16, heads). NJ*16 = padded
// row width (== ld). Normalized probs written in place; pad cols get 0.
template<int NJ>
__global__ __launch_bounds__(256) void k_softmax(
    float* __restrict__ S, int ld, int NK, float* __restrict__ impp)
{
    const int qc = blockIdx.x, h = blockIdx.y;
    const int tid = threadIdx.x;
    const int r = tid >> 4, c = tid & 15;
    float* row = S + (size_t)h*4096*ld + (size_t)(qc*16 + r)*ld;
    float s[NJ];
    float m = -1e30f;
    #pragma unroll
    for(int j=0;j<NJ;j++){
        int k = c + j*16;
        s[j] = (k < NK) ? row[k] : -1e30f;
        m = fmaxf(m, s[j]);
    }
    m = fmaxf(m, __shfl_xor(m, 1));
    m = fmaxf(m, __shfl_xor(m, 2));
    m = fmaxf(m, __shfl_xor(m, 4));
    m = fmaxf(m, __shfl_xor(m, 8));
    float l = 0.f;
    #pragma unroll
    for(int j=0;j<NJ;j++){ s[j] = __expf(s[j] - m); l += s[j]; }
    l += __shfl_xor(l, 1);
    l += __shfl_xor(l, 2);
    l += __shfl_xor(l, 4);
    l += __shfl_xor(l, 8);
    const float inv = 1.f / l;
    #pragma unroll
    for(int j=0;j<NJ;j++){
        row[c + j*16] = s[j]*inv;   // pad lanes: exp(-1e30-m)=0 -> writes 0
    }
    if(impp){
        __syncthreads();           // P of all 16 rows visible to block
        int k4 = tid*4;
        if(k4 < NJ*16){
            const float* base = S + (size_t)h*4096*ld + (size_t)(qc*16)*ld + k4;
            float4 acc = make_float4(0.f,0.f,0.f,0.f);
            #pragma unroll
            for(int rr=0; rr<16; rr++){
                float4 v = *reinterpret_cast<const float4*>(base + (size_t)rr*ld);
                acc.x+=v.x; acc.y+=v.y; acc.z+=v.z; acc.w+=v.w;
            }
            *reinterpret_cast<float4*>(&impp[(size_t)(h*256 + qc)*976 + k4]) = acc;
        }
    }
}

// ---------------- bf16 MFMA GEMM: C = act(A(M,K f32) @ W + bias) -------------
__global__ __launch_bounds__(256) void k_gemm_mfma(
        const float* __restrict__ A, const unsigned short* __restrict__ WT,
        const float* __restrict__ bias, float* __restrict__ C,
        int M, int K, int Nn, int act)
{
    __shared__ unsigned short Al[128*64];
    __shared__ unsigned short Bl[128*64];
    const int m0 = blockIdx.y*128, n0 = blockIdx.x*128;
    const int tid = threadIdx.x, lane = tid&63, wv = tid>>6;
    const int wm = (wv>>1)*64, wn = (wv&1)*64;
    f32x4 acc[4][4] = {};

    const int srow = tid>>1;
    const int sks  = (tid&1)*32;

    for(int kt=0; kt<K; kt+=64){
        {
            const bool ok = (m0+srow) < M;
            const float* src = &A[(size_t)(m0+srow)*K + kt + sks];
            #pragma unroll
            for(int c=0;c<4;c++){
                float4 v0 = make_float4(0,0,0,0), v1 = v0;
                if(ok){
                    v0 = *reinterpret_cast<const float4*>(src + c*8);
                    v1 = *reinterpret_cast<const float4*>(src + c*8 + 4);
                }
                short8 s;
                s[0]=(short)f2bf(v0.x); s[1]=(short)f2bf(v0.y);
                s[2]=(short)f2bf(v0.z); s[3]=(short)f2bf(v0.w);
                s[4]=(short)f2bf(v1.x); s[5]=(short)f2bf(v1.y);
                s[6]=(short)f2bf(v1.z); s[7]=(short)f2bf(v1.w);
                int byteoff = srow*128 + ((sks*2 + c*16) ^ ((srow&7)<<4));
                *reinterpret_cast<short8*>(reinterpret_cast<char*>(Al) + byteoff) = s;
            }
        }
        {
            const bool ok = (n0+srow) < Nn;
            const unsigned short* src = &WT[(size_t)(n0+srow)*K + kt + sks];
            #pragma unroll
            for(int c=0;c<4;c++){
                short8 s = {};
                if(ok) s = *reinterpret_cast<const short8*>(src + c*8);
                int byteoff = srow*128 + ((sks*2 + c*16) ^ ((srow&7)<<4));
                *reinterpret_cast<short8*>(reinterpret_cast<char*>(Bl) + byteoff) = s;
            }
        }
        __syncthreads();
        #pragma unroll
        for(int kb=0;kb<2;kb++){
            short8 af[4], bfr[4];
            #pragma unroll
            for(int i=0;i<4;i++){
                int ar = wm + i*16 + (lane&15);
                int abyte = ar*128 + (((kb*64) + ((lane>>4)*16)) ^ ((ar&7)<<4));
                af[i] = *reinterpret_cast<const short8*>(reinterpret_cast<const char*>(Al) + abyte);
                int br = wn + i*16 + (lane&15);
                int bbyte = br*128 + (((kb*64) + ((lane>>4)*16)) ^ ((br&7)<<4));
                bfr[i] = *reinterpret_cast<const short8*>(reinterpret_cast<const char*>(Bl) + bbyte);
            }
            #pragma unroll
            for(int mi=0;mi<4;mi++)
                #pragma unroll
                for(int ni=0;ni<4;ni++)
                    acc[mi][ni] = __builtin_amdgcn_mfma_f32_16x16x32_bf16(
                                      af[mi], bfr[ni], acc[mi][ni], 0, 0, 0);
        }
        __syncthreads();
    }
    #pragma unroll
    for(int mi=0;mi<4;mi++){
        #pragma unroll
        for(int ni=0;ni<4;ni++){
            int col = n0 + wn + ni*16 + (lane&15);
            if(col >= Nn) continue;
            int rowb = m0 + wm + mi*16 + ((lane>>4)*4);
            float bv = bias[col];
            #pragma unroll
            for(int r=0;r<4;r++){
                int m = rowb + r;
                if(m >= M) continue;
                float v = acc[mi][ni][r] + bv;
                if(act==1)      v = 0.5f*v*(1.0f + erff(v*0.70710678118654752f));
                else if(act==2) v = 1.0f/(1.0f + expf(-v));
                C[(size_t)m*Nn + col] = v;
            }
        }
    }
}

// ------------- unfold (CBS=4, stride 2) with torch-quirk flat order -----------
__global__ void k_unfold(const float* __restrict__ qkv, const float* __restrict__ pos,
                         float* __restrict__ outA, int chanBase){
    int row = blockIdx.x;                 // 0..3843
    int b = row / 961, blk = row % 961;
    int bi = blk / 31, bj = blk % 31;
    for(int j = threadIdx.x; j < 4096; j += 256){
        int ch = j >> 4;
        int kh = (j >> 2) & 3, kw = j & 3;
        int n = (bi*2 + kh)*64 + (bj*2 + kw);
        float v = qkv[((size_t)(b*4096) + n)*768 + chanBase + ch];
        if(pos) v += pos[j];
        outA[(size_t)row*4096 + j] = v;
    }
}

// ------------- deterministic importance reduce -------------------------------
// impp: per-b 1024 rows x 976 cols. Each block: 64 k-cols, 4-way row split.
__global__ void k_imp_reduce(const float* __restrict__ impp, float* __restrict__ imp){
    __shared__ float part[4][64];
    int b = blockIdx.y;
    int k = blockIdx.x*64 + (threadIdx.x & 63);
    int rr = threadIdx.x >> 6;
    float s = 0.f;
    for(int r=rr; r<1024; r+=4)
        s += impp[((size_t)(b*1024) + r)*976 + k];
    part[rr][threadIdx.x & 63] = s;
    __syncthreads();
    if(threadIdx.x < 64 && k < 961){
        float t = ((part[0][threadIdx.x] + part[1][threadIdx.x])
                 + part[2][threadIdx.x]) + part[3][threadIdx.x];
        imp[b*961 + k] = t;
    }
}

// ------------- top-16 with lowest-index tie-break ----------------------------
__global__ void k_topk(const float* __restrict__ imp, int* __restrict__ idx){
    int b = blockIdx.x;
    __shared__ float v[961];
    __shared__ float bestv[256];
    __shared__ int   besti[256];
    int t = threadIdx.x;
    for(int i=t;i<961;i+=256) v[i] = imp[b*961+i];
    __syncthreads();
    for(int it=0; it<16; it++){
        float bv = -1e30f; int bi = 0;
        for(int i=t;i<961;i+=256){
            if(v[i] > bv){ bv=v[i]; bi=i; }
        }
        bestv[t]=bv; besti[t]=bi;
        __syncthreads();
        if(t==0){
            float gb=-1e30f; int gi=0;
            for(int i=0;i<256;i++){
                if(bestv[i]>gb || (bestv[i]==gb && besti[i]<gi)){ gb=bestv[i]; gi=besti[i]; }
            }
            idx[b*16+it] = gi;
            v[gi] = -1e30f;
        }
        __syncthreads();
    }
}

// ------------- gather selected K/V (quirk layout, clip to 255) ----------------
__global__ void k_gather_sel(const float* __restrict__ qkv2, const int* __restrict__ idx,
                             float* __restrict__ Ks, float* __restrict__ Vs){
    int row = blockIdx.x;            // b*256 + t ; t = sel*16 + p
    int b = row >> 8, tt = row & 255;
    int sel = tt >> 4, p = tt & 15;
    int blk = idx[b*16+sel]; if(blk > 255) blk = 255;
    int bi = blk >> 4, bj = blk & 15;
    int cc = threadIdx.x;
    int y = bi*4 + ((cc>>2)&3), xx = bj*4 + (cc&3);
    int ch = p*16 + (cc>>4);
    size_t src = ((size_t)(b*4096) + y*64 + xx)*768;
    Ks[(size_t)row*256 + cc] = qkv2[src + 256 + ch];
    Vs[(size_t)row*256 + cc] = qkv2[src + 512 + ch];
}

// ------------- build padded window tokens xw (400*49, 256) -------------------
__global__ void k_xw(const float* __restrict__ xs, float* __restrict__ xw){
    int row = blockIdx.x;             // wb*49 + t
    int wb = row / 49, t = row % 49;
    int b = wb / 100, wrem = wb % 100;
    int wy = wrem / 10, wx = wrem % 10;
    int ty = t / 7, tx = t % 7;
    int y = wy*7 + ty, xx = wx*7 + tx;
    int c = threadIdx.x;
    float v = 0.f;
    if(y < 64 && xx < 64) v = xs[((size_t)(b*4096) + y*64 + xx)*256 + c];
    xw[(size_t)row*256 + c] = v;
}

// ------------- window attention: 49 tokens, rel-pos bias ---------------------
__global__ __launch_bounds__(64) void k_attn_win(
    const float* __restrict__ qkvw, const float* __restrict__ btab,
    float* __restrict__ outp)
{
    const int wb = blockIdx.x, h = blockIdx.y;
    const int lane = threadIdx.x;
    __shared__ float lk[49][64];
    __shared__ float lv[49][64];
    __shared__ float ls[49][51];
    __shared__ float lbias[169];
    for(int i=lane;i<169;i+=64) lbias[i] = btab[i*4 + h];
    for(int r=0;r<49;r++){
        lk[r][lane] = qkvw[((size_t)(wb*49 + r))*768 + 256 + h*64 + lane];
        lv[r][lane] = qkvw[((size_t)(wb*49 + r))*768 + 512 + h*64 + lane];
    }
    __syncthreads();
    if(lane < 49){
        const float* qptr = &qkvw[((size_t)(wb*49 + lane))*768 + h*64];
        float qreg[64];
        #pragma unroll
        for(int d=0;d<64;++d) qreg[d] = qptr[d];
        int ih = lane/7, iw = lane%7;
        float m = -1e30f;
        for(int j=0;j<49;j++){
            float s0=0,s1=0,s2=0,s3=0;
            #pragma unroll
            for(int d=0; d<64; d+=4){
                s0 = fmaf(qreg[d+0], lk[j][d+0], s0);
                s1 = fmaf(qreg[d+1], lk[j][d+1], s1);
                s2 = fmaf(qreg[d+2], lk[j][d+2], s2);
                s3 = fmaf(qreg[d+3], lk[j][d+3], s3);
            }
            int jh=j/7, jw=j%7;
            float s = ((s0+s1)+(s2+s3))*0.125f + lbias[(ih-jh+6)*13 + (iw-jw+6)];
            ls[lane][j] = s;
            m = fmaxf(m, s);
        }
        float l = 0.f;
        for(int j=0;j<49;j++){ float p = __expf(ls[lane][j] - m); ls[lane][j] = p; l += p; }
        float inv = 1.f/l;
        float* op = &outp[((size_t)(wb*49 + lane))*256 + h*64];
        for(int d=0;d<64;d++){
            float a0=0,a1=0;
            for(int j=0;j<48;j+=2){
                a0 = fmaf(ls[lane][j],   lv[j][d],   a0);
                a1 = fmaf(ls[lane][j+1], lv[j+1][d], a1);
            }
            a0 = fmaf(ls[lane][48], lv[48][d], a0);
            op[d] = (a0+a1)*inv;
        }
    }
}

// ------------- final gated combine + transpose to (B,C,H,W) f32 -------------
__global__ void k_combine(const float* __restrict__ ocp, const float* __restrict__ osp,
                          const float* __restrict__ owp, const float* __restrict__ g,
                          float* __restrict__ out){
    __shared__ float tile[32][33];
    int b = blockIdx.z; int c0 = blockIdx.y*32, n0 = blockIdx.x*32;
    int tx = threadIdx.x, ty = threadIdx.y;    // (32,8)
    for(int i=ty;i<32;i+=8){
        int n = n0 + i;
        float g0 = g[(size_t)(b*4096+n)*3 + 0];
        float g1 = g[(size_t)(b*4096+n)*3 + 1];
        float g2 = g[(size_t)(b*4096+n)*3 + 2];
        int y = n >> 6, xx = n & 63;
        int wy = y/7, ty2 = y%7, wx = xx/7, tx2 = xx%7;
        size_t wrow = (size_t)(b*100 + wy*10 + wx)*49 + ty2*7 + tx2;
        size_t base = ((size_t)(b*4096) + n)*256 + c0;
        float vc = ocp[base + tx];
        float vs = osp[base + tx];
        float vw = owp[wrow*256 + c0 + tx];
        tile[i][tx] = g0*vc + g1*vs + g2*vw;
    }
    __syncthreads();
    for(int i=ty;i<32;i+=8)
        out[((size_t)(b*256 + c0+i))*4096 + n0 + tx] = tile[tx][i];
}

// =============================== host side ===================================
extern "C" void kernel_launch(void* const* d_in, const int* in_sizes, int n_in,
                              void* d_out, int out_size, void* d_ws, size_t ws_size,
                              hipStream_t stream)
{
    typedef const float* fp;
    fp x          = (fp)d_in[0];
    fp qkv_cmp_w  = (fp)d_in[1];  fp qkv_cmp_b = (fp)d_in[2];
    fp qkv_slc_w  = (fp)d_in[3];  fp qkv_slc_b = (fp)d_in[4];
    fp cmpk_w1    = (fp)d_in[5];  fp cmpk_b1   = (fp)d_in[6];
    fp cmpk_w2    = (fp)d_in[7];  fp cmpk_b2   = (fp)d_in[8];
    fp cmpv_w1    = (fp)d_in[9];  fp cmpv_b1   = (fp)d_in[10];
    fp cmpv_w2    = (fp)d_in[11]; fp cmpv_b2   = (fp)d_in[12];
    fp pos_embed  = (fp)d_in[13];
    fp win_qkv_w  = (fp)d_in[14]; fp win_qkv_b = (fp)d_in[15];
    fp win_proj_w = (fp)d_in[16]; fp win_proj_b= (fp)d_in[17];
    fp win_btab   = (fp)d_in[18];
    fp proj_cmp_w = (fp)d_in[19]; fp proj_cmp_b= (fp)d_in[20];
    fp proj_slc_w = (fp)d_in[21]; fp proj_slc_b= (fp)d_in[22];
    fp gate_w1    = (fp)d_in[23]; fp gate_b1   = (fp)d_in[24];
    fp gate_w2    = (fp)d_in[25]; fp gate_b2   = (fp)d_in[26];
    (void)in_sizes; (void)n_in; (void)out_size;

    char* ws = (char*)d_ws;
    size_t off = 0;
    auto alloc = [&](size_t bytes)->size_t{
        size_t r = off; off += (bytes + 255) & ~(size_t)255; return r;
    };
    const size_t XS   = alloc((size_t)16384*256*4);
    const size_t QKV  = alloc((size_t)16384*768*4);
    const size_t BIGA = alloc((size_t)4*4096*976*4);     // fk/fv/qkvw AND S (64 MB)
    const size_t HID  = alloc((size_t)3844*512*4);
    const size_t KC   = alloc((size_t)3844*256*4);
    const size_t VC   = alloc((size_t)(3844+16)*256*4);  // +16 row slack (PV K-pad)
    const size_t OC   = alloc((size_t)16384*256*4);
    const size_t IMPP = alloc((size_t)4096*976*4);
    const size_t IMP  = alloc((size_t)4*961*4);
    const size_t IDX  = alloc((size_t)4*16*4);
    const size_t OCP  = alloc((size_t)16384*256*4);
    const size_t XW   = alloc((size_t)19600*256*4);
    const size_t OWP  = alloc((size_t)19600*256*4);
    const size_t KS   = alloc((size_t)4*256*256*4);
    const size_t VS   = alloc((size_t)4*256*256*4);
    const size_t G2   = alloc((size_t)16384*3*4);
    const size_t TQS  = alloc((size_t)768*256*2);
    const size_t TWQ  = alloc((size_t)768*256*2);
    const size_t TV1  = alloc((size_t)512*4096*2);
    const size_t TV2  = alloc((size_t)256*512*2);
    const size_t TPC  = alloc((size_t)256*256*2);
    const size_t TPS  = alloc((size_t)256*256*2);
    const size_t TWP  = alloc((size_t)256*256*2);
    const size_t TG1  = alloc((size_t)64*256*2);
    if(off > ws_size) return;

    float* p_xs  = (float*)(ws + XS);
    float* p_qkv = (float*)(ws + QKV);
    float* p_big = (float*)(ws + BIGA);
    float* p_hid = (float*)(ws + HID);
    float* p_kc  = (float*)(ws + KC);
    float* p_vc  = (float*)(ws + VC);
    float* p_oc  = (float*)(ws + OC);
    float* p_impp= (float*)(ws + IMPP);
    float* p_imp = (float*)(ws + IMP);
    int*   p_idx = (int*)  (ws + IDX);
    float* p_ocp = (float*)(ws + OCP);
    float* p_xw  = (float*)(ws + XW);
    float* p_owp = (float*)(ws + OWP);
    float* p_ks  = (float*)(ws + KS);
    float* p_vs  = (float*)(ws + VS);
    float* p_g   = (float*)(ws + G2);
    unsigned short* t_qs = (unsigned short*)(ws + TQS);
    unsigned short* t_wq = (unsigned short*)(ws + TWQ);
    unsigned short* t_v1 = (unsigned short*)(ws + TV1);
    unsigned short* t_v2 = (unsigned short*)(ws + TV2);
    unsigned short* t_pc = (unsigned short*)(ws + TPC);
    unsigned short* t_ps = (unsigned short*)(ws + TPS);
    unsigned short* t_wp = (unsigned short*)(ws + TWP);
    unsigned short* t_g1 = (unsigned short*)(ws + TG1);

    auto gemm = [&](const float* A, fp W, fp bias, float* Cc, int M, int K, int Nn, int act){
        dim3 g((Nn+63)/64, (M+63)/64);
        k_gemm<<<g, 256, 0, stream>>>(A, W, bias, Cc, M, K, Nn, K, Nn, Nn, act, 0, 0, 0);
    };
    auto wt = [&](fp W, unsigned short* WT, int K, int Nn){
        k_wt<<<dim3(K/32, Nn/32), dim3(32,8), 0, stream>>>(W, WT, K, Nn);
    };
    auto mgemm = [&](const float* A, const unsigned short* WT, fp bias, float* Cc,
                     int M, int K, int Nn, int act){
        dim3 g((Nn+127)/128, (M+127)/128);
        k_gemm_mfma<<<g, 256, 0, stream>>>(A, WT, bias, Cc, M, K, Nn, act);
    };

    // 0. transposed bf16 weights (selection-safe gemms)
    wt(qkv_slc_w, t_qs, 256, 768);
    wt(win_qkv_w, t_wq, 256, 768);
    wt(cmpv_w1,   t_v1, 4096, 512);
    wt(cmpv_w2,   t_v2, 512, 256);
    wt(proj_cmp_w,t_pc, 256, 256);
    wt(proj_slc_w,t_ps, 256, 256);
    wt(win_proj_w,t_wp, 256, 256);
    wt(gate_w1,   t_g1, 256, 64);

    // 1. xs = transpose(x)
    k_xs<<<dim3(128,8,4), dim3(32,8), 0, stream>>>(x, p_xs);
    // 2. qkv_cmp (f32 — selection-critical)
    gemm(p_xs, qkv_cmp_w, qkv_cmp_b, p_qkv, 16384, 256, 768, 0);
    // 3-5. compressed K path (f32 — selection-critical)
    k_unfold<<<3844, 256, 0, stream>>>(p_qkv, pos_embed, p_big, 256);
    gemm(p_big, cmpk_w1, cmpk_b1, p_hid, 3844, 4096, 512, 1);
    gemm(p_hid, cmpk_w2, cmpk_b2, p_kc, 3844, 512, 256, 0);
    // 6-8. compressed V path (MFMA)
    k_unfold<<<3844, 256, 0, stream>>>(p_qkv, nullptr, p_big, 512);
    mgemm(p_big, t_v1, cmpv_b1, p_hid, 3844, 4096, 512, 1);
    mgemm(p_hid, t_v2, cmpv_b2, p_vc, 3844, 512, 256, 0);
    // 9. compressed attention as GEMMs, per batch (S reuses BIGA, 64 MB)
    for(int b=0;b<4;b++){
        // S[h][q][k] = 0.125 * Q · K^T   (f32)
        k_gemm_nt<<<dim3(16,64,4), 256, 0, stream>>>(
            p_qkv + (size_t)b*4096*768, p_kc + (size_t)b*961*256, p_big,
            4096, 961, 64, 768, 256, 976,
            64, 64, (long)4096*976, 0.125f);
        // softmax rows + importance partials
        k_softmax<61><<<dim3(256,4), 256, 0, stream>>>(
            p_big, 976, 961, p_impp + (size_t)b*1024*976);
        // out = P · V   (f32)
        k_gemm<<<dim3(1,64,4), 256, 0, stream>>>(
            p_big, p_vc + (size_t)b*961*256, nullptr, p_oc + (size_t)b*4096*256,
            4096, 976, 64, 976, 256, 256, 0,
            (long)4096*976, 64, 64);
    }
    k_imp_reduce<<<dim3(16,4), 256, 0, stream>>>(p_impp, p_imp);
    k_topk<<<4, 256, 0, stream>>>(p_imp, p_idx);
    // 10. out_cmp projection (MFMA)
    mgemm(p_oc, t_pc, proj_cmp_b, p_ocp, 16384, 256, 256, 0);
    // 11. qkv_slc (MFMA)
    mgemm(p_xs, t_qs, qkv_slc_b, p_qkv, 16384, 256, 768, 0);
    // 12-14. window branch (qkvw reuses BIGA)
    k_xw<<<19600, 256, 0, stream>>>(p_xs, p_xw);
    mgemm(p_xw, t_wq, win_qkv_b, p_big, 19600, 256, 768, 0);
    k_attn_win<<<dim3(400,4), 64, 0, stream>>>(p_big, win_btab, p_xw);   // xw := owin_tok
    mgemm(p_xw, t_wp, win_proj_b, p_owp, 19600, 256, 256, 0);
    // 15-17. selected branch as GEMMs (S_slc reuses BIGA, 16.8 MB)
    k_gather_sel<<<1024, 256, 0, stream>>>(p_qkv, p_idx, p_ks, p_vs);
    for(int b=0;b<4;b++){
        k_gemm_nt<<<dim3(4,64,4), 256, 0, stream>>>(
            p_qkv + (size_t)b*4096*768, p_ks + (size_t)b*256*256, p_big,
            4096, 256, 64, 768, 256, 256,
            64, 64, (long)4096*256, 0.125f);
        k_softmax<16><<<dim3(256,4), 256, 0, stream>>>(
            p_big, 256, 256, nullptr);
        k_gemm<<<dim3(1,64,4), 256, 0, stream>>>(
            p_big, p_vs + (size_t)b*256*256, nullptr, p_oc + (size_t)b*4096*256,
            4096, 256, 64, 256, 256, 256, 0,
            (long)4096*256, 64, 64);
    }
    mgemm(p_oc, t_ps, proj_slc_b, p_xw, 16384, 256, 256, 0);             // xw := out_slc
    // 18-19. gate
    mgemm(p_xs, t_g1, gate_b1, p_hid, 16384, 256, 64, 1);
    gemm(p_hid, gate_w2, gate_b2, p_g, 16384, 64, 3, 2);
    // 20. combine
    k_combine<<<dim3(128,8,4), dim3(32,8), 0, stream>>>(p_ocp, p_xw, p_owp, p_g,
                                                        (float*)d_out);
}

// Round 6
// 1972.061 us; speedup vs baseline: 2.3712x; 1.1455x over previous
//
#include <hip/hip_runtime.h>
#include <stdint.h>
#include <stddef.h>

// SpatialNSA on MI355X — round 6:
//  * split-bf16 MFMA (3-term, ~1e-5 rel err) replaces ALL remaining f32 GEMMs
//    on the selection-critical path (qkv_cmp, cmpk MLP) and the QK^T GEMMs.
//  * k_mgs<WM,WN,BPAIR>: generalized round-3 MFMA kernel; 64x64 or 128x128
//    tiles; B from f32 NT rows or pre-split bf16 weight pairs.
//  * PV stays f32 k_gemm; softmax/topk/gather/window/combine unchanged.

#define DEV __device__ __forceinline__

typedef __attribute__((ext_vector_type(8))) short short8;
typedef __attribute__((ext_vector_type(4))) float f32x4;

DEV unsigned short f2bf(float f){
    unsigned u = __float_as_uint(f);
    u += 0x7FFFu + ((u>>16)&1u);   // RNE
    return (unsigned short)(u>>16);
}
DEV float bf2f(unsigned short u){ return __uint_as_float(((unsigned)u)<<16); }

// ---------------- transpose: x (B,C,N) f32 -> xs (B,N,C) f32 -------------
__global__ void k_xs(const float* __restrict__ x, float* __restrict__ xs){
    __shared__ float t[32][33];
    int b = blockIdx.z; int c0 = blockIdx.y*32; int n0 = blockIdx.x*32;
    int tx = threadIdx.x, ty = threadIdx.y;            // (32,8)
    for(int i=ty;i<32;i+=8)
        t[i][tx] = x[((size_t)(b*256 + c0+i))*4096 + n0 + tx];
    __syncthreads();
    for(int i=ty;i<32;i+=8)
        xs[((size_t)(b*4096 + n0+i))*256 + c0 + tx] = t[tx][i];
}

// -------- weight transpose+cast: W (K,N) f32 -> WT (N,K) bf16 ---------------
__global__ void k_wt(const float* __restrict__ W, unsigned short* __restrict__ WT,
                     int K, int N){
    __shared__ float t[32][33];
    int k0 = blockIdx.x*32, n0 = blockIdx.y*32;
    int tx = threadIdx.x, ty = threadIdx.y;            // (32,8)
    for(int i=ty;i<32;i+=8)
        if(k0+i<K && n0+tx<N) t[i][tx] = W[(size_t)(k0+i)*N + n0+tx];
    __syncthreads();
    for(int i=ty;i<32;i+=8)
        if(n0+i<N && k0+tx<K) WT[(size_t)(n0+i)*K + k0+tx] = f2bf(t[tx][i]);
}

// -------- split weight transpose: W (K,N) f32 -> (N,K) bf16 hi + lo ---------
__global__ void k_wt2(const float* __restrict__ W, unsigned short* __restrict__ Hi,
                      unsigned short* __restrict__ Lo, int K, int N){
    __shared__ float t[32][33];
    int k0 = blockIdx.x*32, n0 = blockIdx.y*32;
    int tx = threadIdx.x, ty = threadIdx.y;
    for(int i=ty;i<32;i+=8)
        if(k0+i<K && n0+tx<N) t[i][tx] = W[(size_t)(k0+i)*N + n0+tx];
    __syncthreads();
    for(int i=ty;i<32;i+=8)
        if(n0+i<N && k0+tx<K){
            float v = t[tx][i];
            unsigned short h = f2bf(v);
            unsigned short l = f2bf(v - bf2f(h));
            Hi[(size_t)(n0+i)*K + k0+tx] = h;
            Lo[(size_t)(n0+i)*K + k0+tx] = l;
        }
}

// ---------------- f32 GEMM (PV + tiny gate) ----------------------------------
__global__ __launch_bounds__(256) void k_gemm(
        const float* __restrict__ A, const float* __restrict__ W,
        const float* __restrict__ bias, float* __restrict__ C,
        int M, int K, int Nn, int lda, int ldw, int ldc, int act,
        long zsA, long zsW, long zsC)
{
    A += (size_t)blockIdx.z * zsA;
    W += (size_t)blockIdx.z * zsW;
    C += (size_t)blockIdx.z * zsC;
    __shared__ float As[16][68];
    __shared__ float Bs[16][64];
    const int m0 = blockIdx.y*64, n0 = blockIdx.x*64;
    const int t = threadIdx.x, tx = t&15, ty = t>>4;
    float acc[4][4] = {};
    const int am = t>>2;
    const int ak = (t&3)*4;
    const bool arow_ok = (m0+am) < M;

    for(int k0=0;k0<K;k0+=16){
        float4 av = make_float4(0.f,0.f,0.f,0.f);
        if(arow_ok) av = *reinterpret_cast<const float4*>(&A[(size_t)(m0+am)*lda + k0 + ak]);
        As[ak+0][am]=av.x; As[ak+1][am]=av.y; As[ak+2][am]=av.z; As[ak+3][am]=av.w;
        if((Nn & 3) == 0){
            int bn = (t&15)*4, bk = t>>4;
            float4 bv = make_float4(0.f,0.f,0.f,0.f);
            if(n0+bn < Nn)
                bv = *reinterpret_cast<const float4*>(&W[(size_t)(k0+bk)*ldw + n0+bn]);
            Bs[bk][bn]=bv.x; Bs[bk][bn+1]=bv.y; Bs[bk][bn+2]=bv.z; Bs[bk][bn+3]=bv.w;
        } else {
            int n = t&63, kb = t>>6;
            #pragma unroll
            for(int r=0;r<4;r++){
                int kk = r*4 + kb; float v = 0.f;
                if(n0+n < Nn) v = W[(size_t)(k0+kk)*ldw + n0+n];
                Bs[kk][n] = v;
            }
        }
        __syncthreads();
        #pragma unroll
        for(int kk=0;kk<16;kk++){
            float a0=As[kk][ty*4+0], a1=As[kk][ty*4+1], a2=As[kk][ty*4+2], a3=As[kk][ty*4+3];
            float b0=Bs[kk][tx*4+0], b1=Bs[kk][tx*4+1], b2=Bs[kk][tx*4+2], b3=Bs[kk][tx*4+3];
            acc[0][0]=fmaf(a0,b0,acc[0][0]); acc[0][1]=fmaf(a0,b1,acc[0][1]);
            acc[0][2]=fmaf(a0,b2,acc[0][2]); acc[0][3]=fmaf(a0,b3,acc[0][3]);
            acc[1][0]=fmaf(a1,b0,acc[1][0]); acc[1][1]=fmaf(a1,b1,acc[1][1]);
            acc[1][2]=fmaf(a1,b2,acc[1][2]); acc[1][3]=fmaf(a1,b3,acc[1][3]);
            acc[2][0]=fmaf(a2,b0,acc[2][0]); acc[2][1]=fmaf(a2,b1,acc[2][1]);
            acc[2][2]=fmaf(a2,b2,acc[2][2]); acc[2][3]=fmaf(a2,b3,acc[2][3]);
            acc[3][0]=fmaf(a3,b0,acc[3][0]); acc[3][1]=fmaf(a3,b1,acc[3][1]);
            acc[3][2]=fmaf(a3,b2,acc[3][2]); acc[3][3]=fmaf(a3,b3,acc[3][3]);
        }
        __syncthreads();
    }
    #pragma unroll
    for(int i=0;i<4;i++){
        int m = m0 + ty*4 + i;
        if(m >= M) continue;
        #pragma unroll
        for(int j=0;j<4;j++){
            int n = n0 + tx*4 + j;
            if(n >= Nn) continue;
            float v = acc[i][j] + (bias ? bias[n] : 0.f);
            if(act==1)      v = 0.5f*v*(1.0f + erff(v*0.70710678118654752f));
            else if(act==2) v = 1.0f/(1.0f + expf(-v));
            C[(size_t)m*ldc + n] = v;
        }
    }
}

// ============ split-bf16 MFMA GEMM: C = scale*(A @ B^T) [+bias][act] =========
// A: f32 (M x K, lda). B: BPAIR ? pre-split bf16 [N][K] hi/lo : f32 [N][K] ldb.
// 3-term split product => ~f32 accuracy. Tile 32WM x 32WN, BK=64, 4 waves 2x2.
template<int WM, int WN, int BPAIR>
__global__ __launch_bounds__(256) void k_mgs(
        const float* __restrict__ A, const float* __restrict__ Bf,
        const unsigned short* __restrict__ Bh, const unsigned short* __restrict__ Blo_,
        const float* __restrict__ bias, float* __restrict__ C,
        int M, int N, int K, int lda, int ldb, int ldc, int act, float scale,
        long zsA, long zsB, long zsC)
{
    constexpr int BM = 32*WM, BN = 32*WN;
    A += (size_t)blockIdx.z * zsA;
    if(BPAIR==0 && Bf) Bf += (size_t)blockIdx.z * zsB;
    C += (size_t)blockIdx.z * zsC;

    __shared__ unsigned short Ahi[BM*64], Alo[BM*64];
    __shared__ unsigned short Bhi[BN*64], Blo[BN*64];

    const int m0 = blockIdx.y*BM, n0 = blockIdx.x*BN;
    const int tid = threadIdx.x, lane = tid&63, wv = tid>>6;
    const int wm = (wv>>1)*(16*WM), wn = (wv&1)*(16*WN);
    f32x4 acc[WM][WN] = {};

    constexpr int TPR_A = 256/BM;          // threads per A row (2 or 4)
    constexpr int CH_A  = 8/TPR_A;         // 16B chunks per thread
    const int arow = tid / TPR_A;
    const int acol0 = (tid % TPR_A)*(128/TPR_A);   // byte base in 128B row
    constexpr int TPR_B = 256/BN;
    constexpr int CH_B  = 8/TPR_B;
    const int brow = tid / TPR_B;
    const int bcol0 = (tid % TPR_B)*(128/TPR_B);

    for(int kt=0; kt<K; kt+=64){
        // ---- stage A (f32 -> hi/lo bf16, swizzled) ----
        {
            const bool ok = (m0+arow) < M;
            #pragma unroll
            for(int c=0;c<CH_A;c++){
                int colbyte = acol0 + c*16;
                int e = colbyte>>1;            // element offset 0..56
                float4 v0 = make_float4(0,0,0,0), v1 = v0;
                if(ok){
                    const float* src = &A[(size_t)(m0+arow)*lda + kt + e];
                    v0 = *reinterpret_cast<const float4*>(src);
                    v1 = *reinterpret_cast<const float4*>(src+4);
                }
                short8 h, l;
                float vv[8] = {v0.x,v0.y,v0.z,v0.w,v1.x,v1.y,v1.z,v1.w};
                #pragma unroll
                for(int j=0;j<8;j++){
                    unsigned short hb = f2bf(vv[j]);
                    h[j] = (short)hb;
                    l[j] = (short)f2bf(vv[j] - bf2f(hb));
                }
                int byteoff = arow*128 + (colbyte ^ ((arow&7)<<4));
                *reinterpret_cast<short8*>(reinterpret_cast<char*>(Ahi)+byteoff) = h;
                *reinterpret_cast<short8*>(reinterpret_cast<char*>(Alo)+byteoff) = l;
            }
        }
        // ---- stage B ----
        {
            const bool ok = (n0+brow) < N;
            #pragma unroll
            for(int c=0;c<CH_B;c++){
                int colbyte = bcol0 + c*16;
                int e = colbyte>>1;
                short8 h = {}, l = {};
                if(ok){
                    if(BPAIR){
                        h = *reinterpret_cast<const short8*>(Bh  + (size_t)(n0+brow)*K + kt + e);
                        l = *reinterpret_cast<const short8*>(Blo_+ (size_t)(n0+brow)*K + kt + e);
                    } else {
                        const float* src = &Bf[(size_t)(n0+brow)*ldb + kt + e];
                        float4 v0 = *reinterpret_cast<const float4*>(src);
                        float4 v1 = *reinterpret_cast<const float4*>(src+4);
                        float vv[8] = {v0.x,v0.y,v0.z,v0.w,v1.x,v1.y,v1.z,v1.w};
                        #pragma unroll
                        for(int j=0;j<8;j++){
                            unsigned short hb = f2bf(vv[j]);
                            h[j] = (short)hb;
                            l[j] = (short)f2bf(vv[j] - bf2f(hb));
                        }
                    }
                }
                int byteoff = brow*128 + (colbyte ^ ((brow&7)<<4));
                *reinterpret_cast<short8*>(reinterpret_cast<char*>(Bhi)+byteoff) = h;
                *reinterpret_cast<short8*>(reinterpret_cast<char*>(Blo)+byteoff) = l;
            }
        }
        __syncthreads();
        #pragma unroll
        for(int kb=0;kb<2;kb++){
            short8 ah[WM], al[WM], bh[WN], bl[WN];
            #pragma unroll
            for(int i=0;i<WM;i++){
                int ar = wm + i*16 + (lane&15);
                int ab = ar*128 + (((kb*64) + ((lane>>4)*16)) ^ ((ar&7)<<4));
                ah[i] = *reinterpret_cast<const short8*>(reinterpret_cast<const char*>(Ahi)+ab);
                al[i] = *reinterpret_cast<const short8*>(reinterpret_cast<const char*>(Alo)+ab);
            }
            #pragma unroll
            for(int i=0;i<WN;i++){
                int br = wn + i*16 + (lane&15);
                int bb = br*128 + (((kb*64) + ((lane>>4)*16)) ^ ((br&7)<<4));
                bh[i] = *reinterpret_cast<const short8*>(reinterpret_cast<const char*>(Bhi)+bb);
                bl[i] = *reinterpret_cast<const short8*>(reinterpret_cast<const char*>(Blo)+bb);
            }
            #pragma unroll
            for(int mi=0;mi<WM;mi++)
                #pragma unroll
                for(int ni=0;ni<WN;ni++){
                    acc[mi][ni] = __builtin_amdgcn_mfma_f32_16x16x32_bf16(
                                      al[mi], bh[ni], acc[mi][ni], 0, 0, 0);
                    acc[mi][ni] = __builtin_amdgcn_mfma_f32_16x16x32_bf16(
                                      ah[mi], bl[ni], acc[mi][ni], 0, 0, 0);
                    acc[mi][ni] = __builtin_amdgcn_mfma_f32_16x16x32_bf16(
                                      ah[mi], bh[ni], acc[mi][ni], 0, 0, 0);
                }
        }
        __syncthreads();
    }
    // epilogue: col=lane&15, row=(lane>>4)*4+r
    #pragma unroll
    for(int mi=0;mi<WM;mi++){
        #pragma unroll
        for(int ni=0;ni<WN;ni++){
            int col = n0 + wn + ni*16 + (lane&15);
            if(col >= N) continue;
            int rowb = m0 + wm + mi*16 + ((lane>>4)*4);
            float bv = bias ? bias[col] : 0.f;
            #pragma unroll
            for(int r=0;r<4;r++){
                int m = rowb + r;
                if(m >= M) continue;
                float v = acc[mi][ni][r]*scale + bv;
                if(act==1)      v = 0.5f*v*(1.0f + erff(v*0.70710678118654752f));
                else if(act==2) v = 1.0f/(1.0f + expf(-v));
                C[(size_t)m*ldc + col] = v;
            }
        }
    }
}

// ------------- softmax (+optional importance partials) over S rows -----------
template<int NJ>
__global__ __launch_bounds__(256) void k_softmax(
    float* __restrict__ S, int ld, int NK, float* __restrict__ impp)
{
    const int qc = blockIdx.x, h = blockIdx.y;
    const int tid = threadIdx.x;
    const int r = tid >> 4, c = tid & 15;
    float* row = S + (size_t)h*4096*ld + (size_t)(qc*16 + r)*ld;
    float s[NJ];
    float m = -1e30f;
    #pragma unroll
    for(int j=0;j<NJ;j++){
        int k = c + j*16;
        s[j] = (k < NK) ? row[k] : -1e30f;
        m = fmaxf(m, s[j]);
    }
    m = fmaxf(m, __shfl_xor(m, 1));
    m = fmaxf(m, __shfl_xor(m, 2));
    m = fmaxf(m, __shfl_xor(m, 4));
    m = fmaxf(m, __shfl_xor(m, 8));
    float l = 0.f;
    #pragma unroll
    for(int j=0;j<NJ;j++){ s[j] = __expf(s[j] - m); l += s[j]; }
    l += __shfl_xor(l, 1);
    l += __shfl_xor(l, 2);
    l += __shfl_xor(l, 4);
    l += __shfl_xor(l, 8);
    const float inv = 1.f / l;
    #pragma unroll
    for(int j=0;j<NJ;j++){
        row[c + j*16] = s[j]*inv;
    }
    if(impp){
        __syncthreads();
        int k4 = tid*4;
        if(k4 < NJ*16){
            const float* base = S + (size_t)h*4096*ld + (size_t)(qc*16)*ld + k4;
            float4 acc = make_float4(0.f,0.f,0.f,0.f);
            #pragma unroll
            for(int rr=0; rr<16; rr++){
                float4 v = *reinterpret_cast<const float4*>(base + (size_t)rr*ld);
                acc.x+=v.x; acc.y+=v.y; acc.z+=v.z; acc.w+=v.w;
            }
            *reinterpret_cast<float4*>(&impp[(size_t)(h*256 + qc)*976 + k4]) = acc;
        }
    }
}

// ---------------- bf16 MFMA GEMM (single, pre-transposed WT) -----------------
__global__ __launch_bounds__(256) void k_gemm_mfma(
        const float* __restrict__ A, const unsigned short* __restrict__ WT,
        const float* __restrict__ bias, float* __restrict__ C,
        int M, int K, int Nn, int act)
{
    __shared__ unsigned short Al[128*64];
    __shared__ unsigned short Bl[128*64];
    const int m0 = blockIdx.y*128, n0 = blockIdx.x*128;
    const int tid = threadIdx.x, lane = tid&63, wv = tid>>6;
    const int wm = (wv>>1)*64, wn = (wv&1)*64;
    f32x4 acc[4][4] = {};

    const int srow = tid>>1;
    const int sks  = (tid&1)*32;

    for(int kt=0; kt<K; kt+=64){
        {
            const bool ok = (m0+srow) < M;
            const float* src = &A[(size_t)(m0+srow)*K + kt + sks];
            #pragma unroll
            for(int c=0;c<4;c++){
                float4 v0 = make_float4(0,0,0,0), v1 = v0;
                if(ok){
                    v0 = *reinterpret_cast<const float4*>(src + c*8);
                    v1 = *reinterpret_cast<const float4*>(src + c*8 + 4);
                }
                short8 s;
                s[0]=(short)f2bf(v0.x); s[1]=(short)f2bf(v0.y);
                s[2]=(short)f2bf(v0.z); s[3]=(short)f2bf(v0.w);
                s[4]=(short)f2bf(v1.x); s[5]=(short)f2bf(v1.y);
                s[6]=(short)f2bf(v1.z); s[7]=(short)f2bf(v1.w);
                int byteoff = srow*128 + ((sks*2 + c*16) ^ ((srow&7)<<4));
                *reinterpret_cast<short8*>(reinterpret_cast<char*>(Al) + byteoff) = s;
            }
        }
        {
            const bool ok = (n0+srow) < Nn;
            const unsigned short* src = &WT[(size_t)(n0+srow)*K + kt + sks];
            #pragma unroll
            for(int c=0;c<4;c++){
                short8 s = {};
                if(ok) s = *reinterpret_cast<const short8*>(src + c*8);
                int byteoff = srow*128 + ((sks*2 + c*16) ^ ((srow&7)<<4));
                *reinterpret_cast<short8*>(reinterpret_cast<char*>(Bl) + byteoff) = s;
            }
        }
        __syncthreads();
        #pragma unroll
        for(int kb=0;kb<2;kb++){
            short8 af[4], bfr[4];
            #pragma unroll
            for(int i=0;i<4;i++){
                int ar = wm + i*16 + (lane&15);
                int abyte = ar*128 + (((kb*64) + ((lane>>4)*16)) ^ ((ar&7)<<4));
                af[i] = *reinterpret_cast<const short8*>(reinterpret_cast<const char*>(Al) + abyte);
                int br = wn + i*16 + (lane&15);
                int bbyte = br*128 + (((kb*64) + ((lane>>4)*16)) ^ ((br&7)<<4));
                bfr[i] = *reinterpret_cast<const short8*>(reinterpret_cast<const char*>(Bl) + bbyte);
            }
            #pragma unroll
            for(int mi=0;mi<4;mi++)
                #pragma unroll
                for(int ni=0;ni<4;ni++)
                    acc[mi][ni] = __builtin_amdgcn_mfma_f32_16x16x32_bf16(
                                      af[mi], bfr[ni], acc[mi][ni], 0, 0, 0);
        }
        __syncthreads();
    }
    #pragma unroll
    for(int mi=0;mi<4;mi++){
        #pragma unroll
        for(int ni=0;ni<4;ni++){
            int col = n0 + wn + ni*16 + (lane&15);
            if(col >= Nn) continue;
            int rowb = m0 + wm + mi*16 + ((lane>>4)*4);
            float bv = bias[col];
            #pragma unroll
            for(int r=0;r<4;r++){
                int m = rowb + r;
                if(m >= M) continue;
                float v = acc[mi][ni][r] + bv;
                if(act==1)      v = 0.5f*v*(1.0f + erff(v*0.70710678118654752f));
                else if(act==2) v = 1.0f/(1.0f + expf(-v));
                C[(size_t)m*Nn + col] = v;
            }
        }
    }
}

// ------------- unfold (CBS=4, stride 2) with torch-quirk flat order -----------
__global__ void k_unfold(const float* __restrict__ qkv, const float* __restrict__ pos,
                         float* __restrict__ outA, int chanBase){
    int row = blockIdx.x;                 // 0..3843
    int b = row / 961, blk = row % 961;
    int bi = blk / 31, bj = blk % 31;
    for(int j = threadIdx.x; j < 4096; j += 256){
        int ch = j >> 4;
        int kh = (j >> 2) & 3, kw = j & 3;
        int n = (bi*2 + kh)*64 + (bj*2 + kw);
        float v = qkv[((size_t)(b*4096) + n)*768 + chanBase + ch];
        if(pos) v += pos[j];
        outA[(size_t)row*4096 + j] = v;
    }
}

// ------------- deterministic importance reduce -------------------------------
__global__ void k_imp_reduce(const float* __restrict__ impp, float* __restrict__ imp){
    __shared__ float part[4][64];
    int b = blockIdx.y;
    int k = blockIdx.x*64 + (threadIdx.x & 63);
    int rr = threadIdx.x >> 6;
    float s = 0.f;
    if(k < 976){
        for(int r=rr; r<1024; r+=4)
            s += impp[((size_t)(b*1024) + r)*976 + k];
    }
    part[rr][threadIdx.x & 63] = s;
    __syncthreads();
    if(threadIdx.x < 64 && k < 961){
        float t = ((part[0][threadIdx.x] + part[1][threadIdx.x])
                 + part[2][threadIdx.x]) + part[3][threadIdx.x];
        imp[b*961 + k] = t;
    }
}

// ------------- top-16 with lowest-index tie-break ----------------------------
__global__ void k_topk(const float* __restrict__ imp, int* __restrict__ idx){
    int b = blockIdx.x;
    __shared__ float v[961];
    __shared__ float bestv[256];
    __shared__ int   besti[256];
    int t = threadIdx.x;
    for(int i=t;i<961;i+=256) v[i] = imp[b*961+i];
    __syncthreads();
    for(int it=0; it<16; it++){
        float bv = -1e30f; int bi = 0;
        for(int i=t;i<961;i+=256){
            if(v[i] > bv){ bv=v[i]; bi=i; }
        }
        bestv[t]=bv; besti[t]=bi;
        __syncthreads();
        if(t==0){
            float gb=-1e30f; int gi=0;
            for(int i=0;i<256;i++){
                if(bestv[i]>gb || (bestv[i]==gb && besti[i]<gi)){ gb=bestv[i]; gi=besti[i]; }
            }
            idx[b*16+it] = gi;
            v[gi] = -1e30f;
        }
        __syncthreads();
    }
}

// ------------- gather selected K/V (quirk layout, clip to 255) ----------------
__global__ void k_gather_sel(const float* __restrict__ qkv2, const int* __restrict__ idx,
                             float* __restrict__ Ks, float* __restrict__ Vs){
    int row = blockIdx.x;            // b*256 + t ; t = sel*16 + p
    int b = row >> 8, tt = row & 255;
    int sel = tt >> 4, p = tt & 15;
    int blk = idx[b*16+sel]; if(blk > 255) blk = 255;
    int bi = blk >> 4, bj = blk & 15;
    int cc = threadIdx.x;
    int y = bi*4 + ((cc>>2)&3), xx = bj*4 + (cc&3);
    int ch = p*16 + (cc>>4);
    size_t src = ((size_t)(b*4096) + y*64 + xx)*768;
    Ks[(size_t)row*256 + cc] = qkv2[src + 256 + ch];
    Vs[(size_t)row*256 + cc] = qkv2[src + 512 + ch];
}

// ------------- build padded window tokens xw (400*49, 256) -------------------
__global__ void k_xw(const float* __restrict__ xs, float* __restrict__ xw){
    int row = blockIdx.x;             // wb*49 + t
    int wb = row / 49, t = row % 49;
    int b = wb / 100, wrem = wb % 100;
    int wy = wrem / 10, wx = wrem % 10;
    int ty = t / 7, tx = t % 7;
    int y = wy*7 + ty, xx = wx*7 + tx;
    int c = threadIdx.x;
    float v = 0.f;
    if(y < 64 && xx < 64) v = xs[((size_t)(b*4096) + y*64 + xx)*256 + c];
    xw[(size_t)row*256 + c] = v;
}

// ------------- window attention: 49 tokens, rel-pos bias ---------------------
__global__ __launch_bounds__(64) void k_attn_win(
    const float* __restrict__ qkvw, const float* __restrict__ btab,
    float* __restrict__ outp)
{
    const int wb = blockIdx.x, h = blockIdx.y;
    const int lane = threadIdx.x;
    __shared__ float lk[49][64];
    __shared__ float lv[49][64];
    __shared__ float ls[49][51];
    __shared__ float lbias[169];
    for(int i=lane;i<169;i+=64) lbias[i] = btab[i*4 + h];
    for(int r=0;r<49;r++){
        lk[r][lane] = qkvw[((size_t)(wb*49 + r))*768 + 256 + h*64 + lane];
        lv[r][lane] = qkvw[((size_t)(wb*49 + r))*768 + 512 + h*64 + lane];
    }
    __syncthreads();
    if(lane < 49){
        const float* qptr = &qkvw[((size_t)(wb*49 + lane))*768 + h*64];
        float qreg[64];
        #pragma unroll
        for(int d=0;d<64;++d) qreg[d] = qptr[d];
        int ih = lane/7, iw = lane%7;
        float m = -1e30f;
        for(int j=0;j<49;j++){
            float s0=0,s1=0,s2=0,s3=0;
            #pragma unroll
            for(int d=0; d<64; d+=4){
                s0 = fmaf(qreg[d+0], lk[j][d+0], s0);
                s1 = fmaf(qreg[d+1], lk[j][d+1], s1);
                s2 = fmaf(qreg[d+2], lk[j][d+2], s2);
                s3 = fmaf(qreg[d+3], lk[j][d+3], s3);
            }
            int jh=j/7, jw=j%7;
            float s = ((s0+s1)+(s2+s3))*0.125f + lbias[(ih-jh+6)*13 + (iw-jw+6)];
            ls[lane][j] = s;
            m = fmaxf(m, s);
        }
        float l = 0.f;
        for(int j=0;j<49;j++){ float p = __expf(ls[lane][j] - m); ls[lane][j] = p; l += p; }
        float inv = 1.f/l;
        float* op = &outp[((size_t)(wb*49 + lane))*256 + h*64];
        for(int d=0;d<64;d++){
            float a0=0,a1=0;
            for(int j=0;j<48;j+=2){
                a0 = fmaf(ls[lane][j],   lv[j][d],   a0);
                a1 = fmaf(ls[lane][j+1], lv[j+1][d], a1);
            }
            a0 = fmaf(ls[lane][48], lv[48][d], a0);
            op[d] = (a0+a1)*inv;
        }
    }
}

// ------------- final gated combine + transpose to (B,C,H,W) f32 -------------
__global__ void k_combine(const float* __restrict__ ocp, const float* __restrict__ osp,
                          const float* __restrict__ owp, const float* __restrict__ g,
                          float* __restrict__ out){
    __shared__ float tile[32][33];
    int b = blockIdx.z; int c0 = blockIdx.y*32, n0 = blockIdx.x*32;
    int tx = threadIdx.x, ty = threadIdx.y;    // (32,8)
    for(int i=ty;i<32;i+=8){
        int n = n0 + i;
        float g0 = g[(size_t)(b*4096+n)*3 + 0];
        float g1 = g[(size_t)(b*4096+n)*3 + 1];
        float g2 = g[(size_t)(b*4096+n)*3 + 2];
        int y = n >> 6, xx = n & 63;
        int wy = y/7, ty2 = y%7, wx = xx/7, tx2 = xx%7;
        size_t wrow = (size_t)(b*100 + wy*10 + wx)*49 + ty2*7 + tx2;
        size_t base = ((size_t)(b*4096) + n)*256 + c0;
        float vc = ocp[base + tx];
        float vs = osp[base + tx];
        float vw = owp[wrow*256 + c0 + tx];
        tile[i][tx] = g0*vc + g1*vs + g2*vw;
    }
    __syncthreads();
    for(int i=ty;i<32;i+=8)
        out[((size_t)(b*256 + c0+i))*4096 + n0 + tx] = tile[tx][i];
}

// =============================== host side ===================================
extern "C" void kernel_launch(void* const* d_in, const int* in_sizes, int n_in,
                              void* d_out, int out_size, void* d_ws, size_t ws_size,
                              hipStream_t stream)
{
    typedef const float* fp;
    fp x          = (fp)d_in[0];
    fp qkv_cmp_w  = (fp)d_in[1];  fp qkv_cmp_b = (fp)d_in[2];
    fp qkv_slc_w  = (fp)d_in[3];  fp qkv_slc_b = (fp)d_in[4];
    fp cmpk_w1    = (fp)d_in[5];  fp cmpk_b1   = (fp)d_in[6];
    fp cmpk_w2    = (fp)d_in[7];  fp cmpk_b2   = (fp)d_in[8];
    fp cmpv_w1    = (fp)d_in[9];  fp cmpv_b1   = (fp)d_in[10];
    fp cmpv_w2    = (fp)d_in[11]; fp cmpv_b2   = (fp)d_in[12];
    fp pos_embed  = (fp)d_in[13];
    fp win_qkv_w  = (fp)d_in[14]; fp win_qkv_b = (fp)d_in[15];
    fp win_proj_w = (fp)d_in[16]; fp win_proj_b= (fp)d_in[17];
    fp win_btab   = (fp)d_in[18];
    fp proj_cmp_w = (fp)d_in[19]; fp proj_cmp_b= (fp)d_in[20];
    fp proj_slc_w = (fp)d_in[21]; fp proj_slc_b= (fp)d_in[22];
    fp gate_w1    = (fp)d_in[23]; fp gate_b1   = (fp)d_in[24];
    fp gate_w2    = (fp)d_in[25]; fp gate_b2   = (fp)d_in[26];
    (void)in_sizes; (void)n_in; (void)out_size;

    char* ws = (char*)d_ws;
    size_t off = 0;
    auto alloc = [&](size_t bytes)->size_t{
        size_t r = off; off += (bytes + 255) & ~(size_t)255; return r;
    };
    const size_t XS   = alloc((size_t)16384*256*4);
    const size_t QKV  = alloc((size_t)16384*768*4);
    const size_t BIGA = alloc((size_t)4*4096*976*4);     // unfold-A / qkvw / S
    const size_t HID  = alloc((size_t)3844*512*4);
    const size_t KC   = alloc((size_t)3844*256*4);
    const size_t VC   = alloc((size_t)(3844+16)*256*4);
    const size_t OC   = alloc((size_t)16384*256*4);
    const size_t IMPP = alloc((size_t)4096*976*4);
    const size_t IMP  = alloc((size_t)4*961*4);
    const size_t IDX  = alloc((size_t)4*16*4);
    const size_t OCP  = alloc((size_t)16384*256*4);
    const size_t XW   = alloc((size_t)19600*256*4);
    const size_t OWP  = alloc((size_t)19600*256*4);
    const size_t KS   = alloc((size_t)4*256*256*4);
    const size_t VS   = alloc((size_t)4*256*256*4);
    const size_t G2   = alloc((size_t)16384*3*4);
    const size_t TQS  = alloc((size_t)768*256*2);
    const size_t TWQ  = alloc((size_t)768*256*2);
    const size_t TV1  = alloc((size_t)512*4096*2);
    const size_t TV2  = alloc((size_t)256*512*2);
    const size_t TPC  = alloc((size_t)256*256*2);
    const size_t TPS  = alloc((size_t)256*256*2);
    const size_t TWP  = alloc((size_t)256*256*2);
    const size_t TG1  = alloc((size_t)64*256*2);
    // split weight pairs (selection-critical path)
    const size_t TQCH = alloc((size_t)768*256*2);
    const size_t TQCL = alloc((size_t)768*256*2);
    const size_t TK1H = alloc((size_t)512*4096*2);
    const size_t TK1L = alloc((size_t)512*4096*2);
    const size_t TK2H = alloc((size_t)256*512*2);
    const size_t TK2L = alloc((size_t)256*512*2);
    if(off > ws_size) return;

    float* p_xs  = (float*)(ws + XS);
    float* p_qkv = (float*)(ws + QKV);
    float* p_big = (float*)(ws + BIGA);
    float* p_hid = (float*)(ws + HID);
    float* p_kc  = (float*)(ws + KC);
    float* p_vc  = (float*)(ws + VC);
    float* p_oc  = (float*)(ws + OC);
    float* p_impp= (float*)(ws + IMPP);
    float* p_imp = (float*)(ws + IMP);
    int*   p_idx = (int*)  (ws + IDX);
    float* p_ocp = (float*)(ws + OCP);
    float* p_xw  = (float*)(ws + XW);
    float* p_owp = (float*)(ws + OWP);
    float* p_ks  = (float*)(ws + KS);
    float* p_vs  = (float*)(ws + VS);
    float* p_g   = (float*)(ws + G2);
    unsigned short* t_qs = (unsigned short*)(ws + TQS);
    unsigned short* t_wq = (unsigned short*)(ws + TWQ);
    unsigned short* t_v1 = (unsigned short*)(ws + TV1);
    unsigned short* t_v2 = (unsigned short*)(ws + TV2);
    unsigned short* t_pc = (unsigned short*)(ws + TPC);
    unsigned short* t_ps = (unsigned short*)(ws + TPS);
    unsigned short* t_wp = (unsigned short*)(ws + TWP);
    unsigned short* t_g1 = (unsigned short*)(ws + TG1);
    unsigned short* t_qch= (unsigned short*)(ws + TQCH);
    unsigned short* t_qcl= (unsigned short*)(ws + TQCL);
    unsigned short* t_k1h= (unsigned short*)(ws + TK1H);
    unsigned short* t_k1l= (unsigned short*)(ws + TK1L);
    unsigned short* t_k2h= (unsigned short*)(ws + TK2H);
    unsigned short* t_k2l= (unsigned short*)(ws + TK2L);

    auto gemm = [&](const float* A, fp W, fp bias, float* Cc, int M, int K, int Nn, int act){
        dim3 g((Nn+63)/64, (M+63)/64);
        k_gemm<<<g, 256, 0, stream>>>(A, W, bias, Cc, M, K, Nn, K, Nn, Nn, act, 0, 0, 0);
    };
    auto wt = [&](fp W, unsigned short* WT, int K, int Nn){
        k_wt<<<dim3((K+31)/32, (Nn+31)/32), dim3(32,8), 0, stream>>>(W, WT, K, Nn);
    };
    auto wt2 = [&](fp W, unsigned short* H, unsigned short* L, int K, int Nn){
        k_wt2<<<dim3((K+31)/32, (Nn+31)/32), dim3(32,8), 0, stream>>>(W, H, L, K, Nn);
    };
    auto mgemm = [&](const float* A, const unsigned short* WT, fp bias, float* Cc,
                     int M, int K, int Nn, int act){
        dim3 g((Nn+127)/128, (M+127)/128);
        k_gemm_mfma<<<g, 256, 0, stream>>>(A, WT, bias, Cc, M, K, Nn, act);
    };
    // split NN gemm with pre-split weight pair
    auto sgemm = [&](const float* A, const unsigned short* H, const unsigned short* L,
                     fp bias, float* Cc, int M, int K, int Nn, int act, bool big){
        if(big){
            dim3 g((Nn+127)/128, (M+127)/128);
            k_mgs<4,4,1><<<g, 256, 0, stream>>>(A, nullptr, H, L, bias, Cc,
                M, Nn, K, K, 0, Nn, act, 1.0f, 0, 0, 0);
        } else {
            dim3 g((Nn+63)/64, (M+63)/64);
            k_mgs<2,2,1><<<g, 256, 0, stream>>>(A, nullptr, H, L, bias, Cc,
                M, Nn, K, K, 0, Nn, act, 1.0f, 0, 0, 0);
        }
    };

    // 0. weight preprocessing
    wt(qkv_slc_w, t_qs, 256, 768);
    wt(win_qkv_w, t_wq, 256, 768);
    wt(cmpv_w1,   t_v1, 4096, 512);
    wt(cmpv_w2,   t_v2, 512, 256);
    wt(proj_cmp_w,t_pc, 256, 256);
    wt(proj_slc_w,t_ps, 256, 256);
    wt(win_proj_w,t_wp, 256, 256);
    wt(gate_w1,   t_g1, 256, 64);
    wt2(qkv_cmp_w, t_qch, t_qcl, 256, 768);
    wt2(cmpk_w1,   t_k1h, t_k1l, 4096, 512);
    wt2(cmpk_w2,   t_k2h, t_k2l, 512, 256);

    // 1. xs = transpose(x)
    k_xs<<<dim3(128,8,4), dim3(32,8), 0, stream>>>(x, p_xs);
    // 2. qkv_cmp (split MFMA — selection-critical, ~f32 accuracy)
    sgemm(p_xs, t_qch, t_qcl, qkv_cmp_b, p_qkv, 16384, 256, 768, 0, true);
    // 3-5. compressed K path (split MFMA)
    k_unfold<<<3844, 256, 0, stream>>>(p_qkv, pos_embed, p_big, 256);
    sgemm(p_big, t_k1h, t_k1l, cmpk_b1, p_hid, 3844, 4096, 512, 1, false);
    sgemm(p_hid, t_k2h, t_k2l, cmpk_b2, p_kc, 3844, 512, 256, 0, false);
    // 6-8. compressed V path (single bf16 MFMA)
    k_unfold<<<3844, 256, 0, stream>>>(p_qkv, nullptr, p_big, 512);
    mgemm(p_big, t_v1, cmpv_b1, p_hid, 3844, 4096, 512, 1);
    mgemm(p_hid, t_v2, cmpv_b2, p_vc, 3844, 512, 256, 0);
    // 9. compressed attention: S = 0.125*Q·K^T (split MFMA), softmax, PV (f32)
    for(int b=0;b<4;b++){
        k_mgs<4,4,0><<<dim3(8,32,4), 256, 0, stream>>>(
            p_qkv + (size_t)b*4096*768, p_kc + (size_t)b*961*256, nullptr, nullptr,
            nullptr, p_big, 4096, 961, 64, 768, 256, 976, 0, 0.125f,
            64, 64, (long)4096*976);
        k_softmax<61><<<dim3(256,4), 256, 0, stream>>>(
            p_big, 976, 961, p_impp + (size_t)b*1024*976);
        k_gemm<<<dim3(1,64,4), 256, 0, stream>>>(
            p_big, p_vc + (size_t)b*961*256, nullptr, p_oc + (size_t)b*4096*256,
            4096, 976, 64, 976, 256, 256, 0,
            (long)4096*976, 64, 64);
    }
    k_imp_reduce<<<dim3(16,4), 256, 0, stream>>>(p_impp, p_imp);
    k_topk<<<4, 256, 0, stream>>>(p_imp, p_idx);
    // 10. out_cmp projection
    mgemm(p_oc, t_pc, proj_cmp_b, p_ocp, 16384, 256, 256, 0);
    // 11. qkv_slc
    mgemm(p_xs, t_qs, qkv_slc_b, p_qkv, 16384, 256, 768, 0);
    // 12-14. window branch (qkvw reuses BIGA)
    k_xw<<<19600, 256, 0, stream>>>(p_xs, p_xw);
    mgemm(p_xw, t_wq, win_qkv_b, p_big, 19600, 256, 768, 0);
    k_attn_win<<<dim3(400,4), 64, 0, stream>>>(p_big, win_btab, p_xw);   // xw := owin_tok
    mgemm(p_xw, t_wp, win_proj_b, p_owp, 19600, 256, 256, 0);
    // 15-17. selected branch (S_slc reuses BIGA)
    k_gather_sel<<<1024, 256, 0, stream>>>(p_qkv, p_idx, p_ks, p_vs);
    for(int b=0;b<4;b++){
        k_mgs<2,2,0><<<dim3(4,64,4), 256, 0, stream>>>(
            p_qkv + (size_t)b*4096*768, p_ks + (size_t)b*256*256, nullptr, nullptr,
            nullptr, p_big, 4096, 256, 64, 768, 256, 256, 0, 0.125f,
            64, 64, (long)4096*256);
        k_softmax<16><<<dim3(256,4), 256, 0, stream>>>(
            p_big, 256, 256, nullptr);
        k_gemm<<<dim3(1,64,4), 256, 0, stream>>>(
            p_big, p_vs + (size_t)b*256*256, nullptr, p_oc + (size_t)b*4096*256,
            4096, 256, 64, 256, 256, 256, 0,
            (long)4096*256, 64, 64);
    }
    mgemm(p_oc, t_ps, proj_slc_b, p_xw, 16384, 256, 256, 0);             // xw := out_slc
    // 18-19. gate
    mgemm(p_xs, t_g1, gate_b1, p_hid, 16384, 256, 64, 1);
    gemm(p_hid, gate_w2, gate_b2, p_g, 16384, 64, 3, 2);
    // 20. combine
    k_combine<<<dim3(128,8,4), dim3(32,8), 0, stream>>>(p_ocp, p_xw, p_owp, p_g,
                                                        (float*)d_out);
}

// Round 7
// 1625.945 us; speedup vs baseline: 2.8759x; 1.2129x over previous
//
#include <hip/hip_runtime.h>
#include <stdint.h>
#include <stddef.h>

// SpatialNSA on MI355X — round 7:
//  * k_topk: parallel butterfly argmax (was serial thread-0 scan, 295 us).
//  * PV re-cast as split-bf16 MFMA via per-(b,c) transposed V (k_vt), with
//    chunk-granular K-guard in k_mgs staging (K=976 remainder tile).
//  * everything else identical to passing round-6 pipeline.

#define DEV __device__ __forceinline__

typedef __attribute__((ext_vector_type(8))) short short8;
typedef __attribute__((ext_vector_type(4))) float f32x4;

DEV unsigned short f2bf(float f){
    unsigned u = __float_as_uint(f);
    u += 0x7FFFu + ((u>>16)&1u);   // RNE
    return (unsigned short)(u>>16);
}
DEV float bf2f(unsigned short u){ return __uint_as_float(((unsigned)u)<<16); }

// ---------------- transpose: x (B,C,N) f32 -> xs (B,N,C) f32 -------------
__global__ void k_xs(const float* __restrict__ x, float* __restrict__ xs){
    __shared__ float t[32][33];
    int b = blockIdx.z; int c0 = blockIdx.y*32; int n0 = blockIdx.x*32;
    int tx = threadIdx.x, ty = threadIdx.y;            // (32,8)
    for(int i=ty;i<32;i+=8)
        t[i][tx] = x[((size_t)(b*256 + c0+i))*4096 + n0 + tx];
    __syncthreads();
    for(int i=ty;i<32;i+=8)
        xs[((size_t)(b*4096 + n0+i))*256 + c0 + tx] = t[tx][i];
}

// -------- weight transpose+cast: W (K,N) f32 -> WT (N,K) bf16 ---------------
__global__ void k_wt(const float* __restrict__ W, unsigned short* __restrict__ WT,
                     int K, int N){
    __shared__ float t[32][33];
    int k0 = blockIdx.x*32, n0 = blockIdx.y*32;
    int tx = threadIdx.x, ty = threadIdx.y;            // (32,8)
    for(int i=ty;i<32;i+=8)
        if(k0+i<K && n0+tx<N) t[i][tx] = W[(size_t)(k0+i)*N + n0+tx];
    __syncthreads();
    for(int i=ty;i<32;i+=8)
        if(n0+i<N && k0+tx<K) WT[(size_t)(n0+i)*K + k0+tx] = f2bf(t[tx][i]);
}

// -------- split weight transpose: W (K,N) f32 -> (N,K) bf16 hi + lo ---------
__global__ void k_wt2(const float* __restrict__ W, unsigned short* __restrict__ Hi,
                      unsigned short* __restrict__ Lo, int K, int N){
    __shared__ float t[32][33];
    int k0 = blockIdx.x*32, n0 = blockIdx.y*32;
    int tx = threadIdx.x, ty = threadIdx.y;
    for(int i=ty;i<32;i+=8)
        if(k0+i<K && n0+tx<N) t[i][tx] = W[(size_t)(k0+i)*N + n0+tx];
    __syncthreads();
    for(int i=ty;i<32;i+=8)
        if(n0+i<N && k0+tx<K){
            float v = t[tx][i];
            unsigned short h = f2bf(v);
            unsigned short l = f2bf(v - bf2f(h));
            Hi[(size_t)(n0+i)*K + k0+tx] = h;
            Lo[(size_t)(n0+i)*K + k0+tx] = l;
        }
}

// -------- V transpose: vc rows (b*NK+k)*256+c -> vt[(b*256+c)*ldk + k] -------
// zero-fills k in [NK, ldk).
__global__ void k_vt(const float* __restrict__ vc, float* __restrict__ vt,
                     int NK, int ldk){
    __shared__ float t[32][33];
    int b = blockIdx.z; int k0 = blockIdx.x*32; int c0 = blockIdx.y*32;
    int tx = threadIdx.x, ty = threadIdx.y;            // (32,8)
    for(int i=ty;i<32;i+=8){
        int k = k0+i;
        t[i][tx] = (k < NK) ? vc[((size_t)(b*NK + k))*256 + c0 + tx] : 0.f;
    }
    __syncthreads();
    for(int i=ty;i<32;i+=8){
        int k = k0+tx;
        if(k < ldk)
            vt[((size_t)(b*256 + c0+i))*ldk + k] = t[tx][i];
    }
}

// ---------------- f32 GEMM (gate tail only) ----------------------------------
__global__ __launch_bounds__(256) void k_gemm(
        const float* __restrict__ A, const float* __restrict__ W,
        const float* __restrict__ bias, float* __restrict__ C,
        int M, int K, int Nn, int lda, int ldw, int ldc, int act,
        long zsA, long zsW, long zsC)
{
    A += (size_t)blockIdx.z * zsA;
    W += (size_t)blockIdx.z * zsW;
    C += (size_t)blockIdx.z * zsC;
    __shared__ float As[16][68];
    __shared__ float Bs[16][64];
    const int m0 = blockIdx.y*64, n0 = blockIdx.x*64;
    const int t = threadIdx.x, tx = t&15, ty = t>>4;
    float acc[4][4] = {};
    const int am = t>>2;
    const int ak = (t&3)*4;
    const bool arow_ok = (m0+am) < M;

    for(int k0=0;k0<K;k0+=16){
        float4 av = make_float4(0.f,0.f,0.f,0.f);
        if(arow_ok) av = *reinterpret_cast<const float4*>(&A[(size_t)(m0+am)*lda + k0 + ak]);
        As[ak+0][am]=av.x; As[ak+1][am]=av.y; As[ak+2][am]=av.z; As[ak+3][am]=av.w;
        if((Nn & 3) == 0){
            int bn = (t&15)*4, bk = t>>4;
            float4 bv = make_float4(0.f,0.f,0.f,0.f);
            if(n0+bn < Nn)
                bv = *reinterpret_cast<const float4*>(&W[(size_t)(k0+bk)*ldw + n0+bn]);
            Bs[bk][bn]=bv.x; Bs[bk][bn+1]=bv.y; Bs[bk][bn+2]=bv.z; Bs[bk][bn+3]=bv.w;
        } else {
            int n = t&63, kb = t>>6;
            #pragma unroll
            for(int r=0;r<4;r++){
                int kk = r*4 + kb; float v = 0.f;
                if(n0+n < Nn) v = W[(size_t)(k0+kk)*ldw + n0+n];
                Bs[kk][n] = v;
            }
        }
        __syncthreads();
        #pragma unroll
        for(int kk=0;kk<16;kk++){
            float a0=As[kk][ty*4+0], a1=As[kk][ty*4+1], a2=As[kk][ty*4+2], a3=As[kk][ty*4+3];
            float b0=Bs[kk][tx*4+0], b1=Bs[kk][tx*4+1], b2=Bs[kk][tx*4+2], b3=Bs[kk][tx*4+3];
            acc[0][0]=fmaf(a0,b0,acc[0][0]); acc[0][1]=fmaf(a0,b1,acc[0][1]);
            acc[0][2]=fmaf(a0,b2,acc[0][2]); acc[0][3]=fmaf(a0,b3,acc[0][3]);
            acc[1][0]=fmaf(a1,b0,acc[1][0]); acc[1][1]=fmaf(a1,b1,acc[1][1]);
            acc[1][2]=fmaf(a1,b2,acc[1][2]); acc[1][3]=fmaf(a1,b3,acc[1][3]);
            acc[2][0]=fmaf(a2,b0,acc[2][0]); acc[2][1]=fmaf(a2,b1,acc[2][1]);
            acc[2][2]=fmaf(a2,b2,acc[2][2]); acc[2][3]=fmaf(a2,b3,acc[2][3]);
            acc[3][0]=fmaf(a3,b0,acc[3][0]); acc[3][1]=fmaf(a3,b1,acc[3][1]);
            acc[3][2]=fmaf(a3,b2,acc[3][2]); acc[3][3]=fmaf(a3,b3,acc[3][3]);
        }
        __syncthreads();
    }
    #pragma unroll
    for(int i=0;i<4;i++){
        int m = m0 + ty*4 + i;
        if(m >= M) continue;
        #pragma unroll
        for(int j=0;j<4;j++){
            int n = n0 + tx*4 + j;
            if(n >= Nn) continue;
            float v = acc[i][j] + (bias ? bias[n] : 0.f);
            if(act==1)      v = 0.5f*v*(1.0f + erff(v*0.70710678118654752f));
            else if(act==2) v = 1.0f/(1.0f + expf(-v));
            C[(size_t)m*ldc + n] = v;
        }
    }
}

// ============ split-bf16 MFMA GEMM: C = scale*(A @ B^T) [+bias][act] =========
// A: f32 (M x K, lda). B: BPAIR ? pre-split bf16 [N][K] hi/lo : f32 [N][K] ldb.
// 3-term split product => ~f32 accuracy. Tile 32WM x 32WN, BK=64, 4 waves 2x2.
// Chunk-granular K-guard: partial last tile zero-filled (requires K%8==0).
template<int WM, int WN, int BPAIR>
__global__ __launch_bounds__(256) void k_mgs(
        const float* __restrict__ A, const float* __restrict__ Bf,
        const unsigned short* __restrict__ Bh, const unsigned short* __restrict__ Blo_,
        const float* __restrict__ bias, float* __restrict__ C,
        int M, int N, int K, int lda, int ldb, int ldc, int act, float scale,
        long zsA, long zsB, long zsC)
{
    constexpr int BM = 32*WM, BN = 32*WN;
    A += (size_t)blockIdx.z * zsA;
    if(BPAIR==0 && Bf) Bf += (size_t)blockIdx.z * zsB;
    C += (size_t)blockIdx.z * zsC;

    __shared__ unsigned short Ahi[BM*64], Alo[BM*64];
    __shared__ unsigned short Bhi[BN*64], Blo[BN*64];

    const int m0 = blockIdx.y*BM, n0 = blockIdx.x*BN;
    const int tid = threadIdx.x, lane = tid&63, wv = tid>>6;
    const int wm = (wv>>1)*(16*WM), wn = (wv&1)*(16*WN);
    f32x4 acc[WM][WN] = {};

    constexpr int TPR_A = 256/BM;
    constexpr int CH_A  = 8/TPR_A;
    const int arow = tid / TPR_A;
    const int acol0 = (tid % TPR_A)*(128/TPR_A);
    constexpr int TPR_B = 256/BN;
    constexpr int CH_B  = 8/TPR_B;
    const int brow = tid / TPR_B;
    const int bcol0 = (tid % TPR_B)*(128/TPR_B);

    for(int kt=0; kt<K; kt+=64){
        // ---- stage A (f32 -> hi/lo bf16, swizzled) ----
        {
            const bool ok = (m0+arow) < M;
            #pragma unroll
            for(int c=0;c<CH_A;c++){
                int colbyte = acol0 + c*16;
                int e = colbyte>>1;
                float4 v0 = make_float4(0,0,0,0), v1 = v0;
                if(ok && (kt + e + 8 <= K)){
                    const float* src = &A[(size_t)(m0+arow)*lda + kt + e];
                    v0 = *reinterpret_cast<const float4*>(src);
                    v1 = *reinterpret_cast<const float4*>(src+4);
                }
                short8 h, l;
                float vv[8] = {v0.x,v0.y,v0.z,v0.w,v1.x,v1.y,v1.z,v1.w};
                #pragma unroll
                for(int j=0;j<8;j++){
                    unsigned short hb = f2bf(vv[j]);
                    h[j] = (short)hb;
                    l[j] = (short)f2bf(vv[j] - bf2f(hb));
                }
                int byteoff = arow*128 + (colbyte ^ ((arow&7)<<4));
                *reinterpret_cast<short8*>(reinterpret_cast<char*>(Ahi)+byteoff) = h;
                *reinterpret_cast<short8*>(reinterpret_cast<char*>(Alo)+byteoff) = l;
            }
        }
        // ---- stage B ----
        {
            const bool ok = (n0+brow) < N;
            #pragma unroll
            for(int c=0;c<CH_B;c++){
                int colbyte = bcol0 + c*16;
                int e = colbyte>>1;
                short8 h = {}, l = {};
                if(ok && (kt + e + 8 <= K)){
                    if(BPAIR){
                        h = *reinterpret_cast<const short8*>(Bh  + (size_t)(n0+brow)*K + kt + e);
                        l = *reinterpret_cast<const short8*>(Blo_+ (size_t)(n0+brow)*K + kt + e);
                    } else {
                        const float* src = &Bf[(size_t)(n0+brow)*ldb + kt + e];
                        float4 v0 = *reinterpret_cast<const float4*>(src);
                        float4 v1 = *reinterpret_cast<const float4*>(src+4);
                        float vv[8] = {v0.x,v0.y,v0.z,v0.w,v1.x,v1.y,v1.z,v1.w};
                        #pragma unroll
                        for(int j=0;j<8;j++){
                            unsigned short hb = f2bf(vv[j]);
                            h[j] = (short)hb;
                            l[j] = (short)f2bf(vv[j] - bf2f(hb));
                        }
                    }
                }
                int byteoff = brow*128 + (colbyte ^ ((brow&7)<<4));
                *reinterpret_cast<short8*>(reinterpret_cast<char*>(Bhi)+byteoff) = h;
                *reinterpret_cast<short8*>(reinterpret_cast<char*>(Blo)+byteoff) = l;
            }
        }
        __syncthreads();
        #pragma unroll
        for(int kb=0;kb<2;kb++){
            short8 ah[WM], al[WM], bh[WN], bl[WN];
            #pragma unroll
            for(int i=0;i<WM;i++){
                int ar = wm + i*16 + (lane&15);
                int ab = ar*128 + (((kb*64) + ((lane>>4)*16)) ^ ((ar&7)<<4));
                ah[i] = *reinterpret_cast<const short8*>(reinterpret_cast<const char*>(Ahi)+ab);
                al[i] = *reinterpret_cast<const short8*>(reinterpret_cast<const char*>(Alo)+ab);
            }
            #pragma unroll
            for(int i=0;i<WN;i++){
                int br = wn + i*16 + (lane&15);
                int bb = br*128 + (((kb*64) + ((lane>>4)*16)) ^ ((br&7)<<4));
                bh[i] = *reinterpret_cast<const short8*>(reinterpret_cast<const char*>(Bhi)+bb);
                bl[i] = *reinterpret_cast<const short8*>(reinterpret_cast<const char*>(Blo)+bb);
            }
            #pragma unroll
            for(int mi=0;mi<WM;mi++)
                #pragma unroll
                for(int ni=0;ni<WN;ni++){
                    acc[mi][ni] = __builtin_amdgcn_mfma_f32_16x16x32_bf16(
                                      al[mi], bh[ni], acc[mi][ni], 0, 0, 0);
                    acc[mi][ni] = __builtin_amdgcn_mfma_f32_16x16x32_bf16(
                                      ah[mi], bl[ni], acc[mi][ni], 0, 0, 0);
                    acc[mi][ni] = __builtin_amdgcn_mfma_f32_16x16x32_bf16(
                                      ah[mi], bh[ni], acc[mi][ni], 0, 0, 0);
                }
        }
        __syncthreads();
    }
    #pragma unroll
    for(int mi=0;mi<WM;mi++){
        #pragma unroll
        for(int ni=0;ni<WN;ni++){
            int col = n0 + wn + ni*16 + (lane&15);
            if(col >= N) continue;
            int rowb = m0 + wm + mi*16 + ((lane>>4)*4);
            float bv = bias ? bias[col] : 0.f;
            #pragma unroll
            for(int r=0;r<4;r++){
                int m = rowb + r;
                if(m >= M) continue;
                float v = acc[mi][ni][r]*scale + bv;
                if(act==1)      v = 0.5f*v*(1.0f + erff(v*0.70710678118654752f));
                else if(act==2) v = 1.0f/(1.0f + expf(-v));
                C[(size_t)m*ldc + col] = v;
            }
        }
    }
}

// ------------- softmax (+optional importance partials) over S rows -----------
template<int NJ>
__global__ __launch_bounds__(256) void k_softmax(
    float* __restrict__ S, int ld, int NK, float* __restrict__ impp)
{
    const int qc = blockIdx.x, h = blockIdx.y;
    const int tid = threadIdx.x;
    const int r = tid >> 4, c = tid & 15;
    float* row = S + (size_t)h*4096*ld + (size_t)(qc*16 + r)*ld;
    float s[NJ];
    float m = -1e30f;
    #pragma unroll
    for(int j=0;j<NJ;j++){
        int k = c + j*16;
        s[j] = (k < NK) ? row[k] : -1e30f;
        m = fmaxf(m, s[j]);
    }
    m = fmaxf(m, __shfl_xor(m, 1));
    m = fmaxf(m, __shfl_xor(m, 2));
    m = fmaxf(m, __shfl_xor(m, 4));
    m = fmaxf(m, __shfl_xor(m, 8));
    float l = 0.f;
    #pragma unroll
    for(int j=0;j<NJ;j++){ s[j] = __expf(s[j] - m); l += s[j]; }
    l += __shfl_xor(l, 1);
    l += __shfl_xor(l, 2);
    l += __shfl_xor(l, 4);
    l += __shfl_xor(l, 8);
    const float inv = 1.f / l;
    #pragma unroll
    for(int j=0;j<NJ;j++){
        row[c + j*16] = s[j]*inv;
    }
    if(impp){
        __syncthreads();
        int k4 = tid*4;
        if(k4 < NJ*16){
            const float* base = S + (size_t)h*4096*ld + (size_t)(qc*16)*ld + k4;
            float4 acc = make_float4(0.f,0.f,0.f,0.f);
            #pragma unroll
            for(int rr=0; rr<16; rr++){
                float4 v = *reinterpret_cast<const float4*>(base + (size_t)rr*ld);
                acc.x+=v.x; acc.y+=v.y; acc.z+=v.z; acc.w+=v.w;
            }
            *reinterpret_cast<float4*>(&impp[(size_t)(h*256 + qc)*976 + k4]) = acc;
        }
    }
}

// ---------------- bf16 MFMA GEMM (single, pre-transposed WT) -----------------
__global__ __launch_bounds__(256) void k_gemm_mfma(
        const float* __restrict__ A, const unsigned short* __restrict__ WT,
        const float* __restrict__ bias, float* __restrict__ C,
        int M, int K, int Nn, int act)
{
    __shared__ unsigned short Al[128*64];
    __shared__ unsigned short Bl[128*64];
    const int m0 = blockIdx.y*128, n0 = blockIdx.x*128;
    const int tid = threadIdx.x, lane = tid&63, wv = tid>>6;
    const int wm = (wv>>1)*64, wn = (wv&1)*64;
    f32x4 acc[4][4] = {};

    const int srow = tid>>1;
    const int sks  = (tid&1)*32;

    for(int kt=0; kt<K; kt+=64){
        {
            const bool ok = (m0+srow) < M;
            const float* src = &A[(size_t)(m0+srow)*K + kt + sks];
            #pragma unroll
            for(int c=0;c<4;c++){
                float4 v0 = make_float4(0,0,0,0), v1 = v0;
                if(ok){
                    v0 = *reinterpret_cast<const float4*>(src + c*8);
                    v1 = *reinterpret_cast<const float4*>(src + c*8 + 4);
                }
                short8 s;
                s[0]=(short)f2bf(v0.x); s[1]=(short)f2bf(v0.y);
                s[2]=(short)f2bf(v0.z); s[3]=(short)f2bf(v0.w);
                s[4]=(short)f2bf(v1.x); s[5]=(short)f2bf(v1.y);
                s[6]=(short)f2bf(v1.z); s[7]=(short)f2bf(v1.w);
                int byteoff = srow*128 + ((sks*2 + c*16) ^ ((srow&7)<<4));
                *reinterpret_cast<short8*>(reinterpret_cast<char*>(Al) + byteoff) = s;
            }
        }
        {
            const bool ok = (n0+srow) < Nn;
            const unsigned short* src = &WT[(size_t)(n0+srow)*K + kt + sks];
            #pragma unroll
            for(int c=0;c<4;c++){
                short8 s = {};
                if(ok) s = *reinterpret_cast<const short8*>(src + c*8);
                int byteoff = srow*128 + ((sks*2 + c*16) ^ ((srow&7)<<4));
                *reinterpret_cast<short8*>(reinterpret_cast<char*>(Bl) + byteoff) = s;
            }
        }
        __syncthreads();
        #pragma unroll
        for(int kb=0;kb<2;kb++){
            short8 af[4], bfr[4];
            #pragma unroll
            for(int i=0;i<4;i++){
                int ar = wm + i*16 + (lane&15);
                int abyte = ar*128 + (((kb*64) + ((lane>>4)*16)) ^ ((ar&7)<<4));
                af[i] = *reinterpret_cast<const short8*>(reinterpret_cast<const char*>(Al) + abyte);
                int br = wn + i*16 + (lane&15);
                int bbyte = br*128 + (((kb*64) + ((lane>>4)*16)) ^ ((br&7)<<4));
                bfr[i] = *reinterpret_cast<const short8*>(reinterpret_cast<const char*>(Bl) + bbyte);
            }
            #pragma unroll
            for(int mi=0;mi<4;mi++)
                #pragma unroll
                for(int ni=0;ni<4;ni++)
                    acc[mi][ni] = __builtin_amdgcn_mfma_f32_16x16x32_bf16(
                                      af[mi], bfr[ni], acc[mi][ni], 0, 0, 0);
        }
        __syncthreads();
    }
    #pragma unroll
    for(int mi=0;mi<4;mi++){
        #pragma unroll
        for(int ni=0;ni<4;ni++){
            int col = n0 + wn + ni*16 + (lane&15);
            if(col >= Nn) continue;
            int rowb = m0 + wm + mi*16 + ((lane>>4)*4);
            float bv = bias[col];
            #pragma unroll
            for(int r=0;r<4;r++){
                int m = rowb + r;
                if(m >= M) continue;
                float v = acc[mi][ni][r] + bv;
                if(act==1)      v = 0.5f*v*(1.0f + erff(v*0.70710678118654752f));
                else if(act==2) v = 1.0f/(1.0f + expf(-v));
                C[(size_t)m*Nn + col] = v;
            }
        }
    }
}

// ------------- unfold (CBS=4, stride 2) with torch-quirk flat order -----------
__global__ void k_unfold(const float* __restrict__ qkv, const float* __restrict__ pos,
                         float* __restrict__ outA, int chanBase){
    int row = blockIdx.x;                 // 0..3843
    int b = row / 961, blk = row % 961;
    int bi = blk / 31, bj = blk % 31;
    for(int j = threadIdx.x; j < 4096; j += 256){
        int ch = j >> 4;
        int kh = (j >> 2) & 3, kw = j & 3;
        int n = (bi*2 + kh)*64 + (bj*2 + kw);
        float v = qkv[((size_t)(b*4096) + n)*768 + chanBase + ch];
        if(pos) v += pos[j];
        outA[(size_t)row*4096 + j] = v;
    }
}

// ------------- deterministic importance reduce -------------------------------
__global__ void k_imp_reduce(const float* __restrict__ impp, float* __restrict__ imp){
    __shared__ float part[4][64];
    int b = blockIdx.y;
    int k = blockIdx.x*64 + (threadIdx.x & 63);
    int rr = threadIdx.x >> 6;
    float s = 0.f;
    if(k < 976){
        for(int r=rr; r<1024; r+=4)
            s += impp[((size_t)(b*1024) + r)*976 + k];
    }
    part[rr][threadIdx.x & 63] = s;
    __syncthreads();
    if(threadIdx.x < 64 && k < 961){
        float t = ((part[0][threadIdx.x] + part[1][threadIdx.x])
                 + part[2][threadIdx.x]) + part[3][threadIdx.x];
        imp[b*961 + k] = t;
    }
}

// ------------- top-16, parallel argmax, lowest-index tie-break ---------------
__global__ __launch_bounds__(256) void k_topk(const float* __restrict__ imp,
                                              int* __restrict__ idx){
    int b = blockIdx.x;
    __shared__ float v[961];
    __shared__ float wvv[4];
    __shared__ int   wvi[4];
    int t = threadIdx.x;
    int lane = t & 63, wid = t >> 6;
    for(int i=t;i<961;i+=256) v[i] = imp[b*961+i];
    __syncthreads();
    for(int it=0; it<16; it++){
        float bv = -1e30f; int bi = 1<<30;
        for(int i=t;i<961;i+=256){
            float val = v[i];
            if(val > bv){ bv=val; bi=i; }
        }
        #pragma unroll
        for(int off=32; off>0; off>>=1){
            float ov = __shfl_xor(bv, off);
            int   oi = __shfl_xor(bi, off);
            if(ov > bv || (ov == bv && oi < bi)){ bv = ov; bi = oi; }
        }
        if(lane==0){ wvv[wid]=bv; wvi[wid]=bi; }
        __syncthreads();
        if(t==0){
            float gb=wvv[0]; int gi=wvi[0];
            #pragma unroll
            for(int w=1;w<4;w++){
                if(wvv[w]>gb || (wvv[w]==gb && wvi[w]<gi)){ gb=wvv[w]; gi=wvi[w]; }
            }
            idx[b*16+it] = gi;
            v[gi] = -1e30f;
        }
        __syncthreads();
    }
}

// ------------- gather selected K/V (quirk layout, clip to 255) ----------------
__global__ void k_gather_sel(const float* __restrict__ qkv2, const int* __restrict__ idx,
                             float* __restrict__ Ks, float* __restrict__ Vs){
    int row = blockIdx.x;            // b*256 + t ; t = sel*16 + p
    int b = row >> 8, tt = row & 255;
    int sel = tt >> 4, p = tt & 15;
    int blk = idx[b*16+sel]; if(blk > 255) blk = 255;
    int bi = blk >> 4, bj = blk & 15;
    int cc = threadIdx.x;
    int y = bi*4 + ((cc>>2)&3), xx = bj*4 + (cc&3);
    int ch = p*16 + (cc>>4);
    size_t src = ((size_t)(b*4096) + y*64 + xx)*768;
    Ks[(size_t)row*256 + cc] = qkv2[src + 256 + ch];
    Vs[(size_t)row*256 + cc] = qkv2[src + 512 + ch];
}

// ------------- build padded window tokens xw (400*49, 256) -------------------
__global__ void k_xw(const float* __restrict__ xs, float* __restrict__ xw){
    int row = blockIdx.x;             // wb*49 + t
    int wb = row / 49, t = row % 49;
    int b = wb / 100, wrem = wb % 100;
    int wy = wrem / 10, wx = wrem % 10;
    int ty = t / 7, tx = t % 7;
    int y = wy*7 + ty, xx = wx*7 + tx;
    int c = threadIdx.x;
    float v = 0.f;
    if(y < 64 && xx < 64) v = xs[((size_t)(b*4096) + y*64 + xx)*256 + c];
    xw[(size_t)row*256 + c] = v;
}

// ------------- window attention: 49 tokens, rel-pos bias ---------------------
__global__ __launch_bounds__(64) void k_attn_win(
    const float* __restrict__ qkvw, const float* __restrict__ btab,
    float* __restrict__ outp)
{
    const int wb = blockIdx.x, h = blockIdx.y;
    const int lane = threadIdx.x;
    __shared__ float lk[49][64];
    __shared__ float lv[49][64];
    __shared__ float ls[49][51];
    __shared__ float lbias[169];
    for(int i=lane;i<169;i+=64) lbias[i] = btab[i*4 + h];
    for(int r=0;r<49;r++){
        lk[r][lane] = qkvw[((size_t)(wb*49 + r))*768 + 256 + h*64 + lane];
        lv[r][lane] = qkvw[((size_t)(wb*49 + r))*768 + 512 + h*64 + lane];
    }
    __syncthreads();
    if(lane < 49){
        const float* qptr = &qkvw[((size_t)(wb*49 + lane))*768 + h*64];
        float qreg[64];
        #pragma unroll
        for(int d=0;d<64;++d) qreg[d] = qptr[d];
        int ih = lane/7, iw = lane%7;
        float m = -1e30f;
        for(int j=0;j<49;j++){
            float s0=0,s1=0,s2=0,s3=0;
            #pragma unroll
            for(int d=0; d<64; d+=4){
                s0 = fmaf(qreg[d+0], lk[j][d+0], s0);
                s1 = fmaf(qreg[d+1], lk[j][d+1], s1);
                s2 = fmaf(qreg[d+2], lk[j][d+2], s2);
                s3 = fmaf(qreg[d+3], lk[j][d+3], s3);
            }
            int jh=j/7, jw=j%7;
            float s = ((s0+s1)+(s2+s3))*0.125f + lbias[(ih-jh+6)*13 + (iw-jw+6)];
            ls[lane][j] = s;
            m = fmaxf(m, s);
        }
        float l = 0.f;
        for(int j=0;j<49;j++){ float p = __expf(ls[lane][j] - m); ls[lane][j] = p; l += p; }
        float inv = 1.f/l;
        float* op = &outp[((size_t)(wb*49 + lane))*256 + h*64];
        for(int d=0;d<64;d++){
            float a0=0,a1=0;
            for(int j=0;j<48;j+=2){
                a0 = fmaf(ls[lane][j],   lv[j][d],   a0);
                a1 = fmaf(ls[lane][j+1], lv[j+1][d], a1);
            }
            a0 = fmaf(ls[lane][48], lv[48][d], a0);
            op[d] = (a0+a1)*inv;
        }
    }
}

// ------------- final gated combine + transpose to (B,C,H,W) f32 -------------
__global__ void k_combine(const float* __restrict__ ocp, const float* __restrict__ osp,
                          const float* __restrict__ owp, const float* __restrict__ g,
                          float* __restrict__ out){
    __shared__ float tile[32][33];
    int b = blockIdx.z; int c0 = blockIdx.y*32, n0 = blockIdx.x*32;
    int tx = threadIdx.x, ty = threadIdx.y;    // (32,8)
    for(int i=ty;i<32;i+=8){
        int n = n0 + i;
        float g0 = g[(size_t)(b*4096+n)*3 + 0];
        float g1 = g[(size_t)(b*4096+n)*3 + 1];
        float g2 = g[(size_t)(b*4096+n)*3 + 2];
        int y = n >> 6, xx = n & 63;
        int wy = y/7, ty2 = y%7, wx = xx/7, tx2 = xx%7;
        size_t wrow = (size_t)(b*100 + wy*10 + wx)*49 + ty2*7 + tx2;
        size_t base = ((size_t)(b*4096) + n)*256 + c0;
        float vc = ocp[base + tx];
        float vs = osp[base + tx];
        float vw = owp[wrow*256 + c0 + tx];
        tile[i][tx] = g0*vc + g1*vs + g2*vw;
    }
    __syncthreads();
    for(int i=ty;i<32;i+=8)
        out[((size_t)(b*256 + c0+i))*4096 + n0 + tx] = tile[tx][i];
}

// =============================== host side ===================================
extern "C" void kernel_launch(void* const* d_in, const int* in_sizes, int n_in,
                              void* d_out, int out_size, void* d_ws, size_t ws_size,
                              hipStream_t stream)
{
    typedef const float* fp;
    fp x          = (fp)d_in[0];
    fp qkv_cmp_w  = (fp)d_in[1];  fp qkv_cmp_b = (fp)d_in[2];
    fp qkv_slc_w  = (fp)d_in[3];  fp qkv_slc_b = (fp)d_in[4];
    fp cmpk_w1    = (fp)d_in[5];  fp cmpk_b1   = (fp)d_in[6];
    fp cmpk_w2    = (fp)d_in[7];  fp cmpk_b2   = (fp)d_in[8];
    fp cmpv_w1    = (fp)d_in[9];  fp cmpv_b1   = (fp)d_in[10];
    fp cmpv_w2    = (fp)d_in[11]; fp cmpv_b2   = (fp)d_in[12];
    fp pos_embed  = (fp)d_in[13];
    fp win_qkv_w  = (fp)d_in[14]; fp win_qkv_b = (fp)d_in[15];
    fp win_proj_w = (fp)d_in[16]; fp win_proj_b= (fp)d_in[17];
    fp win_btab   = (fp)d_in[18];
    fp proj_cmp_w = (fp)d_in[19]; fp proj_cmp_b= (fp)d_in[20];
    fp proj_slc_w = (fp)d_in[21]; fp proj_slc_b= (fp)d_in[22];
    fp gate_w1    = (fp)d_in[23]; fp gate_b1   = (fp)d_in[24];
    fp gate_w2    = (fp)d_in[25]; fp gate_b2   = (fp)d_in[26];
    (void)in_sizes; (void)n_in; (void)out_size;

    char* ws = (char*)d_ws;
    size_t off = 0;
    auto alloc = [&](size_t bytes)->size_t{
        size_t r = off; off += (bytes + 255) & ~(size_t)255; return r;
    };
    const size_t XS   = alloc((size_t)16384*256*4);
    const size_t QKV  = alloc((size_t)16384*768*4);
    const size_t BIGA = alloc((size_t)4*4096*976*4);     // unfold-A / qkvw / S
    const size_t HID  = alloc((size_t)3844*512*4);
    const size_t KC   = alloc((size_t)3844*256*4);
    const size_t VC   = alloc((size_t)3844*256*4);
    const size_t OC   = alloc((size_t)16384*256*4);
    const size_t IMPP = alloc((size_t)4096*976*4);
    const size_t IMP  = alloc((size_t)4*961*4);
    const size_t IDX  = alloc((size_t)4*16*4);
    const size_t OCP  = alloc((size_t)16384*256*4);
    const size_t XW   = alloc((size_t)19600*256*4);
    const size_t OWP  = alloc((size_t)19600*256*4);
    const size_t KS   = alloc((size_t)4*256*256*4);
    const size_t VS   = alloc((size_t)4*256*256*4);
    const size_t G2   = alloc((size_t)16384*3*4);
    const size_t VTC  = alloc((size_t)4*256*976*4);      // V^T cmp (zero-padded)
    const size_t VTS  = alloc((size_t)4*256*256*4);      // V^T slc
    const size_t TQS  = alloc((size_t)768*256*2);
    const size_t TWQ  = alloc((size_t)768*256*2);
    const size_t TV1  = alloc((size_t)512*4096*2);
    const size_t TV2  = alloc((size_t)256*512*2);
    const size_t TPC  = alloc((size_t)256*256*2);
    const size_t TPS  = alloc((size_t)256*256*2);
    const size_t TWP  = alloc((size_t)256*256*2);
    const size_t TG1  = alloc((size_t)64*256*2);
    const size_t TQCH = alloc((size_t)768*256*2);
    const size_t TQCL = alloc((size_t)768*256*2);
    const size_t TK1H = alloc((size_t)512*4096*2);
    const size_t TK1L = alloc((size_t)512*4096*2);
    const size_t TK2H = alloc((size_t)256*512*2);
    const size_t TK2L = alloc((size_t)256*512*2);
    if(off > ws_size) return;

    float* p_xs  = (float*)(ws + XS);
    float* p_qkv = (float*)(ws + QKV);
    float* p_big = (float*)(ws + BIGA);
    float* p_hid = (float*)(ws + HID);
    float* p_kc  = (float*)(ws + KC);
    float* p_vc  = (float*)(ws + VC);
    float* p_oc  = (float*)(ws + OC);
    float* p_impp= (float*)(ws + IMPP);
    float* p_imp = (float*)(ws + IMP);
    int*   p_idx = (int*)  (ws + IDX);
    float* p_ocp = (float*)(ws + OCP);
    float* p_xw  = (float*)(ws + XW);
    float* p_owp = (float*)(ws + OWP);
    float* p_ks  = (float*)(ws + KS);
    float* p_vs  = (float*)(ws + VS);
    float* p_g   = (float*)(ws + G2);
    float* p_vtc = (float*)(ws + VTC);
    float* p_vts = (float*)(ws + VTS);
    unsigned short* t_qs = (unsigned short*)(ws + TQS);
    unsigned short* t_wq = (unsigned short*)(ws + TWQ);
    unsigned short* t_v1 = (unsigned short*)(ws + TV1);
    unsigned short* t_v2 = (unsigned short*)(ws + TV2);
    unsigned short* t_pc = (unsigned short*)(ws + TPC);
    unsigned short* t_ps = (unsigned short*)(ws + TPS);
    unsigned short* t_wp = (unsigned short*)(ws + TWP);
    unsigned short* t_g1 = (unsigned short*)(ws + TG1);
    unsigned short* t_qch= (unsigned short*)(ws + TQCH);
    unsigned short* t_qcl= (unsigned short*)(ws + TQCL);
    unsigned short* t_k1h= (unsigned short*)(ws + TK1H);
    unsigned short* t_k1l= (unsigned short*)(ws + TK1L);
    unsigned short* t_k2h= (unsigned short*)(ws + TK2H);
    unsigned short* t_k2l= (unsigned short*)(ws + TK2L);

    auto gemm = [&](const float* A, fp W, fp bias, float* Cc, int M, int K, int Nn, int act){
        dim3 g((Nn+63)/64, (M+63)/64);
        k_gemm<<<g, 256, 0, stream>>>(A, W, bias, Cc, M, K, Nn, K, Nn, Nn, act, 0, 0, 0);
    };
    auto wt = [&](fp W, unsigned short* WT, int K, int Nn){
        k_wt<<<dim3((K+31)/32, (Nn+31)/32), dim3(32,8), 0, stream>>>(W, WT, K, Nn);
    };
    auto wt2 = [&](fp W, unsigned short* H, unsigned short* L, int K, int Nn){
        k_wt2<<<dim3((K+31)/32, (Nn+31)/32), dim3(32,8), 0, stream>>>(W, H, L, K, Nn);
    };
    auto mgemm = [&](const float* A, const unsigned short* WT, fp bias, float* Cc,
                     int M, int K, int Nn, int act){
        dim3 g((Nn+127)/128, (M+127)/128);
        k_gemm_mfma<<<g, 256, 0, stream>>>(A, WT, bias, Cc, M, K, Nn, act);
    };
    auto sgemm = [&](const float* A, const unsigned short* H, const unsigned short* L,
                     fp bias, float* Cc, int M, int K, int Nn, int act, bool big){
        if(big){
            dim3 g((Nn+127)/128, (M+127)/128);
            k_mgs<4,4,1><<<g, 256, 0, stream>>>(A, nullptr, H, L, bias, Cc,
                M, Nn, K, K, 0, Nn, act, 1.0f, 0, 0, 0);
        } else {
            dim3 g((Nn+63)/64, (M+63)/64);
            k_mgs<2,2,1><<<g, 256, 0, stream>>>(A, nullptr, H, L, bias, Cc,
                M, Nn, K, K, 0, Nn, act, 1.0f, 0, 0, 0);
        }
    };

    // 0. weight preprocessing
    wt(qkv_slc_w, t_qs, 256, 768);
    wt(win_qkv_w, t_wq, 256, 768);
    wt(cmpv_w1,   t_v1, 4096, 512);
    wt(cmpv_w2,   t_v2, 512, 256);
    wt(proj_cmp_w,t_pc, 256, 256);
    wt(proj_slc_w,t_ps, 256, 256);
    wt(win_proj_w,t_wp, 256, 256);
    wt(gate_w1,   t_g1, 256, 64);
    wt2(qkv_cmp_w, t_qch, t_qcl, 256, 768);
    wt2(cmpk_w1,   t_k1h, t_k1l, 4096, 512);
    wt2(cmpk_w2,   t_k2h, t_k2l, 512, 256);

    // 1. xs = transpose(x)
    k_xs<<<dim3(128,8,4), dim3(32,8), 0, stream>>>(x, p_xs);
    // 2. qkv_cmp (split MFMA)
    sgemm(p_xs, t_qch, t_qcl, qkv_cmp_b, p_qkv, 16384, 256, 768, 0, true);
    // 3-5. compressed K path (split MFMA)
    k_unfold<<<3844, 256, 0, stream>>>(p_qkv, pos_embed, p_big, 256);
    sgemm(p_big, t_k1h, t_k1l, cmpk_b1, p_hid, 3844, 4096, 512, 1, false);
    sgemm(p_hid, t_k2h, t_k2l, cmpk_b2, p_kc, 3844, 512, 256, 0, false);
    // 6-8. compressed V path (single bf16 MFMA)
    k_unfold<<<3844, 256, 0, stream>>>(p_qkv, nullptr, p_big, 512);
    mgemm(p_big, t_v1, cmpv_b1, p_hid, 3844, 4096, 512, 1);
    mgemm(p_hid, t_v2, cmpv_b2, p_vc, 3844, 512, 256, 0);
    // V^T for PV (zero-padded to 976)
    k_vt<<<dim3(31,8,4), dim3(32,8), 0, stream>>>(p_vc, p_vtc, 961, 976);
    // 9. compressed attention: S = 0.125*Q·K^T (split MFMA), softmax, PV (split MFMA)
    for(int b=0;b<4;b++){
        k_mgs<4,4,0><<<dim3(8,32,4), 256, 0, stream>>>(
            p_qkv + (size_t)b*4096*768, p_kc + (size_t)b*961*256, nullptr, nullptr,
            nullptr, p_big, 4096, 961, 64, 768, 256, 976, 0, 0.125f,
            64, 64, (long)4096*976);
        k_softmax<61><<<dim3(256,4), 256, 0, stream>>>(
            p_big, 976, 961, p_impp + (size_t)b*1024*976);
        k_mgs<4,2,0><<<dim3(1,32,4), 256, 0, stream>>>(
            p_big, p_vtc + (size_t)b*256*976, nullptr, nullptr,
            nullptr, p_oc + (size_t)b*4096*256,
            4096, 64, 976, 976, 976, 256, 0, 1.0f,
            (long)4096*976, (long)64*976, 64);
    }
    k_imp_reduce<<<dim3(16,4), 256, 0, stream>>>(p_impp, p_imp);
    k_topk<<<4, 256, 0, stream>>>(p_imp, p_idx);
    // 10. out_cmp projection
    mgemm(p_oc, t_pc, proj_cmp_b, p_ocp, 16384, 256, 256, 0);
    // 11. qkv_slc
    mgemm(p_xs, t_qs, qkv_slc_b, p_qkv, 16384, 256, 768, 0);
    // 12-14. window branch (qkvw reuses BIGA)
    k_xw<<<19600, 256, 0, stream>>>(p_xs, p_xw);
    mgemm(p_xw, t_wq, win_qkv_b, p_big, 19600, 256, 768, 0);
    k_attn_win<<<dim3(400,4), 64, 0, stream>>>(p_big, win_btab, p_xw);   // xw := owin_tok
    mgemm(p_xw, t_wp, win_proj_b, p_owp, 19600, 256, 256, 0);
    // 15-17. selected branch
    k_gather_sel<<<1024, 256, 0, stream>>>(p_qkv, p_idx, p_ks, p_vs);
    k_vt<<<dim3(8,8,4), dim3(32,8), 0, stream>>>(p_vs, p_vts, 256, 256);
    for(int b=0;b<4;b++){
        k_mgs<2,2,0><<<dim3(4,64,4), 256, 0, stream>>>(
            p_qkv + (size_t)b*4096*768, p_ks + (size_t)b*256*256, nullptr, nullptr,
            nullptr, p_big, 4096, 256, 64, 768, 256, 256, 0, 0.125f,
            64, 64, (long)4096*256);
        k_softmax<16><<<dim3(256,4), 256, 0, stream>>>(
            p_big, 256, 256, nullptr);
        k_mgs<4,2,0><<<dim3(1,32,4), 256, 0, stream>>>(
            p_big, p_vts + (size_t)b*256*256, nullptr, nullptr,
            nullptr, p_oc + (size_t)b*4096*256,
            4096, 64, 256, 256, 256, 256, 0, 1.0f,
            (long)4096*256, (long)64*256, 64);
    }
    mgemm(p_oc, t_ps, proj_slc_b, p_xw, 16384, 256, 256, 0);             // xw := out_slc
    // 18-19. gate
    mgemm(p_xs, t_g1, gate_b1, p_hid, 16384, 256, 64, 1);
    gemm(p_hid, gate_w2, gate_b2, p_g, 16384, 64, 3, 2);
    // 20. combine
    k_combine<<<dim3(128,8,4), dim3(32,8), 0, stream>>>(p_ocp, p_xw, p_owp, p_g,
                                                        (float*)d_out);
}

// Round 8
// 1428.054 us; speedup vs baseline: 3.2745x; 1.1386x over previous
//
#include <hip/hip_runtime.h>
#include <stdint.h>
#include <stddef.h>

// SpatialNSA on MI355X — round 8:
//  * unified k_mgs<WM,WN,BPAIR,NSPLIT>; NSPLIT=1 (single-bf16) compiles out
//    the lo LDS arrays and lo MFMAs. Tile sizes chosen for >=244 blocks
//    everywhere (round-7 top dispatch was 124-block grid-starved: 5% occ).
//  * math identical to round 7 (split paths bit-identical; single path same
//    rounding as old k_gemm_mfma).

#define DEV __device__ __forceinline__

typedef __attribute__((ext_vector_type(8))) short short8;
typedef __attribute__((ext_vector_type(4))) float f32x4;

DEV unsigned short f2bf(float f){
    unsigned u = __float_as_uint(f);
    u += 0x7FFFu + ((u>>16)&1u);   // RNE
    return (unsigned short)(u>>16);
}
DEV float bf2f(unsigned short u){ return __uint_as_float(((unsigned)u)<<16); }

// ---------------- transpose: x (B,C,N) f32 -> xs (B,N,C) f32 -------------
__global__ void k_xs(const float* __restrict__ x, float* __restrict__ xs){
    __shared__ float t[32][33];
    int b = blockIdx.z; int c0 = blockIdx.y*32; int n0 = blockIdx.x*32;
    int tx = threadIdx.x, ty = threadIdx.y;            // (32,8)
    for(int i=ty;i<32;i+=8)
        t[i][tx] = x[((size_t)(b*256 + c0+i))*4096 + n0 + tx];
    __syncthreads();
    for(int i=ty;i<32;i+=8)
        xs[((size_t)(b*4096 + n0+i))*256 + c0 + tx] = t[tx][i];
}

// -------- weight transpose+cast: W (K,N) f32 -> WT (N,K) bf16 ---------------
__global__ void k_wt(const float* __restrict__ W, unsigned short* __restrict__ WT,
                     int K, int N){
    __shared__ float t[32][33];
    int k0 = blockIdx.x*32, n0 = blockIdx.y*32;
    int tx = threadIdx.x, ty = threadIdx.y;            // (32,8)
    for(int i=ty;i<32;i+=8)
        if(k0+i<K && n0+tx<N) t[i][tx] = W[(size_t)(k0+i)*N + n0+tx];
    __syncthreads();
    for(int i=ty;i<32;i+=8)
        if(n0+i<N && k0+tx<K) WT[(size_t)(n0+i)*K + k0+tx] = f2bf(t[tx][i]);
}

// -------- split weight transpose: W (K,N) f32 -> (N,K) bf16 hi + lo ---------
__global__ void k_wt2(const float* __restrict__ W, unsigned short* __restrict__ Hi,
                      unsigned short* __restrict__ Lo, int K, int N){
    __shared__ float t[32][33];
    int k0 = blockIdx.x*32, n0 = blockIdx.y*32;
    int tx = threadIdx.x, ty = threadIdx.y;
    for(int i=ty;i<32;i+=8)
        if(k0+i<K && n0+tx<N) t[i][tx] = W[(size_t)(k0+i)*N + n0+tx];
    __syncthreads();
    for(int i=ty;i<32;i+=8)
        if(n0+i<N && k0+tx<K){
            float v = t[tx][i];
            unsigned short h = f2bf(v);
            unsigned short l = f2bf(v - bf2f(h));
            Hi[(size_t)(n0+i)*K + k0+tx] = h;
            Lo[(size_t)(n0+i)*K + k0+tx] = l;
        }
}

// -------- V transpose: vc rows (b*NK+k)*256+c -> vt[(b*256+c)*ldk + k] -------
__global__ void k_vt(const float* __restrict__ vc, float* __restrict__ vt,
                     int NK, int ldk){
    __shared__ float t[32][33];
    int b = blockIdx.z; int k0 = blockIdx.x*32; int c0 = blockIdx.y*32;
    int tx = threadIdx.x, ty = threadIdx.y;            // (32,8)
    for(int i=ty;i<32;i+=8){
        int k = k0+i;
        t[i][tx] = (k < NK) ? vc[((size_t)(b*NK + k))*256 + c0 + tx] : 0.f;
    }
    __syncthreads();
    for(int i=ty;i<32;i+=8){
        int k = k0+tx;
        if(k < ldk)
            vt[((size_t)(b*256 + c0+i))*ldk + k] = t[tx][i];
    }
}

// ---------------- f32 GEMM (gate tail only) ----------------------------------
__global__ __launch_bounds__(256) void k_gemm(
        const float* __restrict__ A, const float* __restrict__ W,
        const float* __restrict__ bias, float* __restrict__ C,
        int M, int K, int Nn, int lda, int ldw, int ldc, int act,
        long zsA, long zsW, long zsC)
{
    A += (size_t)blockIdx.z * zsA;
    W += (size_t)blockIdx.z * zsW;
    C += (size_t)blockIdx.z * zsC;
    __shared__ float As[16][68];
    __shared__ float Bs[16][64];
    const int m0 = blockIdx.y*64, n0 = blockIdx.x*64;
    const int t = threadIdx.x, tx = t&15, ty = t>>4;
    float acc[4][4] = {};
    const int am = t>>2;
    const int ak = (t&3)*4;
    const bool arow_ok = (m0+am) < M;

    for(int k0=0;k0<K;k0+=16){
        float4 av = make_float4(0.f,0.f,0.f,0.f);
        if(arow_ok) av = *reinterpret_cast<const float4*>(&A[(size_t)(m0+am)*lda + k0 + ak]);
        As[ak+0][am]=av.x; As[ak+1][am]=av.y; As[ak+2][am]=av.z; As[ak+3][am]=av.w;
        if((Nn & 3) == 0){
            int bn = (t&15)*4, bk = t>>4;
            float4 bv = make_float4(0.f,0.f,0.f,0.f);
            if(n0+bn < Nn)
                bv = *reinterpret_cast<const float4*>(&W[(size_t)(k0+bk)*ldw + n0+bn]);
            Bs[bk][bn]=bv.x; Bs[bk][bn+1]=bv.y; Bs[bk][bn+2]=bv.z; Bs[bk][bn+3]=bv.w;
        } else {
            int n = t&63, kb = t>>6;
            #pragma unroll
            for(int r=0;r<4;r++){
                int kk = r*4 + kb; float v = 0.f;
                if(n0+n < Nn) v = W[(size_t)(k0+kk)*ldw + n0+n];
                Bs[kk][n] = v;
            }
        }
        __syncthreads();
        #pragma unroll
        for(int kk=0;kk<16;kk++){
            float a0=As[kk][ty*4+0], a1=As[kk][ty*4+1], a2=As[kk][ty*4+2], a3=As[kk][ty*4+3];
            float b0=Bs[kk][tx*4+0], b1=Bs[kk][tx*4+1], b2=Bs[kk][tx*4+2], b3=Bs[kk][tx*4+3];
            acc[0][0]=fmaf(a0,b0,acc[0][0]); acc[0][1]=fmaf(a0,b1,acc[0][1]);
            acc[0][2]=fmaf(a0,b2,acc[0][2]); acc[0][3]=fmaf(a0,b3,acc[0][3]);
            acc[1][0]=fmaf(a1,b0,acc[1][0]); acc[1][1]=fmaf(a1,b1,acc[1][1]);
            acc[1][2]=fmaf(a1,b2,acc[1][2]); acc[1][3]=fmaf(a1,b3,acc[1][3]);
            acc[2][0]=fmaf(a2,b0,acc[2][0]); acc[2][1]=fmaf(a2,b1,acc[2][1]);
            acc[2][2]=fmaf(a2,b2,acc[2][2]); acc[2][3]=fmaf(a2,b3,acc[2][3]);
            acc[3][0]=fmaf(a3,b0,acc[3][0]); acc[3][1]=fmaf(a3,b1,acc[3][1]);
            acc[3][2]=fmaf(a3,b2,acc[3][2]); acc[3][3]=fmaf(a3,b3,acc[3][3]);
        }
        __syncthreads();
    }
    #pragma unroll
    for(int i=0;i<4;i++){
        int m = m0 + ty*4 + i;
        if(m >= M) continue;
        #pragma unroll
        for(int j=0;j<4;j++){
            int n = n0 + tx*4 + j;
            if(n >= Nn) continue;
            float v = acc[i][j] + (bias ? bias[n] : 0.f);
            if(act==1)      v = 0.5f*v*(1.0f + erff(v*0.70710678118654752f));
            else if(act==2) v = 1.0f/(1.0f + expf(-v));
            C[(size_t)m*ldc + n] = v;
        }
    }
}

// ===== unified MFMA GEMM: C = scale*(A @ B^T) [+bias][act] ===================
// A: f32 (M x K, lda). B: BPAIR ? pre-split bf16 [N][K] (hi[,lo]) : f32 [N][K].
// NSPLIT: 3 = hi/lo split product (~f32 accuracy), 1 = plain bf16.
// Tile 32WM x 32WN, BK=64, 4 waves 2x2. Chunk K-guard (needs K%8==0).
template<int WM, int WN, int BPAIR, int NSPLIT>
__global__ __launch_bounds__(256) void k_mgs(
        const float* __restrict__ A, const float* __restrict__ Bf,
        const unsigned short* __restrict__ Bh, const unsigned short* __restrict__ Blo_,
        const float* __restrict__ bias, float* __restrict__ C,
        int M, int N, int K, int lda, int ldb, int ldc, int act, float scale,
        long zsA, long zsB, long zsC)
{
    constexpr int BM = 32*WM, BN = 32*WN;
    constexpr bool SP = (NSPLIT == 3);
    A += (size_t)blockIdx.z * zsA;
    if(BPAIR==0 && Bf) Bf += (size_t)blockIdx.z * zsB;
    C += (size_t)blockIdx.z * zsC;

    __shared__ unsigned short Ahi[BM*64];
    __shared__ unsigned short Alo[SP ? BM*64 : 8];
    __shared__ unsigned short Bhi[BN*64];
    __shared__ unsigned short Blo[SP ? BN*64 : 8];

    const int m0 = blockIdx.y*BM, n0 = blockIdx.x*BN;
    const int tid = threadIdx.x, lane = tid&63, wv = tid>>6;
    const int wm = (wv>>1)*(16*WM), wn = (wv&1)*(16*WN);
    f32x4 acc[WM][WN] = {};

    constexpr int TPR_A = 256/BM;
    constexpr int CH_A  = 8/TPR_A;
    const int arow = tid / TPR_A;
    const int acol0 = (tid % TPR_A)*(128/TPR_A);
    constexpr int TPR_B = 256/BN;
    constexpr int CH_B  = 8/TPR_B;
    const int brow = tid / TPR_B;
    const int bcol0 = (tid % TPR_B)*(128/TPR_B);

    for(int kt=0; kt<K; kt+=64){
        // ---- stage A (f32 -> bf16 [pair], swizzled) ----
        {
            const bool ok = (m0+arow) < M;
            #pragma unroll
            for(int c=0;c<CH_A;c++){
                int colbyte = acol0 + c*16;
                int e = colbyte>>1;
                float4 v0 = make_float4(0,0,0,0), v1 = v0;
                if(ok && (kt + e + 8 <= K)){
                    const float* src = &A[(size_t)(m0+arow)*lda + kt + e];
                    v0 = *reinterpret_cast<const float4*>(src);
                    v1 = *reinterpret_cast<const float4*>(src+4);
                }
                short8 h, l;
                float vv[8] = {v0.x,v0.y,v0.z,v0.w,v1.x,v1.y,v1.z,v1.w};
                #pragma unroll
                for(int j=0;j<8;j++){
                    unsigned short hb = f2bf(vv[j]);
                    h[j] = (short)hb;
                    if(SP) l[j] = (short)f2bf(vv[j] - bf2f(hb));
                }
                int byteoff = arow*128 + (colbyte ^ ((arow&7)<<4));
                *reinterpret_cast<short8*>(reinterpret_cast<char*>(Ahi)+byteoff) = h;
                if(SP)
                    *reinterpret_cast<short8*>(reinterpret_cast<char*>(Alo)+byteoff) = l;
            }
        }
        // ---- stage B ----
        {
            const bool ok = (n0+brow) < N;
            #pragma unroll
            for(int c=0;c<CH_B;c++){
                int colbyte = bcol0 + c*16;
                int e = colbyte>>1;
                short8 h = {}, l = {};
                if(ok && (kt + e + 8 <= K)){
                    if(BPAIR){
                        h = *reinterpret_cast<const short8*>(Bh  + (size_t)(n0+brow)*K + kt + e);
                        if(SP)
                            l = *reinterpret_cast<const short8*>(Blo_+ (size_t)(n0+brow)*K + kt + e);
                    } else {
                        const float* src = &Bf[(size_t)(n0+brow)*ldb + kt + e];
                        float4 v0 = *reinterpret_cast<const float4*>(src);
                        float4 v1 = *reinterpret_cast<const float4*>(src+4);
                        float vv[8] = {v0.x,v0.y,v0.z,v0.w,v1.x,v1.y,v1.z,v1.w};
                        #pragma unroll
                        for(int j=0;j<8;j++){
                            unsigned short hb = f2bf(vv[j]);
                            h[j] = (short)hb;
                            if(SP) l[j] = (short)f2bf(vv[j] - bf2f(hb));
                        }
                    }
                }
                int byteoff = brow*128 + (colbyte ^ ((brow&7)<<4));
                *reinterpret_cast<short8*>(reinterpret_cast<char*>(Bhi)+byteoff) = h;
                if(SP)
                    *reinterpret_cast<short8*>(reinterpret_cast<char*>(Blo)+byteoff) = l;
            }
        }
        __syncthreads();
        #pragma unroll
        for(int kb=0;kb<2;kb++){
            short8 ah[WM], al[WM], bh[WN], bl[WN];
            #pragma unroll
            for(int i=0;i<WM;i++){
                int ar = wm + i*16 + (lane&15);
                int ab = ar*128 + (((kb*64) + ((lane>>4)*16)) ^ ((ar&7)<<4));
                ah[i] = *reinterpret_cast<const short8*>(reinterpret_cast<const char*>(Ahi)+ab);
                if(SP)
                    al[i] = *reinterpret_cast<const short8*>(reinterpret_cast<const char*>(Alo)+ab);
            }
            #pragma unroll
            for(int i=0;i<WN;i++){
                int br = wn + i*16 + (lane&15);
                int bb = br*128 + (((kb*64) + ((lane>>4)*16)) ^ ((br&7)<<4));
                bh[i] = *reinterpret_cast<const short8*>(reinterpret_cast<const char*>(Bhi)+bb);
                if(SP)
                    bl[i] = *reinterpret_cast<const short8*>(reinterpret_cast<const char*>(Blo)+bb);
            }
            #pragma unroll
            for(int mi=0;mi<WM;mi++)
                #pragma unroll
                for(int ni=0;ni<WN;ni++){
                    if(SP){
                        acc[mi][ni] = __builtin_amdgcn_mfma_f32_16x16x32_bf16(
                                          al[mi], bh[ni], acc[mi][ni], 0, 0, 0);
                        acc[mi][ni] = __builtin_amdgcn_mfma_f32_16x16x32_bf16(
                                          ah[mi], bl[ni], acc[mi][ni], 0, 0, 0);
                    }
                    acc[mi][ni] = __builtin_amdgcn_mfma_f32_16x16x32_bf16(
                                      ah[mi], bh[ni], acc[mi][ni], 0, 0, 0);
                }
        }
        __syncthreads();
    }
    #pragma unroll
    for(int mi=0;mi<WM;mi++){
        #pragma unroll
        for(int ni=0;ni<WN;ni++){
            int col = n0 + wn + ni*16 + (lane&15);
            if(col >= N) continue;
            int rowb = m0 + wm + mi*16 + ((lane>>4)*4);
            float bv = bias ? bias[col] : 0.f;
            #pragma unroll
            for(int r=0;r<4;r++){
                int m = rowb + r;
                if(m >= M) continue;
                float v = acc[mi][ni][r]*scale + bv;
                if(act==1)      v = 0.5f*v*(1.0f + erff(v*0.70710678118654752f));
                else if(act==2) v = 1.0f/(1.0f + expf(-v));
                C[(size_t)m*ldc + col] = v;
            }
        }
    }
}

// ------------- softmax (+optional importance partials) over S rows -----------
template<int NJ>
__global__ __launch_bounds__(256) void k_softmax(
    float* __restrict__ S, int ld, int NK, float* __restrict__ impp)
{
    const int qc = blockIdx.x, h = blockIdx.y;
    const int tid = threadIdx.x;
    const int r = tid >> 4, c = tid & 15;
    float* row = S + (size_t)h*4096*ld + (size_t)(qc*16 + r)*ld;
    float s[NJ];
    float m = -1e30f;
    #pragma unroll
    for(int j=0;j<NJ;j++){
        int k = c + j*16;
        s[j] = (k < NK) ? row[k] : -1e30f;
        m = fmaxf(m, s[j]);
    }
    m = fmaxf(m, __shfl_xor(m, 1));
    m = fmaxf(m, __shfl_xor(m, 2));
    m = fmaxf(m, __shfl_xor(m, 4));
    m = fmaxf(m, __shfl_xor(m, 8));
    float l = 0.f;
    #pragma unroll
    for(int j=0;j<NJ;j++){ s[j] = __expf(s[j] - m); l += s[j]; }
    l += __shfl_xor(l, 1);
    l += __shfl_xor(l, 2);
    l += __shfl_xor(l, 4);
    l += __shfl_xor(l, 8);
    const float inv = 1.f / l;
    #pragma unroll
    for(int j=0;j<NJ;j++){
        row[c + j*16] = s[j]*inv;
    }
    if(impp){
        __syncthreads();
        int k4 = tid*4;
        if(k4 < NJ*16){
            const float* base = S + (size_t)h*4096*ld + (size_t)(qc*16)*ld + k4;
            float4 acc = make_float4(0.f,0.f,0.f,0.f);
            #pragma unroll
            for(int rr=0; rr<16; rr++){
                float4 v = *reinterpret_cast<const float4*>(base + (size_t)rr*ld);
                acc.x+=v.x; acc.y+=v.y; acc.z+=v.z; acc.w+=v.w;
            }
            *reinterpret_cast<float4*>(&impp[(size_t)(h*256 + qc)*976 + k4]) = acc;
        }
    }
}

// ------------- unfold (CBS=4, stride 2) with torch-quirk flat order -----------
__global__ void k_unfold(const float* __restrict__ qkv, const float* __restrict__ pos,
                         float* __restrict__ outA, int chanBase){
    int row = blockIdx.x;                 // 0..3843
    int b = row / 961, blk = row % 961;
    int bi = blk / 31, bj = blk % 31;
    for(int j = threadIdx.x; j < 4096; j += 256){
        int ch = j >> 4;
        int kh = (j >> 2) & 3, kw = j & 3;
        int n = (bi*2 + kh)*64 + (bj*2 + kw);
        float v = qkv[((size_t)(b*4096) + n)*768 + chanBase + ch];
        if(pos) v += pos[j];
        outA[(size_t)row*4096 + j] = v;
    }
}

// ------------- deterministic importance reduce -------------------------------
__global__ void k_imp_reduce(const float* __restrict__ impp, float* __restrict__ imp){
    __shared__ float part[4][64];
    int b = blockIdx.y;
    int k = blockIdx.x*64 + (threadIdx.x & 63);
    int rr = threadIdx.x >> 6;
    float s = 0.f;
    if(k < 976){
        for(int r=rr; r<1024; r+=4)
            s += impp[((size_t)(b*1024) + r)*976 + k];
    }
    part[rr][threadIdx.x & 63] = s;
    __syncthreads();
    if(threadIdx.x < 64 && k < 961){
        float t = ((part[0][threadIdx.x] + part[1][threadIdx.x])
                 + part[2][threadIdx.x]) + part[3][threadIdx.x];
        imp[b*961 + k] = t;
    }
}

// ------------- top-16, parallel argmax, lowest-index tie-break ---------------
__global__ __launch_bounds__(256) void k_topk(const float* __restrict__ imp,
                                              int* __restrict__ idx){
    int b = blockIdx.x;
    __shared__ float v[961];
    __shared__ float wvv[4];
    __shared__ int   wvi[4];
    int t = threadIdx.x;
    int lane = t & 63, wid = t >> 6;
    for(int i=t;i<961;i+=256) v[i] = imp[b*961+i];
    __syncthreads();
    for(int it=0; it<16; it++){
        float bv = -1e30f; int bi = 1<<30;
        for(int i=t;i<961;i+=256){
            float val = v[i];
            if(val > bv){ bv=val; bi=i; }
        }
        #pragma unroll
        for(int off=32; off>0; off>>=1){
            float ov = __shfl_xor(bv, off);
            int   oi = __shfl_xor(bi, off);
            if(ov > bv || (ov == bv && oi < bi)){ bv = ov; bi = oi; }
        }
        if(lane==0){ wvv[wid]=bv; wvi[wid]=bi; }
        __syncthreads();
        if(t==0){
            float gb=wvv[0]; int gi=wvi[0];
            #pragma unroll
            for(int w=1;w<4;w++){
                if(wvv[w]>gb || (wvv[w]==gb && wvi[w]<gi)){ gb=wvv[w]; gi=wvi[w]; }
            }
            idx[b*16+it] = gi;
            v[gi] = -1e30f;
        }
        __syncthreads();
    }
}

// ------------- gather selected K/V (quirk layout, clip to 255) ----------------
__global__ void k_gather_sel(const float* __restrict__ qkv2, const int* __restrict__ idx,
                             float* __restrict__ Ks, float* __restrict__ Vs){
    int row = blockIdx.x;            // b*256 + t ; t = sel*16 + p
    int b = row >> 8, tt = row & 255;
    int sel = tt >> 4, p = tt & 15;
    int blk = idx[b*16+sel]; if(blk > 255) blk = 255;
    int bi = blk >> 4, bj = blk & 15;
    int cc = threadIdx.x;
    int y = bi*4 + ((cc>>2)&3), xx = bj*4 + (cc&3);
    int ch = p*16 + (cc>>4);
    size_t src = ((size_t)(b*4096) + y*64 + xx)*768;
    Ks[(size_t)row*256 + cc] = qkv2[src + 256 + ch];
    Vs[(size_t)row*256 + cc] = qkv2[src + 512 + ch];
}

// ------------- build padded window tokens xw (400*49, 256) -------------------
__global__ void k_xw(const float* __restrict__ xs, float* __restrict__ xw){
    int row = blockIdx.x;             // wb*49 + t
    int wb = row / 49, t = row % 49;
    int b = wb / 100, wrem = wb % 100;
    int wy = wrem / 10, wx = wrem % 10;
    int ty = t / 7, tx = t % 7;
    int y = wy*7 + ty, xx = wx*7 + tx;
    int c = threadIdx.x;
    float v = 0.f;
    if(y < 64 && xx < 64) v = xs[((size_t)(b*4096) + y*64 + xx)*256 + c];
    xw[(size_t)row*256 + c] = v;
}

// ------------- window attention: 49 tokens, rel-pos bias ---------------------
__global__ __launch_bounds__(64) void k_attn_win(
    const float* __restrict__ qkvw, const float* __restrict__ btab,
    float* __restrict__ outp)
{
    const int wb = blockIdx.x, h = blockIdx.y;
    const int lane = threadIdx.x;
    __shared__ float lk[49][64];
    __shared__ float lv[49][64];
    __shared__ float ls[49][51];
    __shared__ float lbias[169];
    for(int i=lane;i<169;i+=64) lbias[i] = btab[i*4 + h];
    for(int r=0;r<49;r++){
        lk[r][lane] = qkvw[((size_t)(wb*49 + r))*768 + 256 + h*64 + lane];
        lv[r][lane] = qkvw[((size_t)(wb*49 + r))*768 + 512 + h*64 + lane];
    }
    __syncthreads();
    if(lane < 49){
        const float* qptr = &qkvw[((size_t)(wb*49 + lane))*768 + h*64];
        float qreg[64];
        #pragma unroll
        for(int d=0;d<64;++d) qreg[d] = qptr[d];
        int ih = lane/7, iw = lane%7;
        float m = -1e30f;
        for(int j=0;j<49;j++){
            float s0=0,s1=0,s2=0,s3=0;
            #pragma unroll
            for(int d=0; d<64; d+=4){
                s0 = fmaf(qreg[d+0], lk[j][d+0], s0);
                s1 = fmaf(qreg[d+1], lk[j][d+1], s1);
                s2 = fmaf(qreg[d+2], lk[j][d+2], s2);
                s3 = fmaf(qreg[d+3], lk[j][d+3], s3);
            }
            int jh=j/7, jw=j%7;
            float s = ((s0+s1)+(s2+s3))*0.125f + lbias[(ih-jh+6)*13 + (iw-jw+6)];
            ls[lane][j] = s;
            m = fmaxf(m, s);
        }
        float l = 0.f;
        for(int j=0;j<49;j++){ float p = __expf(ls[lane][j] - m); ls[lane][j] = p; l += p; }
        float inv = 1.f/l;
        float* op = &outp[((size_t)(wb*49 + lane))*256 + h*64];
        for(int d=0;d<64;d++){
            float a0=0,a1=0;
            for(int j=0;j<48;j+=2){
                a0 = fmaf(ls[lane][j],   lv[j][d],   a0);
                a1 = fmaf(ls[lane][j+1], lv[j+1][d], a1);
            }
            a0 = fmaf(ls[lane][48], lv[48][d], a0);
            op[d] = (a0+a1)*inv;
        }
    }
}

// ------------- final gated combine + transpose to (B,C,H,W) f32 -------------
__global__ void k_combine(const float* __restrict__ ocp, const float* __restrict__ osp,
                          const float* __restrict__ owp, const float* __restrict__ g,
                          float* __restrict__ out){
    __shared__ float tile[32][33];
    int b = blockIdx.z; int c0 = blockIdx.y*32, n0 = blockIdx.x*32;
    int tx = threadIdx.x, ty = threadIdx.y;    // (32,8)
    for(int i=ty;i<32;i+=8){
        int n = n0 + i;
        float g0 = g[(size_t)(b*4096+n)*3 + 0];
        float g1 = g[(size_t)(b*4096+n)*3 + 1];
        float g2 = g[(size_t)(b*4096+n)*3 + 2];
        int y = n >> 6, xx = n & 63;
        int wy = y/7, ty2 = y%7, wx = xx/7, tx2 = xx%7;
        size_t wrow = (size_t)(b*100 + wy*10 + wx)*49 + ty2*7 + tx2;
        size_t base = ((size_t)(b*4096) + n)*256 + c0;
        float vc = ocp[base + tx];
        float vs = osp[base + tx];
        float vw = owp[wrow*256 + c0 + tx];
        tile[i][tx] = g0*vc + g1*vs + g2*vw;
    }
    __syncthreads();
    for(int i=ty;i<32;i+=8)
        out[((size_t)(b*256 + c0+i))*4096 + n0 + tx] = tile[tx][i];
}

// =============================== host side ===================================
extern "C" void kernel_launch(void* const* d_in, const int* in_sizes, int n_in,
                              void* d_out, int out_size, void* d_ws, size_t ws_size,
                              hipStream_t stream)
{
    typedef const float* fp;
    fp x          = (fp)d_in[0];
    fp qkv_cmp_w  = (fp)d_in[1];  fp qkv_cmp_b = (fp)d_in[2];
    fp qkv_slc_w  = (fp)d_in[3];  fp qkv_slc_b = (fp)d_in[4];
    fp cmpk_w1    = (fp)d_in[5];  fp cmpk_b1   = (fp)d_in[6];
    fp cmpk_w2    = (fp)d_in[7];  fp cmpk_b2   = (fp)d_in[8];
    fp cmpv_w1    = (fp)d_in[9];  fp cmpv_b1   = (fp)d_in[10];
    fp cmpv_w2    = (fp)d_in[11]; fp cmpv_b2   = (fp)d_in[12];
    fp pos_embed  = (fp)d_in[13];
    fp win_qkv_w  = (fp)d_in[14]; fp win_qkv_b = (fp)d_in[15];
    fp win_proj_w = (fp)d_in[16]; fp win_proj_b= (fp)d_in[17];
    fp win_btab   = (fp)d_in[18];
    fp proj_cmp_w = (fp)d_in[19]; fp proj_cmp_b= (fp)d_in[20];
    fp proj_slc_w = (fp)d_in[21]; fp proj_slc_b= (fp)d_in[22];
    fp gate_w1    = (fp)d_in[23]; fp gate_b1   = (fp)d_in[24];
    fp gate_w2    = (fp)d_in[25]; fp gate_b2   = (fp)d_in[26];
    (void)in_sizes; (void)n_in; (void)out_size;

    char* ws = (char*)d_ws;
    size_t off = 0;
    auto alloc = [&](size_t bytes)->size_t{
        size_t r = off; off += (bytes + 255) & ~(size_t)255; return r;
    };
    const size_t XS   = alloc((size_t)16384*256*4);
    const size_t QKV  = alloc((size_t)16384*768*4);
    const size_t BIGA = alloc((size_t)4*4096*976*4);     // unfold-A / qkvw / S
    const size_t HID  = alloc((size_t)3844*512*4);
    const size_t KC   = alloc((size_t)3844*256*4);
    const size_t VC   = alloc((size_t)3844*256*4);
    const size_t OC   = alloc((size_t)16384*256*4);
    const size_t IMPP = alloc((size_t)4096*976*4);
    const size_t IMP  = alloc((size_t)4*961*4);
    const size_t IDX  = alloc((size_t)4*16*4);
    const size_t OCP  = alloc((size_t)16384*256*4);
    const size_t XW   = alloc((size_t)19600*256*4);
    const size_t OWP  = alloc((size_t)19600*256*4);
    const size_t KS   = alloc((size_t)4*256*256*4);
    const size_t VS   = alloc((size_t)4*256*256*4);
    const size_t G2   = alloc((size_t)16384*3*4);
    const size_t VTC  = alloc((size_t)4*256*976*4);      // V^T cmp (zero-padded)
    const size_t VTS  = alloc((size_t)4*256*256*4);      // V^T slc
    const size_t TQS  = alloc((size_t)768*256*2);
    const size_t TWQ  = alloc((size_t)768*256*2);
    const size_t TV1  = alloc((size_t)512*4096*2);
    const size_t TV2  = alloc((size_t)256*512*2);
    const size_t TPC  = alloc((size_t)256*256*2);
    const size_t TPS  = alloc((size_t)256*256*2);
    const size_t TWP  = alloc((size_t)256*256*2);
    const size_t TG1  = alloc((size_t)64*256*2);
    const size_t TQCH = alloc((size_t)768*256*2);
    const size_t TQCL = alloc((size_t)768*256*2);
    const size_t TK1H = alloc((size_t)512*4096*2);
    const size_t TK1L = alloc((size_t)512*4096*2);
    const size_t TK2H = alloc((size_t)256*512*2);
    const size_t TK2L = alloc((size_t)256*512*2);
    if(off > ws_size) return;

    float* p_xs  = (float*)(ws + XS);
    float* p_qkv = (float*)(ws + QKV);
    float* p_big = (float*)(ws + BIGA);
    float* p_hid = (float*)(ws + HID);
    float* p_kc  = (float*)(ws + KC);
    float* p_vc  = (float*)(ws + VC);
    float* p_oc  = (float*)(ws + OC);
    float* p_impp= (float*)(ws + IMPP);
    float* p_imp = (float*)(ws + IMP);
    int*   p_idx = (int*)  (ws + IDX);
    float* p_ocp = (float*)(ws + OCP);
    float* p_xw  = (float*)(ws + XW);
    float* p_owp = (float*)(ws + OWP);
    float* p_ks  = (float*)(ws + KS);
    float* p_vs  = (float*)(ws + VS);
    float* p_g   = (float*)(ws + G2);
    float* p_vtc = (float*)(ws + VTC);
    float* p_vts = (float*)(ws + VTS);
    unsigned short* t_qs = (unsigned short*)(ws + TQS);
    unsigned short* t_wq = (unsigned short*)(ws + TWQ);
    unsigned short* t_v1 = (unsigned short*)(ws + TV1);
    unsigned short* t_v2 = (unsigned short*)(ws + TV2);
    unsigned short* t_pc = (unsigned short*)(ws + TPC);
    unsigned short* t_ps = (unsigned short*)(ws + TPS);
    unsigned short* t_wp = (unsigned short*)(ws + TWP);
    unsigned short* t_g1 = (unsigned short*)(ws + TG1);
    unsigned short* t_qch= (unsigned short*)(ws + TQCH);
    unsigned short* t_qcl= (unsigned short*)(ws + TQCL);
    unsigned short* t_k1h= (unsigned short*)(ws + TK1H);
    unsigned short* t_k1l= (unsigned short*)(ws + TK1L);
    unsigned short* t_k2h= (unsigned short*)(ws + TK2H);
    unsigned short* t_k2l= (unsigned short*)(ws + TK2L);

    auto gemm = [&](const float* A, fp W, fp bias, float* Cc, int M, int K, int Nn, int act){
        dim3 g((Nn+63)/64, (M+63)/64);
        k_gemm<<<g, 256, 0, stream>>>(A, W, bias, Cc, M, K, Nn, K, Nn, Nn, act, 0, 0, 0);
    };
    auto wt = [&](fp W, unsigned short* WT, int K, int Nn){
        k_wt<<<dim3((K+31)/32, (Nn+31)/32), dim3(32,8), 0, stream>>>(W, WT, K, Nn);
    };
    auto wt2 = [&](fp W, unsigned short* H, unsigned short* L, int K, int Nn){
        k_wt2<<<dim3((K+31)/32, (Nn+31)/32), dim3(32,8), 0, stream>>>(W, H, L, K, Nn);
    };
    // single-bf16 weight GEMM, 128^2 tile (grids >=256 blocks for these shapes)
    auto mgemm = [&](const float* A, const unsigned short* WT, fp bias, float* Cc,
                     int M, int K, int Nn, int act){
        dim3 g((Nn+127)/128, (M+127)/128);
        k_mgs<4,4,1,1><<<g, 256, 0, stream>>>(A, nullptr, WT, nullptr, bias, Cc,
            M, Nn, K, K, 0, Nn, act, 1.0f, 0, 0, 0);
    };
    // single-bf16 weight GEMM, 64^2 tile (grid-starved shapes)
    auto mgemm64 = [&](const float* A, const unsigned short* WT, fp bias, float* Cc,
                       int M, int K, int Nn, int act){
        dim3 g((Nn+63)/64, (M+63)/64);
        k_mgs<2,2,1,1><<<g, 256, 0, stream>>>(A, nullptr, WT, nullptr, bias, Cc,
            M, Nn, K, K, 0, Nn, act, 1.0f, 0, 0, 0);
    };
    // split (3-term) weight GEMM
    auto sgemm = [&](const float* A, const unsigned short* H, const unsigned short* L,
                     fp bias, float* Cc, int M, int K, int Nn, int act, bool big){
        if(big){
            dim3 g((Nn+127)/128, (M+127)/128);
            k_mgs<4,4,1,3><<<g, 256, 0, stream>>>(A, nullptr, H, L, bias, Cc,
                M, Nn, K, K, 0, Nn, act, 1.0f, 0, 0, 0);
        } else {
            dim3 g((Nn+63)/64, (M+63)/64);
            k_mgs<2,2,1,3><<<g, 256, 0, stream>>>(A, nullptr, H, L, bias, Cc,
                M, Nn, K, K, 0, Nn, act, 1.0f, 0, 0, 0);
        }
    };

    // 0. weight preprocessing
    wt(qkv_slc_w, t_qs, 256, 768);
    wt(win_qkv_w, t_wq, 256, 768);
    wt(cmpv_w1,   t_v1, 4096, 512);
    wt(cmpv_w2,   t_v2, 512, 256);
    wt(proj_cmp_w,t_pc, 256, 256);
    wt(proj_slc_w,t_ps, 256, 256);
    wt(win_proj_w,t_wp, 256, 256);
    wt(gate_w1,   t_g1, 256, 64);
    wt2(qkv_cmp_w, t_qch, t_qcl, 256, 768);
    wt2(cmpk_w1,   t_k1h, t_k1l, 4096, 512);
    wt2(cmpk_w2,   t_k2h, t_k2l, 512, 256);

    // 1. xs = transpose(x)
    k_xs<<<dim3(128,8,4), dim3(32,8), 0, stream>>>(x, p_xs);
    // 2. qkv_cmp (split MFMA)
    sgemm(p_xs, t_qch, t_qcl, qkv_cmp_b, p_qkv, 16384, 256, 768, 0, true);
    // 3-5. compressed K path (split MFMA)
    k_unfold<<<3844, 256, 0, stream>>>(p_qkv, pos_embed, p_big, 256);
    sgemm(p_big, t_k1h, t_k1l, cmpk_b1, p_hid, 3844, 4096, 512, 1, false);
    sgemm(p_hid, t_k2h, t_k2l, cmpk_b2, p_kc, 3844, 512, 256, 0, false);
    // 6-8. compressed V path (single bf16, 64^2 tile: 488/244 blocks)
    k_unfold<<<3844, 256, 0, stream>>>(p_qkv, nullptr, p_big, 512);
    mgemm64(p_big, t_v1, cmpv_b1, p_hid, 3844, 4096, 512, 1);
    mgemm64(p_hid, t_v2, cmpv_b2, p_vc, 3844, 512, 256, 0);
    // V^T for PV (zero-padded to 976)
    k_vt<<<dim3(31,8,4), dim3(32,8), 0, stream>>>(p_vc, p_vtc, 961, 976);
    // 9. compressed attention: S = 0.125*Q·K^T (split), softmax, PV (split, 64^2)
    for(int b=0;b<4;b++){
        k_mgs<4,4,0,3><<<dim3(8,32,4), 256, 0, stream>>>(
            p_qkv + (size_t)b*4096*768, p_kc + (size_t)b*961*256, nullptr, nullptr,
            nullptr, p_big, 4096, 961, 64, 768, 256, 976, 0, 0.125f,
            64, 64, (long)4096*976);
        k_softmax<61><<<dim3(256,4), 256, 0, stream>>>(
            p_big, 976, 961, p_impp + (size_t)b*1024*976);
        k_mgs<2,2,0,3><<<dim3(1,64,4), 256, 0, stream>>>(
            p_big, p_vtc + (size_t)b*256*976, nullptr, nullptr,
            nullptr, p_oc + (size_t)b*4096*256,
            4096, 64, 976, 976, 976, 256, 0, 1.0f,
            (long)4096*976, (long)64*976, 64);
    }
    k_imp_reduce<<<dim3(16,4), 256, 0, stream>>>(p_impp, p_imp);
    k_topk<<<4, 256, 0, stream>>>(p_imp, p_idx);
    // 10. out_cmp projection (128^2: 256 blocks)
    mgemm(p_oc, t_pc, proj_cmp_b, p_ocp, 16384, 256, 256, 0);
    // 11. qkv_slc
    mgemm(p_xs, t_qs, qkv_slc_b, p_qkv, 16384, 256, 768, 0);
    // 12-14. window branch (qkvw reuses BIGA)
    k_xw<<<19600, 256, 0, stream>>>(p_xs, p_xw);
    mgemm(p_xw, t_wq, win_qkv_b, p_big, 19600, 256, 768, 0);
    k_attn_win<<<dim3(400,4), 64, 0, stream>>>(p_big, win_btab, p_xw);   // xw := owin_tok
    mgemm(p_xw, t_wp, win_proj_b, p_owp, 19600, 256, 256, 0);
    // 15-17. selected branch
    k_gather_sel<<<1024, 256, 0, stream>>>(p_qkv, p_idx, p_ks, p_vs);
    k_vt<<<dim3(8,8,4), dim3(32,8), 0, stream>>>(p_vs, p_vts, 256, 256);
    for(int b=0;b<4;b++){
        k_mgs<2,2,0,3><<<dim3(4,64,4), 256, 0, stream>>>(
            p_qkv + (size_t)b*4096*768, p_ks + (size_t)b*256*256, nullptr, nullptr,
            nullptr, p_big, 4096, 256, 64, 768, 256, 256, 0, 0.125f,
            64, 64, (long)4096*256);
        k_softmax<16><<<dim3(256,4), 256, 0, stream>>>(
            p_big, 256, 256, nullptr);
        k_mgs<2,2,0,3><<<dim3(1,64,4), 256, 0, stream>>>(
            p_big, p_vts + (size_t)b*256*256, nullptr, nullptr,
            nullptr, p_oc + (size_t)b*4096*256,
            4096, 64, 256, 256, 256, 256, 0, 1.0f,
            (long)4096*256, (long)64*256, 64);
    }
    mgemm(p_oc, t_ps, proj_slc_b, p_xw, 16384, 256, 256, 0);             // xw := out_slc
    // 18-19. gate (64^2: 256 blocks)
    mgemm64(p_xs, t_g1, gate_b1, p_hid, 16384, 256, 64, 1);
    gemm(p_hid, gate_w2, gate_b2, p_g, 16384, 64, 3, 2);
    // 20. combine
    k_combine<<<dim3(128,8,4), dim3(32,8), 0, stream>>>(p_ocp, p_xw, p_owp, p_g,
                                                        (float*)d_out);
}

// Round 10
// 1229.839 us; speedup vs baseline: 3.8022x; 1.1612x over previous
//
#include <hip/hip_runtime.h>
#include <stdint.h>
#include <stddef.h>

// SpatialNSA on MI355X — round 10: round-9 compute graph, repacked workspace
// (248.6 MB < proven 259.2 MB budget; round 9's 298.7 MB overflowed ws_size
// and silently early-returned -> zero output).
//  * out_slc -> BIGA+0 ; out_win(f32) -> BIGA+20MB ; window tokens (bf16) ->
//    POOL impp region ; owin_tok stored bf16 in POOL oc region.
//  * attn_win emits bf16; win_proj consumes bf16 A.
//  * selection path (qkv_cmp->cmpk->QK_cmp->softmax->imp) split bf16,
//    bit-identical to round 8.

#define DEV __device__ __forceinline__

typedef __attribute__((ext_vector_type(8))) short short8;
typedef __attribute__((ext_vector_type(4))) float f32x4;
typedef unsigned short u16;

DEV u16 f2bf(float f){
    unsigned u = __float_as_uint(f);
    u += 0x7FFFu + ((u>>16)&1u);   // RNE
    return (u16)(u>>16);
}
DEV float bf2f(u16 u){ return __uint_as_float(((unsigned)u)<<16); }

// ------- transpose+split: x (B,C,N) f32 -> xs_h/xs_l (B,N,C) bf16 ------------
__global__ void k_xs(const float* __restrict__ x, u16* __restrict__ xh,
                     u16* __restrict__ xl){
    __shared__ float t[32][33];
    int b = blockIdx.z; int c0 = blockIdx.y*32; int n0 = blockIdx.x*32;
    int tx = threadIdx.x, ty = threadIdx.y;            // (32,8)
    for(int i=ty;i<32;i+=8)
        t[i][tx] = x[((size_t)(b*256 + c0+i))*4096 + n0 + tx];
    __syncthreads();
    for(int i=ty;i<32;i+=8){
        float v = t[tx][i];
        u16 h = f2bf(v);
        size_t o = ((size_t)(b*4096 + n0+i))*256 + c0 + tx;
        xh[o] = h;
        xl[o] = f2bf(v - bf2f(h));
    }
}

// -------- weight transpose+cast: W (K,N) f32 -> WT (N,K) bf16 ---------------
__global__ void k_wt(const float* __restrict__ W, u16* __restrict__ WT,
                     int K, int N){
    __shared__ float t[32][33];
    int k0 = blockIdx.x*32, n0 = blockIdx.y*32;
    int tx = threadIdx.x, ty = threadIdx.y;
    for(int i=ty;i<32;i+=8)
        if(k0+i<K && n0+tx<N) t[i][tx] = W[(size_t)(k0+i)*N + n0+tx];
    __syncthreads();
    for(int i=ty;i<32;i+=8)
        if(n0+i<N && k0+tx<K) WT[(size_t)(n0+i)*K + k0+tx] = f2bf(t[tx][i]);
}

// -------- split weight transpose: W (K,N) f32 -> (N,K) bf16 hi + lo ---------
__global__ void k_wt2(const float* __restrict__ W, u16* __restrict__ Hi,
                      u16* __restrict__ Lo, int K, int N){
    __shared__ float t[32][33];
    int k0 = blockIdx.x*32, n0 = blockIdx.y*32;
    int tx = threadIdx.x, ty = threadIdx.y;
    for(int i=ty;i<32;i+=8)
        if(k0+i<K && n0+tx<N) t[i][tx] = W[(size_t)(k0+i)*N + n0+tx];
    __syncthreads();
    for(int i=ty;i<32;i+=8)
        if(n0+i<N && k0+tx<K){
            float v = t[tx][i];
            u16 h = f2bf(v);
            Hi[(size_t)(n0+i)*K + k0+tx] = h;
            Lo[(size_t)(n0+i)*K + k0+tx] = f2bf(v - bf2f(h));
        }
}

// -------- V transpose: vc rows (b*NK+k)*256+c -> bf16 vt[(b*256+c)*ldk+k] ----
__global__ void k_vt(const float* __restrict__ vc, u16* __restrict__ vt,
                     int NK, int ldk){
    __shared__ float t[32][33];
    int b = blockIdx.z; int k0 = blockIdx.x*32; int c0 = blockIdx.y*32;
    int tx = threadIdx.x, ty = threadIdx.y;
    for(int i=ty;i<32;i+=8){
        int k = k0+i;
        t[i][tx] = (k < NK) ? vc[((size_t)(b*NK + k))*256 + c0 + tx] : 0.f;
    }
    __syncthreads();
    for(int i=ty;i<32;i+=8){
        int k = k0+tx;
        if(k < ldk)
            vt[((size_t)(b*256 + c0+i))*ldk + k] = f2bf(t[tx][i]);
    }
}

// ---------------- f32 GEMM (gate tail only) ----------------------------------
__global__ __launch_bounds__(256) void k_gemm(
        const float* __restrict__ A, const float* __restrict__ W,
        const float* __restrict__ bias, float* __restrict__ C,
        int M, int K, int Nn, int act)
{
    __shared__ float As[16][68];
    __shared__ float Bs[16][64];
    const int m0 = blockIdx.y*64, n0 = blockIdx.x*64;
    const int t = threadIdx.x, tx = t&15, ty = t>>4;
    float acc[4][4] = {};
    const int am = t>>2;
    const int ak = (t&3)*4;
    const bool arow_ok = (m0+am) < M;

    for(int k0=0;k0<K;k0+=16){
        float4 av = make_float4(0.f,0.f,0.f,0.f);
        if(arow_ok) av = *reinterpret_cast<const float4*>(&A[(size_t)(m0+am)*K + k0 + ak]);
        As[ak+0][am]=av.x; As[ak+1][am]=av.y; As[ak+2][am]=av.z; As[ak+3][am]=av.w;
        {
            int n = t&63, kb = t>>6;
            #pragma unroll
            for(int r=0;r<4;r++){
                int kk = r*4 + kb; float v = 0.f;
                if(n0+n < Nn) v = W[(size_t)(k0+kk)*Nn + n0+n];
                Bs[kk][n] = v;
            }
        }
        __syncthreads();
        #pragma unroll
        for(int kk=0;kk<16;kk++){
            float a0=As[kk][ty*4+0], a1=As[kk][ty*4+1], a2=As[kk][ty*4+2], a3=As[kk][ty*4+3];
            float b0=Bs[kk][tx*4+0], b1=Bs[kk][tx*4+1], b2=Bs[kk][tx*4+2], b3=Bs[kk][tx*4+3];
            acc[0][0]=fmaf(a0,b0,acc[0][0]); acc[0][1]=fmaf(a0,b1,acc[0][1]);
            acc[0][2]=fmaf(a0,b2,acc[0][2]); acc[0][3]=fmaf(a0,b3,acc[0][3]);
            acc[1][0]=fmaf(a1,b0,acc[1][0]); acc[1][1]=fmaf(a1,b1,acc[1][1]);
            acc[1][2]=fmaf(a1,b2,acc[1][2]); acc[1][3]=fmaf(a1,b3,acc[1][3]);
            acc[2][0]=fmaf(a2,b0,acc[2][0]); acc[2][1]=fmaf(a2,b1,acc[2][1]);
            acc[2][2]=fmaf(a2,b2,acc[2][2]); acc[2][3]=fmaf(a2,b3,acc[2][3]);
            acc[3][0]=fmaf(a3,b0,acc[3][0]); acc[3][1]=fmaf(a3,b1,acc[3][1]);
            acc[3][2]=fmaf(a3,b2,acc[3][2]); acc[3][3]=fmaf(a3,b3,acc[3][3]);
        }
        __syncthreads();
    }
    #pragma unroll
    for(int i=0;i<4;i++){
        int m = m0 + ty*4 + i;
        if(m >= M) continue;
        #pragma unroll
        for(int j=0;j<4;j++){
            int n = n0 + tx*4 + j;
            if(n >= Nn) continue;
            float v = acc[i][j] + (bias ? bias[n] : 0.f);
            if(act==1)      v = 0.5f*v*(1.0f + erff(v*0.70710678118654752f));
            else if(act==2) v = 1.0f/(1.0f + expf(-v));
            C[(size_t)m*Nn + n] = v;
        }
    }
}

// ===== unified MFMA GEMM: C = scale*(A @ B^T) [+bias][act] ===================
// AM/BMD: 0 = f32 (convert in staging), 1 = bf16, 2 = bf16 hi/lo pair.
// NSPLIT: 3 = split product (~f32 accuracy), 1 = plain bf16.
// Tile 32WM x 32WN, BK=64, 4 waves 2x2. Chunk K-guard (needs K%8==0).
template<int WM, int WN, int AM, int BMD, int NSPLIT>
__global__ __launch_bounds__(256) void k_mgs(
        const float* __restrict__ Af, const u16* __restrict__ Ah,
        const u16* __restrict__ Al,
        const float* __restrict__ Bf, const u16* __restrict__ Bh,
        const u16* __restrict__ Bl,
        const float* __restrict__ bias, float* __restrict__ C,
        int M, int N, int K, int lda, int ldb, int ldc, int act, float scale,
        long zsA, long zsB, long zsC)
{
    constexpr int BM = 32*WM, BN = 32*WN;
    constexpr bool SP = (NSPLIT == 3);
    const long zo = (long)blockIdx.z;
    if(AM==0){ Af += zo*zsA; } else { Ah += zo*zsA; if(AM==2) Al += zo*zsA; }
    if(BMD==0){ Bf += zo*zsB; } else { Bh += zo*zsB; if(BMD==2) Bl += zo*zsB; }
    C += zo*zsC;

    __shared__ u16 Ahi[BM*64];
    __shared__ u16 Alo[SP ? BM*64 : 8];
    __shared__ u16 Bhi[BN*64];
    __shared__ u16 Blo[SP ? BN*64 : 8];

    const int m0 = blockIdx.y*BM, n0 = blockIdx.x*BN;
    const int tid = threadIdx.x, lane = tid&63, wv = tid>>6;
    const int wm = (wv>>1)*(16*WM), wn = (wv&1)*(16*WN);
    f32x4 acc[WM][WN] = {};

    constexpr int TPR_A = 256/BM;
    constexpr int CH_A  = 8/TPR_A;
    const int arow = tid / TPR_A;
    const int acol0 = (tid % TPR_A)*(128/TPR_A);
    constexpr int TPR_B = 256/BN;
    constexpr int CH_B  = 8/TPR_B;
    const int brow = tid / TPR_B;
    const int bcol0 = (tid % TPR_B)*(128/TPR_B);

    for(int kt=0; kt<K; kt+=64){
        // ---- stage A ----
        {
            const bool ok = (m0+arow) < M;
            #pragma unroll
            for(int c=0;c<CH_A;c++){
                int colbyte = acol0 + c*16;
                int e = colbyte>>1;
                const bool lok = ok && (kt + e + 8 <= K);
                short8 h = {}, l = {};
                if(AM==0){
                    float4 v0 = make_float4(0,0,0,0), v1 = v0;
                    if(lok){
                        const float* src = &Af[(size_t)(m0+arow)*lda + kt + e];
                        v0 = *reinterpret_cast<const float4*>(src);
                        v1 = *reinterpret_cast<const float4*>(src+4);
                    }
                    float vv[8] = {v0.x,v0.y,v0.z,v0.w,v1.x,v1.y,v1.z,v1.w};
                    #pragma unroll
                    for(int j=0;j<8;j++){
                        u16 hb = f2bf(vv[j]);
                        h[j] = (short)hb;
                        if(SP) l[j] = (short)f2bf(vv[j] - bf2f(hb));
                    }
                } else {
                    if(lok){
                        h = *reinterpret_cast<const short8*>(Ah + (size_t)(m0+arow)*lda + kt + e);
                        if(SP && AM==2)
                            l = *reinterpret_cast<const short8*>(Al + (size_t)(m0+arow)*lda + kt + e);
                    }
                }
                int byteoff = arow*128 + (colbyte ^ ((arow&7)<<4));
                *reinterpret_cast<short8*>(reinterpret_cast<char*>(Ahi)+byteoff) = h;
                if(SP)
                    *reinterpret_cast<short8*>(reinterpret_cast<char*>(Alo)+byteoff) = l;
            }
        }
        // ---- stage B ----
        {
            const bool ok = (n0+brow) < N;
            #pragma unroll
            for(int c=0;c<CH_B;c++){
                int colbyte = bcol0 + c*16;
                int e = colbyte>>1;
                const bool lok = ok && (kt + e + 8 <= K);
                short8 h = {}, l = {};
                if(BMD==0){
                    float4 v0 = make_float4(0,0,0,0), v1 = v0;
                    if(lok){
                        const float* src = &Bf[(size_t)(n0+brow)*ldb + kt + e];
                        v0 = *reinterpret_cast<const float4*>(src);
                        v1 = *reinterpret_cast<const float4*>(src+4);
                    }
                    float vv[8] = {v0.x,v0.y,v0.z,v0.w,v1.x,v1.y,v1.z,v1.w};
                    #pragma unroll
                    for(int j=0;j<8;j++){
                        u16 hb = f2bf(vv[j]);
                        h[j] = (short)hb;
                        if(SP) l[j] = (short)f2bf(vv[j] - bf2f(hb));
                    }
                } else {
                    if(lok){
                        h = *reinterpret_cast<const short8*>(Bh + (size_t)(n0+brow)*ldb + kt + e);
                        if(SP && BMD==2)
                            l = *reinterpret_cast<const short8*>(Bl + (size_t)(n0+brow)*ldb + kt + e);
                    }
                }
                int byteoff = brow*128 + (colbyte ^ ((brow&7)<<4));
                *reinterpret_cast<short8*>(reinterpret_cast<char*>(Bhi)+byteoff) = h;
                if(SP)
                    *reinterpret_cast<short8*>(reinterpret_cast<char*>(Blo)+byteoff) = l;
            }
        }
        __syncthreads();
        #pragma unroll
        for(int kb=0;kb<2;kb++){
            short8 ah[WM], al[WM], bh[WN], bl[WN];
            #pragma unroll
            for(int i=0;i<WM;i++){
                int ar = wm + i*16 + (lane&15);
                int ab = ar*128 + (((kb*64) + ((lane>>4)*16)) ^ ((ar&7)<<4));
                ah[i] = *reinterpret_cast<const short8*>(reinterpret_cast<const char*>(Ahi)+ab);
                if(SP)
                    al[i] = *reinterpret_cast<const short8*>(reinterpret_cast<const char*>(Alo)+ab);
            }
            #pragma unroll
            for(int i=0;i<WN;i++){
                int br = wn + i*16 + (lane&15);
                int bb = br*128 + (((kb*64) + ((lane>>4)*16)) ^ ((br&7)<<4));
                bh[i] = *reinterpret_cast<const short8*>(reinterpret_cast<const char*>(Bhi)+bb);
                if(SP)
                    bl[i] = *reinterpret_cast<const short8*>(reinterpret_cast<const char*>(Blo)+bb);
            }
            #pragma unroll
            for(int mi=0;mi<WM;mi++)
                #pragma unroll
                for(int ni=0;ni<WN;ni++){
                    if(SP){
                        acc[mi][ni] = __builtin_amdgcn_mfma_f32_16x16x32_bf16(
                                          al[mi], bh[ni], acc[mi][ni], 0, 0, 0);
                        acc[mi][ni] = __builtin_amdgcn_mfma_f32_16x16x32_bf16(
                                          ah[mi], bl[ni], acc[mi][ni], 0, 0, 0);
                    }
                    acc[mi][ni] = __builtin_amdgcn_mfma_f32_16x16x32_bf16(
                                      ah[mi], bh[ni], acc[mi][ni], 0, 0, 0);
                }
        }
        __syncthreads();
    }
    #pragma unroll
    for(int mi=0;mi<WM;mi++){
        #pragma unroll
        for(int ni=0;ni<WN;ni++){
            int col = n0 + wn + ni*16 + (lane&15);
            if(col >= N) continue;
            int rowb = m0 + wm + mi*16 + ((lane>>4)*4);
            float bv = bias ? bias[col] : 0.f;
            #pragma unroll
            for(int r=0;r<4;r++){
                int m = rowb + r;
                if(m >= M) continue;
                float v = acc[mi][ni][r]*scale + bv;
                if(act==1)      v = 0.5f*v*(1.0f + erff(v*0.70710678118654752f));
                else if(act==2) v = 1.0f/(1.0f + expf(-v));
                C[(size_t)m*ldc + col] = v;
            }
        }
    }
}

// ------------- softmax: S f32 -> P bf16 (+importance via LDS, f32-exact) -----
template<int NJ, bool IMP>
__global__ __launch_bounds__(256) void k_softmax(
    const float* __restrict__ S, u16* __restrict__ P,
    int ld, int NK, float* __restrict__ impp)
{
    __shared__ float lp[IMP ? 16*NJ*16 : 8];
    const int qc = blockIdx.x, h = blockIdx.y;
    const int tid = threadIdx.x;
    const int r = tid >> 4, c = tid & 15;
    const float* row = S + (size_t)h*4096*ld + (size_t)(qc*16 + r)*ld;
    u16* prow = P + (size_t)h*4096*ld + (size_t)(qc*16 + r)*ld;
    float s[NJ];
    float m = -1e30f;
    #pragma unroll
    for(int j=0;j<NJ;j++){
        int k = c + j*16;
        s[j] = (k < NK) ? row[k] : -1e30f;
        m = fmaxf(m, s[j]);
    }
    m = fmaxf(m, __shfl_xor(m, 1));
    m = fmaxf(m, __shfl_xor(m, 2));
    m = fmaxf(m, __shfl_xor(m, 4));
    m = fmaxf(m, __shfl_xor(m, 8));
    float l = 0.f;
    #pragma unroll
    for(int j=0;j<NJ;j++){ s[j] = __expf(s[j] - m); l += s[j]; }
    l += __shfl_xor(l, 1);
    l += __shfl_xor(l, 2);
    l += __shfl_xor(l, 4);
    l += __shfl_xor(l, 8);
    const float inv = 1.f / l;
    #pragma unroll
    for(int j=0;j<NJ;j++){
        float p = s[j]*inv;               // pad lanes: exp(-1e30-m)=0
        prow[c + j*16] = f2bf(p);
        if(IMP) lp[r*(NJ*16) + c + j*16] = p;
    }
    if(IMP){
        __syncthreads();
        int k4 = tid*4;
        if(k4 < NJ*16){
            float4 acc = make_float4(0.f,0.f,0.f,0.f);
            #pragma unroll
            for(int rr=0; rr<16; rr++){
                float4 v = *reinterpret_cast<const float4*>(&lp[rr*(NJ*16) + k4]);
                acc.x+=v.x; acc.y+=v.y; acc.z+=v.z; acc.w+=v.w;
            }
            *reinterpret_cast<float4*>(&impp[(size_t)(h*256 + qc)*976 + k4]) = acc;
        }
    }
}

// ------------- unfold: pair (K path, +pos) or single (V path) bf16 -----------
__global__ void k_unfold(const float* __restrict__ qkv, const float* __restrict__ pos,
                         u16* __restrict__ oh, u16* __restrict__ ol, int chanBase){
    int row = blockIdx.x;                 // 0..3843
    int b = row / 961, blk = row % 961;
    int bi = blk / 31, bj = blk % 31;
    for(int j = threadIdx.x; j < 4096; j += 256){
        int ch = j >> 4;
        int kh = (j >> 2) & 3, kw = j & 3;
        int n = (bi*2 + kh)*64 + (bj*2 + kw);
        float v = qkv[((size_t)(b*4096) + n)*768 + chanBase + ch];
        if(pos) v += pos[j];
        u16 h = f2bf(v);
        oh[(size_t)row*4096 + j] = h;
        if(ol) ol[(size_t)row*4096 + j] = f2bf(v - bf2f(h));
    }
}

// ------------- deterministic importance reduce -------------------------------
__global__ void k_imp_reduce(const float* __restrict__ impp, float* __restrict__ imp){
    __shared__ float part[4][64];
    int b = blockIdx.y;
    int k = blockIdx.x*64 + (threadIdx.x & 63);
    int rr = threadIdx.x >> 6;
    float s = 0.f;
    if(k < 976){
        for(int r=rr; r<1024; r+=4)
            s += impp[((size_t)(b*1024) + r)*976 + k];
    }
    part[rr][threadIdx.x & 63] = s;
    __syncthreads();
    if(threadIdx.x < 64 && k < 961){
        float t = ((part[0][threadIdx.x] + part[1][threadIdx.x])
                 + part[2][threadIdx.x]) + part[3][threadIdx.x];
        imp[b*961 + k] = t;
    }
}

// ------------- top-16, parallel argmax, lowest-index tie-break ---------------
__global__ __launch_bounds__(256) void k_topk(const float* __restrict__ imp,
                                              int* __restrict__ idx){
    int b = blockIdx.x;
    __shared__ float v[961];
    __shared__ float wvv[4];
    __shared__ int   wvi[4];
    int t = threadIdx.x;
    int lane = t & 63, wid = t >> 6;
    for(int i=t;i<961;i+=256) v[i] = imp[b*961+i];
    __syncthreads();
    for(int it=0; it<16; it++){
        float bv = -1e30f; int bi = 1<<30;
        for(int i=t;i<961;i+=256){
            float val = v[i];
            if(val > bv){ bv=val; bi=i; }
        }
        #pragma unroll
        for(int off=32; off>0; off>>=1){
            float ov = __shfl_xor(bv, off);
            int   oi = __shfl_xor(bi, off);
            if(ov > bv || (ov == bv && oi < bi)){ bv = ov; bi = oi; }
        }
        if(lane==0){ wvv[wid]=bv; wvi[wid]=bi; }
        __syncthreads();
        if(t==0){
            float gb=wvv[0]; int gi=wvi[0];
            #pragma unroll
            for(int w=1;w<4;w++){
                if(wvv[w]>gb || (wvv[w]==gb && wvi[w]<gi)){ gb=wvv[w]; gi=wvi[w]; }
            }
            idx[b*16+it] = gi;
            v[gi] = -1e30f;
        }
        __syncthreads();
    }
}

// ------------- gather selected K/V (quirk layout, clip to 255) ----------------
__global__ void k_gather_sel(const float* __restrict__ qkv2, const int* __restrict__ idx,
                             float* __restrict__ Ks, float* __restrict__ Vs){
    int row = blockIdx.x;            // b*256 + t ; t = sel*16 + p
    int b = row >> 8, tt = row & 255;
    int sel = tt >> 4, p = tt & 15;
    int blk = idx[b*16+sel]; if(blk > 255) blk = 255;
    int bi = blk >> 4, bj = blk & 15;
    int cc = threadIdx.x;
    int y = bi*4 + ((cc>>2)&3), xx = bj*4 + (cc&3);
    int ch = p*16 + (cc>>4);
    size_t src = ((size_t)(b*4096) + y*64 + xx)*768;
    Ks[(size_t)row*256 + cc] = qkv2[src + 256 + ch];
    Vs[(size_t)row*256 + cc] = qkv2[src + 512 + ch];
}

// ------------- build padded window tokens xw (bf16) --------------------------
__global__ void k_xw(const u16* __restrict__ xh, u16* __restrict__ xw){
    int row = blockIdx.x;             // wb*49 + t
    int wb = row / 49, t = row % 49;
    int b = wb / 100, wrem = wb % 100;
    int wy = wrem / 10, wx = wrem % 10;
    int ty = t / 7, tx = t % 7;
    int y = wy*7 + ty, xx = wx*7 + tx;
    int c = threadIdx.x;
    u16 v = 0;
    if(y < 64 && xx < 64) v = xh[((size_t)(b*4096) + y*64 + xx)*256 + c];
    xw[(size_t)row*256 + c] = v;
}

// ------------- window attention: 49 tokens, rel-pos bias -> bf16 out ---------
__global__ __launch_bounds__(64) void k_attn_win(
    const float* __restrict__ qkvw, const float* __restrict__ btab,
    u16* __restrict__ outp)
{
    const int wb = blockIdx.x, h = blockIdx.y;
    const int lane = threadIdx.x;
    __shared__ float lk[49][64];
    __shared__ float lv[49][64];
    __shared__ float ls[49][51];
    __shared__ float lbias[169];
    for(int i=lane;i<169;i+=64) lbias[i] = btab[i*4 + h];
    for(int r=0;r<49;r++){
        lk[r][lane] = qkvw[((size_t)(wb*49 + r))*768 + 256 + h*64 + lane];
        lv[r][lane] = qkvw[((size_t)(wb*49 + r))*768 + 512 + h*64 + lane];
    }
    __syncthreads();
    if(lane < 49){
        const float* qptr = &qkvw[((size_t)(wb*49 + lane))*768 + h*64];
        float qreg[64];
        #pragma unroll
        for(int d=0;d<64;++d) qreg[d] = qptr[d];
        int ih = lane/7, iw = lane%7;
        float m = -1e30f;
        for(int j=0;j<49;j++){
            float s0=0,s1=0,s2=0,s3=0;
            #pragma unroll
            for(int d=0; d<64; d+=4){
                s0 = fmaf(qreg[d+0], lk[j][d+0], s0);
                s1 = fmaf(qreg[d+1], lk[j][d+1], s1);
                s2 = fmaf(qreg[d+2], lk[j][d+2], s2);
                s3 = fmaf(qreg[d+3], lk[j][d+3], s3);
            }
            int jh=j/7, jw=j%7;
            float s = ((s0+s1)+(s2+s3))*0.125f + lbias[(ih-jh+6)*13 + (iw-jw+6)];
            ls[lane][j] = s;
            m = fmaxf(m, s);
        }
        float l = 0.f;
        for(int j=0;j<49;j++){ float p = __expf(ls[lane][j] - m); ls[lane][j] = p; l += p; }
        float inv = 1.f/l;
        u16* op = &outp[((size_t)(wb*49 + lane))*256 + h*64];
        for(int d=0;d<64;d++){
            float a0=0,a1=0;
            for(int j=0;j<48;j+=2){
                a0 = fmaf(ls[lane][j],   lv[j][d],   a0);
                a1 = fmaf(ls[lane][j+1], lv[j+1][d], a1);
            }
            a0 = fmaf(ls[lane][48], lv[48][d], a0);
            op[d] = f2bf((a0+a1)*inv);
        }
    }
}

// ------------- final gated combine + transpose to (B,C,H,W) f32 -------------
__global__ void k_combine(const float* __restrict__ ocp, const float* __restrict__ osp,
                          const float* __restrict__ owp, const float* __restrict__ g,
                          float* __restrict__ out){
    __shared__ float tile[32][33];
    int b = blockIdx.z; int c0 = blockIdx.y*32, n0 = blockIdx.x*32;
    int tx = threadIdx.x, ty = threadIdx.y;    // (32,8)
    for(int i=ty;i<32;i+=8){
        int n = n0 + i;
        float g0 = g[(size_t)(b*4096+n)*3 + 0];
        float g1 = g[(size_t)(b*4096+n)*3 + 1];
        float g2 = g[(size_t)(b*4096+n)*3 + 2];
        int y = n >> 6, xx = n & 63;
        int wy = y/7, ty2 = y%7, wx = xx/7, tx2 = xx%7;
        size_t wrow = (size_t)(b*100 + wy*10 + wx)*49 + ty2*7 + tx2;
        size_t base = ((size_t)(b*4096) + n)*256 + c0;
        float vc = ocp[base + tx];
        float vs = osp[base + tx];
        float vw = owp[wrow*256 + c0 + tx];
        tile[i][tx] = g0*vc + g1*vs + g2*vw;
    }
    __syncthreads();
    for(int i=ty;i<32;i+=8)
        out[((size_t)(b*256 + c0+i))*4096 + n0 + tx] = tile[tx][i];
}

// =============================== host side ===================================
extern "C" void kernel_launch(void* const* d_in, const int* in_sizes, int n_in,
                              void* d_out, int out_size, void* d_ws, size_t ws_size,
                              hipStream_t stream)
{
    typedef const float* fp;
    fp x          = (fp)d_in[0];
    fp qkv_cmp_w  = (fp)d_in[1];  fp qkv_cmp_b = (fp)d_in[2];
    fp qkv_slc_w  = (fp)d_in[3];  fp qkv_slc_b = (fp)d_in[4];
    fp cmpk_w1    = (fp)d_in[5];  fp cmpk_b1   = (fp)d_in[6];
    fp cmpk_w2    = (fp)d_in[7];  fp cmpk_b2   = (fp)d_in[8];
    fp cmpv_w1    = (fp)d_in[9];  fp cmpv_b1   = (fp)d_in[10];
    fp cmpv_w2    = (fp)d_in[11]; fp cmpv_b2   = (fp)d_in[12];
    fp pos_embed  = (fp)d_in[13];
    fp win_qkv_w  = (fp)d_in[14]; fp win_qkv_b = (fp)d_in[15];
    fp win_proj_w = (fp)d_in[16]; fp win_proj_b= (fp)d_in[17];
    fp win_btab   = (fp)d_in[18];
    fp proj_cmp_w = (fp)d_in[19]; fp proj_cmp_b= (fp)d_in[20];
    fp proj_slc_w = (fp)d_in[21]; fp proj_slc_b= (fp)d_in[22];
    fp gate_w1    = (fp)d_in[23]; fp gate_b1   = (fp)d_in[24];
    fp gate_w2    = (fp)d_in[25]; fp gate_b2   = (fp)d_in[26];
    (void)in_sizes; (void)n_in; (void)out_size;

    char* ws = (char*)d_ws;
    size_t off = 0;
    auto alloc = [&](size_t bytes)->size_t{
        size_t r = off; off += (bytes + 255) & ~(size_t)255; return r;
    };
    const size_t XSH  = alloc((size_t)16384*256*2);
    const size_t XSL  = alloc((size_t)16384*256*2);
    const size_t QKV  = alloc((size_t)16384*768*4);
    // BIGA hosts (temporally disjoint): S_cmp (64MB, step 9) / qkvw (57.8MB,
    // step 13) / { S_slc [0,16.8M) steps 15-16 ; out_win f32 [20M,40.2M)
    // step 14->combine ; out_slc [0,16.8M) step 17->combine }.
    const size_t BIGA = alloc((size_t)4*4096*976*4);
    const size_t HID  = alloc((size_t)3844*512*4);
    const size_t KC   = alloc((size_t)3844*256*4);
    const size_t VC   = alloc((size_t)3844*256*4);
    // POOL: [impp | oc | ocp | pb]; also hosts UK hi/lo (63MB, steps 3-7,
    // dead before impp/oc/ocp/pb first writes), window tokens bf16 (impp
    // region, steps 12-13), owin_tok bf16 (oc region, steps 13-14).
    const size_t S_IMPP = (size_t)4096*976*4;        // 15,990,784
    const size_t S_OC   = (size_t)16384*256*4;       // 16,777,216
    const size_t S_PB   = (size_t)4*4096*976*2;      // 31,981,568
    const size_t POOL = alloc(S_IMPP + S_OC + S_OC + S_PB);
    const size_t IMP  = alloc((size_t)4*961*4);
    const size_t IDX  = alloc((size_t)4*16*4);
    const size_t KS   = alloc((size_t)4*256*256*4);
    const size_t VS   = alloc((size_t)4*256*256*4);
    const size_t G2   = alloc((size_t)16384*3*4);
    const size_t VTC  = alloc((size_t)4*256*976*2);
    const size_t VTS  = alloc((size_t)4*256*256*2);
    const size_t TQS  = alloc((size_t)768*256*2);
    const size_t TWQ  = alloc((size_t)768*256*2);
    const size_t TV1  = alloc((size_t)512*4096*2);
    const size_t TV2  = alloc((size_t)256*512*2);
    const size_t TPC  = alloc((size_t)256*256*2);
    const size_t TPS  = alloc((size_t)256*256*2);
    const size_t TWP  = alloc((size_t)256*256*2);
    const size_t TG1  = alloc((size_t)64*256*2);
    const size_t TQCH = alloc((size_t)768*256*2);
    const size_t TQCL = alloc((size_t)768*256*2);
    const size_t TK1H = alloc((size_t)512*4096*2);
    const size_t TK1L = alloc((size_t)512*4096*2);
    const size_t TK2H = alloc((size_t)256*512*2);
    const size_t TK2L = alloc((size_t)256*512*2);
    if(off > ws_size) return;   // ~248.6 MB total (round 8's 259.2 passed)

    u16*   p_xsh = (u16*)(ws + XSH);
    u16*   p_xsl = (u16*)(ws + XSL);
    float* p_qkv = (float*)(ws + QKV);
    float* p_big = (float*)(ws + BIGA);
    float* p_oslc= (float*)(ws + BIGA);                      // out_slc alias
    float* p_owp = (float*)(ws + BIGA + 20971520);           // out_win f32 alias
    float* p_hid = (float*)(ws + HID);
    float* p_kc  = (float*)(ws + KC);
    float* p_vc  = (float*)(ws + VC);
    float* p_impp= (float*)(ws + POOL);
    float* p_oc  = (float*)(ws + POOL + S_IMPP);
    float* p_ocp = (float*)(ws + POOL + S_IMPP + S_OC);
    u16*   p_pb  = (u16*)  (ws + POOL + S_IMPP + S_OC + S_OC);
    u16*   p_ukh = (u16*)  (ws + POOL);                      // UK hi (early)
    u16*   p_ukl = p_ukh + (size_t)3844*4096;                // UK lo (early)
    u16*   p_uv  = p_ukh;                                    // V unfold reuse
    u16*   p_xwb = (u16*)  (ws + POOL);                      // win tokens (impp region)
    u16*   p_owin= (u16*)  (ws + POOL + S_IMPP);             // owin_tok bf16 (oc region)
    float* p_imp = (float*)(ws + IMP);
    int*   p_idx = (int*)  (ws + IDX);
    float* p_ks  = (float*)(ws + KS);
    float* p_vs  = (float*)(ws + VS);
    float* p_g   = (float*)(ws + G2);
    u16*   p_vtc = (u16*)(ws + VTC);
    u16*   p_vts = (u16*)(ws + VTS);
    u16* t_qs = (u16*)(ws + TQS);
    u16* t_wq = (u16*)(ws + TWQ);
    u16* t_v1 = (u16*)(ws + TV1);
    u16* t_v2 = (u16*)(ws + TV2);
    u16* t_pc = (u16*)(ws + TPC);
    u16* t_ps = (u16*)(ws + TPS);
    u16* t_wp = (u16*)(ws + TWP);
    u16* t_g1 = (u16*)(ws + TG1);
    u16* t_qch= (u16*)(ws + TQCH);
    u16* t_qcl= (u16*)(ws + TQCL);
    u16* t_k1h= (u16*)(ws + TK1H);
    u16* t_k1l= (u16*)(ws + TK1L);
    u16* t_k2h= (u16*)(ws + TK2H);
    u16* t_k2l= (u16*)(ws + TK2L);

    auto wt = [&](fp W, u16* WT, int K, int Nn){
        k_wt<<<dim3((K+31)/32, (Nn+31)/32), dim3(32,8), 0, stream>>>(W, WT, K, Nn);
    };
    auto wt2 = [&](fp W, u16* H, u16* L, int K, int Nn){
        k_wt2<<<dim3((K+31)/32, (Nn+31)/32), dim3(32,8), 0, stream>>>(W, H, L, K, Nn);
    };

    // 0. weight preprocessing
    wt(qkv_slc_w, t_qs, 256, 768);
    wt(win_qkv_w, t_wq, 256, 768);
    wt(cmpv_w1,   t_v1, 4096, 512);
    wt(cmpv_w2,   t_v2, 512, 256);
    wt(proj_cmp_w,t_pc, 256, 256);
    wt(proj_slc_w,t_ps, 256, 256);
    wt(win_proj_w,t_wp, 256, 256);
    wt(gate_w1,   t_g1, 256, 64);
    wt2(qkv_cmp_w, t_qch, t_qcl, 256, 768);
    wt2(cmpk_w1,   t_k1h, t_k1l, 4096, 512);
    wt2(cmpk_w2,   t_k2h, t_k2l, 512, 256);

    // 1. xs (bf16 hi/lo)
    k_xs<<<dim3(128,8,4), dim3(32,8), 0, stream>>>(x, p_xsh, p_xsl);
    // 2. qkv_cmp (split, A pair, B pair)
    k_mgs<4,4,2,2,3><<<dim3(6,128), 256, 0, stream>>>(
        nullptr, p_xsh, p_xsl, nullptr, t_qch, t_qcl, qkv_cmp_b, p_qkv,
        16384, 768, 256, 256, 256, 768, 0, 1.0f, 0, 0, 0);
    // 3-5. compressed K path (pre-split unfold, split GEMMs)
    k_unfold<<<3844, 256, 0, stream>>>(p_qkv, pos_embed, p_ukh, p_ukl, 256);
    k_mgs<2,2,2,2,3><<<dim3(8,61), 256, 0, stream>>>(
        nullptr, p_ukh, p_ukl, nullptr, t_k1h, t_k1l, cmpk_b1, p_hid,
        3844, 512, 4096, 4096, 4096, 512, 1, 1.0f, 0, 0, 0);
    k_mgs<2,2,0,2,3><<<dim3(4,61), 256, 0, stream>>>(
        p_hid, nullptr, nullptr, nullptr, t_k2h, t_k2l, cmpk_b2, p_kc,
        3844, 256, 512, 512, 512, 256, 0, 1.0f, 0, 0, 0);
    // 6-8. compressed V path (single bf16; UV aliases UKH — K path done)
    k_unfold<<<3844, 256, 0, stream>>>(p_qkv, nullptr, p_uv, nullptr, 512);
    k_mgs<2,2,1,1,1><<<dim3(8,61), 256, 0, stream>>>(
        nullptr, p_uv, nullptr, nullptr, t_v1, nullptr, cmpv_b1, p_hid,
        3844, 512, 4096, 4096, 4096, 512, 1, 1.0f, 0, 0, 0);
    k_mgs<2,2,0,1,1><<<dim3(4,61), 256, 0, stream>>>(
        p_hid, nullptr, nullptr, nullptr, t_v2, nullptr, cmpv_b2, p_vc,
        3844, 256, 512, 512, 512, 256, 0, 1.0f, 0, 0, 0);
    // V^T bf16 (zero-padded to 976)
    k_vt<<<dim3(31,8,4), dim3(32,8), 0, stream>>>(p_vc, p_vtc, 961, 976);
    // 9. compressed attention: QK (split, f32 S), softmax->bf16 P, PV (bf16)
    for(int b=0;b<4;b++){
        k_mgs<4,4,0,0,3><<<dim3(8,32,4), 256, 0, stream>>>(
            p_qkv + (size_t)b*4096*768, nullptr, nullptr,
            p_kc + (size_t)b*961*256, nullptr, nullptr,
            nullptr, p_big, 4096, 961, 64, 768, 256, 976, 0, 0.125f,
            64, 64, (long)4096*976);
        k_softmax<61,true><<<dim3(256,4), 256, 0, stream>>>(
            p_big, p_pb, 976, 961, p_impp + (size_t)b*1024*976);
        k_mgs<2,2,1,1,1><<<dim3(1,64,4), 256, 0, stream>>>(
            nullptr, p_pb, nullptr,
            nullptr, p_vtc + (size_t)b*256*976, nullptr,
            nullptr, p_oc + (size_t)b*4096*256,
            4096, 64, 976, 976, 976, 256, 0, 1.0f,
            (long)4096*976, (long)64*976, 64);
    }
    k_imp_reduce<<<dim3(16,4), 256, 0, stream>>>(p_impp, p_imp);
    k_topk<<<4, 256, 0, stream>>>(p_imp, p_idx);
    // 10. out_cmp projection (bf16 weights)
    k_mgs<4,4,0,1,1><<<dim3(2,128), 256, 0, stream>>>(
        p_oc, nullptr, nullptr, nullptr, t_pc, nullptr, proj_cmp_b, p_ocp,
        16384, 256, 256, 256, 256, 256, 0, 1.0f, 0, 0, 0);
    // 11. qkv_slc (A = xs hi bf16)
    k_mgs<4,4,1,1,1><<<dim3(6,128), 256, 0, stream>>>(
        nullptr, p_xsh, nullptr, nullptr, t_qs, nullptr, qkv_slc_b, p_qkv,
        16384, 768, 256, 256, 256, 768, 0, 1.0f, 0, 0, 0);
    // 12-14. window branch (tokens bf16 in impp region; qkvw f32 in BIGA;
    //        owin_tok bf16 in oc region; out_win f32 at BIGA+20MB)
    k_xw<<<19600, 256, 0, stream>>>(p_xsh, p_xwb);
    k_mgs<4,4,1,1,1><<<dim3(6,154), 256, 0, stream>>>(
        nullptr, p_xwb, nullptr, nullptr, t_wq, nullptr, win_qkv_b, p_big,
        19600, 768, 256, 256, 256, 768, 0, 1.0f, 0, 0, 0);
    k_attn_win<<<dim3(400,4), 64, 0, stream>>>(p_big, win_btab, p_owin);
    k_mgs<4,4,1,1,1><<<dim3(2,154), 256, 0, stream>>>(
        nullptr, p_owin, nullptr, nullptr, t_wp, nullptr, win_proj_b, p_owp,
        19600, 256, 256, 256, 256, 256, 0, 1.0f, 0, 0, 0);
    // 15-17. selected branch (single bf16 — not selection-critical)
    k_gather_sel<<<1024, 256, 0, stream>>>(p_qkv, p_idx, p_ks, p_vs);
    k_vt<<<dim3(8,8,4), dim3(32,8), 0, stream>>>(p_vs, p_vts, 256, 256);
    for(int b=0;b<4;b++){
        k_mgs<2,2,0,0,1><<<dim3(4,64,4), 256, 0, stream>>>(
            p_qkv + (size_t)b*4096*768, nullptr, nullptr,
            p_ks + (size_t)b*256*256, nullptr, nullptr,
            nullptr, p_big, 4096, 256, 64, 768, 256, 256, 0, 0.125f,
            64, 64, (long)4096*256);
        k_softmax<16,false><<<dim3(256,4), 256, 0, stream>>>(
            p_big, p_pb, 256, 256, nullptr);
        k_mgs<2,2,1,1,1><<<dim3(1,64,4), 256, 0, stream>>>(
            nullptr, p_pb, nullptr,
            nullptr, p_vts + (size_t)b*256*256, nullptr,
            nullptr, p_oc + (size_t)b*4096*256,
            4096, 64, 256, 256, 256, 256, 0, 1.0f,
            (long)4096*256, (long)64*256, 64);
    }
    k_mgs<4,4,0,1,1><<<dim3(2,128), 256, 0, stream>>>(
        p_oc, nullptr, nullptr, nullptr, t_ps, nullptr, proj_slc_b, p_oslc,
        16384, 256, 256, 256, 256, 256, 0, 1.0f, 0, 0, 0);
    // 18-19. gate
    k_mgs<2,2,1,1,1><<<dim3(1,256), 256, 0, stream>>>(
        nullptr, p_xsh, nullptr, nullptr, t_g1, nullptr, gate_b1, p_hid,
        16384, 64, 256, 256, 256, 64, 1, 1.0f, 0, 0, 0);
    k_gemm<<<dim3(1,256), 256, 0, stream>>>(p_hid, gate_w2, gate_b2, p_g,
                                            16384, 64, 3, 2);
    // 20. combine
    k_combine<<<dim3(128,8,4), dim3(32,8), 0, stream>>>(p_ocp, p_oslc, p_owp, p_g,
                                                        (float*)d_out);
}